// Round 8
// baseline (1873.798 us; speedup 1.0000x reference)
//
#include <hip/hip_runtime.h>
#include <math.h>

#define B_TOT 4096
#define CHUNK 1024

typedef _Float16 half_t;
typedef _Float16 h2 __attribute__((ext_vector_type(2)));

#if __has_builtin(__builtin_amdgcn_fdot2)
#define FDOT2(a, b, c) __builtin_amdgcn_fdot2((a), (b), (c), false)
#else
#define FDOT2(a, b, c) fmaf((float)(a)[1], (float)(b)[1], fmaf((float)(a)[0], (float)(b)[0], (c)))
#endif

// Per-wave LDS: K 49x36 halves (72B rows, fp16), V 49x34 floats (136B rows, fp32).
// Block: 4 waves KV (40768) + wi stage slot (12288) = 53056 B -> 3 blocks/CU.
// FF weights (32 KB) overlay [0,32768) (over KV) after attention, barrier-guarded.
// V stays fp32: fp16 V measured absmax 2.9e-3 > 1.19e-3 threshold (round 4 —
// upstream-of-topk errors flip selections; decoder-side fp16 is safe).
#define KSTR 36          // halves per K row
#define VSTR 34          // floats per V row
#define KBYTES (49 * 72)
#define WAVE_LDS (49 * 72 + 49 * 136)  // 10192
#define WI_OFF  (4 * WAVE_LDS)         // 40768
#define BLOCK_LDS (WI_OFF + 12288)     // 53056

// ---------------------------------------------------------------------------
// Fused: patch conv (1->32, k4 s4) + 2 transformer blocks.
// wi staged for blk0 at kernel top and for blk1 during blk0's FF-stage window
// (saves one barrier per blk and takes the stage off the critical path).
// ---------------------------------------------------------------------------
__global__ __launch_bounds__(256) void k_tokens(
    const float* __restrict__ x, const float* __restrict__ pw, const float* __restrict__ pb,
    const float* __restrict__ ln1g, const float* __restrict__ ln1b,
    const float* __restrict__ wi, const float* __restrict__ bi,
    const float* __restrict__ wo, const float* __restrict__ bo,
    const float* __restrict__ ln2g, const float* __restrict__ ln2b,
    const float* __restrict__ w1, const float* __restrict__ fb1,
    const float* __restrict__ w2t, const float* __restrict__ fb2,
    float* __restrict__ tokens)
{
    __shared__ __align__(16) unsigned char Lraw[BLOCK_LDS];
    const int tid = threadIdx.x;
    const int wv = tid >> 6, lane = tid & 63;
    const int b = blockIdx.x * 4 + wv;
    half_t* Kb = (half_t*)(Lraw + wv * WAVE_LDS);
    float*  Vb = (float*)(Lraw + wv * WAVE_LDS + KBYTES);
    const float* wiL = (const float*)(Lraw + WI_OFF);
    float* Lf = (float*)Lraw;            // FF-weight overlay (block-wide)
    const bool is_tok = lane < 49;
    const int s = is_tok ? lane : 48;
    const int py = s / 7, px = s % 7;

    // --- prologue: stage blk-0 qkv weights (visible after barrier (A)) ---
    {
        const float4* srcw = (const float4*)(wi);
        float4* dstw = (float4*)(Lraw + WI_OFF);
        for (int e = tid; e < 768; e += 256) dstw[e] = srcw[e];
    }

    // --- patch conv: direct float4 loads (rows are 16B-aligned) ---
    float xv[16];
    const float* xb = x + (size_t)b * 784 + py * 112 + px * 4;
    #pragma unroll
    for (int r = 0; r < 4; ++r) {
        float4 vq = *(const float4*)(xb + r * 28);
        xv[4 * r + 0] = vq.x; xv[4 * r + 1] = vq.y;
        xv[4 * r + 2] = vq.z; xv[4 * r + 3] = vq.w;
    }
    float t[32];
    #pragma unroll 4
    for (int c = 0; c < 32; ++c) {
        float a = pb[c];
        const float* wr = pw + c * 16;
        #pragma unroll
        for (int i = 0; i < 16; ++i) a = fmaf(xv[i], wr[i], a);
        t[c] = a;
    }

    for (int blk = 0; blk < 2; ++blk) {
        const float* bib = bi + blk * 96;

        // --- LN1 ---
        float mu = 0.f;
        #pragma unroll
        for (int c = 0; c < 32; ++c) mu += t[c];
        mu *= 0.03125f;
        float var = 0.f;
        #pragma unroll
        for (int c = 0; c < 32; ++c) { float d = t[c] - mu; var = fmaf(d, d, var); }
        float rstd = rsqrtf(var * 0.03125f + 1e-5f);
        float xn[32];
        #pragma unroll
        for (int c = 0; c < 32; ++c)
            xn[c] = (t[c] - mu) * rstd * ln1g[blk * 32 + c] + ln1b[blk * 32 + c];

        __syncthreads();   // (A) prior-phase LDS reads done; wi stage visible

        // --- K projection -> LDS fp16 (broadcast b128 weight reads) ---
        #pragma unroll 4
        for (int d = 0; d < 32; ++d) {
            const float* wr = wiL + (32 + d) * 32;
            float a0 = bib[32 + d], a1 = 0.f;
            #pragma unroll
            for (int c2 = 0; c2 < 4; ++c2) {
                float4 wq = *(const float4*)&wr[4 * c2];
                a0 = fmaf(xn[4 * c2],     wq.x, a0);
                a0 = fmaf(xn[4 * c2 + 1], wq.y, a0);
                a0 = fmaf(xn[4 * c2 + 2], wq.z, a0);
                a0 = fmaf(xn[4 * c2 + 3], wq.w, a0);
            }
            #pragma unroll
            for (int c2 = 4; c2 < 8; ++c2) {
                float4 wq = *(const float4*)&wr[4 * c2];
                a1 = fmaf(xn[4 * c2],     wq.x, a1);
                a1 = fmaf(xn[4 * c2 + 1], wq.y, a1);
                a1 = fmaf(xn[4 * c2 + 2], wq.z, a1);
                a1 = fmaf(xn[4 * c2 + 3], wq.w, a1);
            }
            if (is_tok) Kb[s * KSTR + d] = (half_t)(a0 + a1);
        }
        // --- V projection -> LDS fp32 ---
        #pragma unroll 4
        for (int d = 0; d < 32; ++d) {
            const float* wr = wiL + (64 + d) * 32;
            float a0 = bib[64 + d], a1 = 0.f;
            #pragma unroll
            for (int c2 = 0; c2 < 4; ++c2) {
                float4 wq = *(const float4*)&wr[4 * c2];
                a0 = fmaf(xn[4 * c2],     wq.x, a0);
                a0 = fmaf(xn[4 * c2 + 1], wq.y, a0);
                a0 = fmaf(xn[4 * c2 + 2], wq.z, a0);
                a0 = fmaf(xn[4 * c2 + 3], wq.w, a0);
            }
            #pragma unroll
            for (int c2 = 4; c2 < 8; ++c2) {
                float4 wq = *(const float4*)&wr[4 * c2];
                a1 = fmaf(xn[4 * c2],     wq.x, a1);
                a1 = fmaf(xn[4 * c2 + 1], wq.y, a1);
                a1 = fmaf(xn[4 * c2 + 2], wq.z, a1);
                a1 = fmaf(xn[4 * c2 + 3], wq.w, a1);
            }
            if (is_tok) Vb[s * VSTR + d] = a0 + a1;
        }
        // --- Q projection (scaled), packed to half2 for fdot2 ---
        float q0[32];
        #pragma unroll 4
        for (int d = 0; d < 32; ++d) {
            const float* wr = wiL + d * 32;
            float a0 = bib[d], a1 = 0.f;
            #pragma unroll
            for (int c2 = 0; c2 < 4; ++c2) {
                float4 wq = *(const float4*)&wr[4 * c2];
                a0 = fmaf(xn[4 * c2],     wq.x, a0);
                a0 = fmaf(xn[4 * c2 + 1], wq.y, a0);
                a0 = fmaf(xn[4 * c2 + 2], wq.z, a0);
                a0 = fmaf(xn[4 * c2 + 3], wq.w, a0);
            }
            #pragma unroll
            for (int c2 = 4; c2 < 8; ++c2) {
                float4 wq = *(const float4*)&wr[4 * c2];
                a1 = fmaf(xn[4 * c2],     wq.x, a1);
                a1 = fmaf(xn[4 * c2 + 1], wq.y, a1);
                a1 = fmaf(xn[4 * c2 + 2], wq.z, a1);
                a1 = fmaf(xn[4 * c2 + 3], wq.w, a1);
            }
            q0[d] = (a0 + a1) * 0.25f;
        }
        h2 qh[16];
        #pragma unroll
        for (int i = 0; i < 16; ++i) {
            h2 hh; hh[0] = (half_t)q0[2 * i]; hh[1] = (half_t)q0[2 * i + 1];
            qh[i] = hh;
        }

        // wave-local fence: own K/V ds_writes visible before broadcast reads
        __asm__ volatile("s_waitcnt lgkmcnt(0)" ::: "memory");

        // --- attention: 2 heads of 16 dims, softmax without running max ---
        float o[32];
        #pragma unroll
        for (int d = 0; d < 32; ++d) o[d] = 0.f;
        float l0 = 0.f, l1 = 0.f;
        union H4 { double qd; h2 p[2]; };
        for (int j = 0; j < 49; ++j) {
            const double* kr = (const double*)(Kb + j * KSTR);
            const float* vr = Vb + j * VSTR;
            H4 u0, u1, u2, u3, w0, w1h, w2h, w3;
            u0.qd = kr[0]; u1.qd = kr[1]; u2.qd = kr[2]; u3.qd = kr[3];
            w0.qd = kr[4]; w1h.qd = kr[5]; w2h.qd = kr[6]; w3.qd = kr[7];
            float s0a = 0.f, s0b = 0.f, s1a = 0.f, s1b = 0.f;
            s0a = FDOT2(u0.p[0], qh[0], s0a); s0a = FDOT2(u0.p[1], qh[1], s0a);
            s0b = FDOT2(u1.p[0], qh[2], s0b); s0b = FDOT2(u1.p[1], qh[3], s0b);
            s0a = FDOT2(u2.p[0], qh[4], s0a); s0a = FDOT2(u2.p[1], qh[5], s0a);
            s0b = FDOT2(u3.p[0], qh[6], s0b); s0b = FDOT2(u3.p[1], qh[7], s0b);
            s1a = FDOT2(w0.p[0], qh[8], s1a); s1a = FDOT2(w0.p[1], qh[9], s1a);
            s1b = FDOT2(w1h.p[0], qh[10], s1b); s1b = FDOT2(w1h.p[1], qh[11], s1b);
            s1a = FDOT2(w2h.p[0], qh[12], s1a); s1a = FDOT2(w2h.p[1], qh[13], s1a);
            s1b = FDOT2(w3.p[0], qh[14], s1b); s1b = FDOT2(w3.p[1], qh[15], s1b);
            float p0 = __expf(s0a + s0b), p1 = __expf(s1a + s1b);
            l0 += p0; l1 += p1;
            #pragma unroll
            for (int i = 0; i < 8; ++i) {
                float2 va = *(const float2*)&vr[2 * i];
                o[2 * i]     = fmaf(p0, va.x, o[2 * i]);
                o[2 * i + 1] = fmaf(p0, va.y, o[2 * i + 1]);
                float2 vc = *(const float2*)&vr[16 + 2 * i];
                o[16 + 2 * i]     = fmaf(p1, vc.x, o[16 + 2 * i]);
                o[16 + 2 * i + 1] = fmaf(p1, vc.y, o[16 + 2 * i + 1]);
            }
        }
        float il0 = 1.f / l0, il1 = 1.f / l1;
        #pragma unroll
        for (int d = 0; d < 16; ++d) { o[d] *= il0; o[16 + d] *= il1; }

        // --- out projection + residual (wave-uniform global weights, 4 KB) ---
        #pragma unroll
        for (int c = 0; c < 32; ++c) {
            const float* wr = wo + blk * 1024 + c * 32;
            float a = bo[blk * 32 + c];
            #pragma unroll
            for (int k2 = 0; k2 < 32; ++k2) a = fmaf(o[k2], wr[k2], a);
            t[c] += a;
        }

        // --- LN2 ---
        mu = 0.f;
        #pragma unroll
        for (int c = 0; c < 32; ++c) mu += t[c];
        mu *= 0.03125f;
        var = 0.f;
        #pragma unroll
        for (int c = 0; c < 32; ++c) { float d = t[c] - mu; var = fmaf(d, d, var); }
        rstd = rsqrtf(var * 0.03125f + 1e-5f);
        #pragma unroll
        for (int c = 0; c < 32; ++c)
            xn[c] = (t[c] - mu) * rstd * ln2g[blk * 32 + c] + ln2b[blk * 32 + c];

        __syncthreads();   // (C) all waves done reading K/V + wi

        // --- stage FF weights (overlay over KV) + next blk's wi ---
        {
            const float4* src1 = (const float4*)(w1 + blk * 4096);
            const float4* src2 = (const float4*)(w2t + blk * 4096);
            float4* dst = (float4*)Lraw;
            for (int e = tid; e < 1024; e += 256) dst[e] = src1[e];
            for (int e = tid; e < 1024; e += 256) dst[1024 + e] = src2[e];
            if (blk == 0) {
                const float4* srcw = (const float4*)(wi + 3072);
                float4* dstw = (float4*)(Lraw + WI_OFF);
                for (int e = tid; e < 768; e += 256) dstw[e] = srcw[e];
            }
        }
        __syncthreads();   // (D) FF weights (and wi for blk1) visible

        // --- FF from LDS: broadcast ds_read_b128 rows ---
        const float* w2L = Lf + 4096;
        #pragma unroll 2
        for (int j = 0; j < 128; ++j) {
            const float* wr = Lf + j * 32;
            float ha = fb1[blk * 128 + j], hb = 0.f;
            #pragma unroll
            for (int c2 = 0; c2 < 4; ++c2) {
                float4 wq = *(const float4*)&wr[4 * c2];
                ha = fmaf(xn[4 * c2],     wq.x, ha);
                ha = fmaf(xn[4 * c2 + 1], wq.y, ha);
                ha = fmaf(xn[4 * c2 + 2], wq.z, ha);
                ha = fmaf(xn[4 * c2 + 3], wq.w, ha);
            }
            #pragma unroll
            for (int c2 = 4; c2 < 8; ++c2) {
                float4 wq = *(const float4*)&wr[4 * c2];
                hb = fmaf(xn[4 * c2],     wq.x, hb);
                hb = fmaf(xn[4 * c2 + 1], wq.y, hb);
                hb = fmaf(xn[4 * c2 + 2], wq.z, hb);
                hb = fmaf(xn[4 * c2 + 3], wq.w, hb);
            }
            float h = ha + hb;
            h = 0.5f * h * (1.f + erff(h * 0.7071067811865476f));
            const float* w2r = w2L + j * 32;
            #pragma unroll
            for (int c2 = 0; c2 < 8; ++c2) {
                float4 wq = *(const float4*)&w2r[4 * c2];
                t[4 * c2]     = fmaf(h, wq.x, t[4 * c2]);
                t[4 * c2 + 1] = fmaf(h, wq.y, t[4 * c2 + 1]);
                t[4 * c2 + 2] = fmaf(h, wq.z, t[4 * c2 + 2]);
                t[4 * c2 + 3] = fmaf(h, wq.w, t[4 * c2 + 3]);
            }
        }
        #pragma unroll
        for (int c = 0; c < 32; ++c) t[c] += fb2[blk * 32 + c];
    }

    if (is_tok) {
        float* op = tokens + (size_t)b * 1568 + s * 32;
        #pragma unroll
        for (int c = 0; c < 32; c += 4) {
            float4 vv = make_float4(t[c], t[c + 1], t[c + 2], t[c + 3]);
            *(float4*)&op[c] = vv;
        }
    }
}

// ---------------------------------------------------------------------------
// C[M,N] = A[M,K] @ B[N,K]^T (+bias, optional ReLU). 128x64 tile, BK=16,
// 8x4 microtile. ph=1: store output as fp16 (relu'd), packed 8B stores.
// ---------------------------------------------------------------------------
__global__ __launch_bounds__(256) void k_gemm(
    const float* __restrict__ A, const float* __restrict__ Bm,
    const float* __restrict__ bias, float* __restrict__ C,
    int M, int N, int K, int relu, int ph)
{
    __shared__ float As[16 * 132];
    __shared__ float Bs[16 * 68];
    const int n0 = blockIdx.x * 64, m0 = blockIdx.y * 128;
    const int tid = threadIdx.x;
    const int tx = tid & 15, ty = tid >> 4;
    const int lr = tid >> 1, lk = (tid & 1) * 8;
    const int br = tid >> 2, bk = (tid & 3) * 4;
    float acc[8][4] = {{0.f}};
    for (int k0 = 0; k0 < K; k0 += 16) {
        float4 av0 = *(const float4*)&A[(size_t)(m0 + lr) * K + k0 + lk];
        float4 av1 = *(const float4*)&A[(size_t)(m0 + lr) * K + k0 + lk + 4];
        float4 bv0 = *(const float4*)&Bm[(size_t)(n0 + br) * K + k0 + bk];
        As[(lk + 0) * 132 + lr] = av0.x;
        As[(lk + 1) * 132 + lr] = av0.y;
        As[(lk + 2) * 132 + lr] = av0.z;
        As[(lk + 3) * 132 + lr] = av0.w;
        As[(lk + 4) * 132 + lr] = av1.x;
        As[(lk + 5) * 132 + lr] = av1.y;
        As[(lk + 6) * 132 + lr] = av1.z;
        As[(lk + 7) * 132 + lr] = av1.w;
        Bs[(bk + 0) * 68 + br] = bv0.x;
        Bs[(bk + 1) * 68 + br] = bv0.y;
        Bs[(bk + 2) * 68 + br] = bv0.z;
        Bs[(bk + 3) * 68 + br] = bv0.w;
        __syncthreads();
        #pragma unroll
        for (int k = 0; k < 16; ++k) {
            float4 a0 = *(const float4*)&As[k * 132 + ty * 8];
            float4 a1 = *(const float4*)&As[k * 132 + ty * 8 + 4];
            float4 bv = *(const float4*)&Bs[k * 68 + tx * 4];
            float a8[8] = {a0.x, a0.y, a0.z, a0.w, a1.x, a1.y, a1.z, a1.w};
            float b4[4] = {bv.x, bv.y, bv.z, bv.w};
            #pragma unroll
            for (int i = 0; i < 8; ++i)
                #pragma unroll
                for (int j = 0; j < 4; ++j)
                    acc[i][j] = fmaf(a8[i], b4[j], acc[i][j]);
        }
        __syncthreads();
    }
    if (!ph) {
        #pragma unroll
        for (int i = 0; i < 8; ++i) {
            int m = m0 + ty * 8 + i;
            #pragma unroll
            for (int j = 0; j < 4; ++j) {
                int n = n0 + tx * 4 + j;
                float v = acc[i][j] + (bias ? bias[n] : 0.f);
                if (relu) v = fmaxf(v, 0.f);
                C[(size_t)m * N + n] = v;
            }
        }
    } else {
        half_t* Ch = (half_t*)C;
        #pragma unroll
        for (int i = 0; i < 8; ++i) {
            int m = m0 + ty * 8 + i;
            float v[4];
            #pragma unroll
            for (int j = 0; j < 4; ++j) {
                int n = n0 + tx * 4 + j;
                float vv = acc[i][j] + (bias ? bias[n] : 0.f);
                if (relu) vv = fmaxf(vv, 0.f);
                v[j] = vv;
            }
            union { h2 hh[2]; double dd; } u;
            h2 p0, p1;
            p0[0] = (half_t)v[0]; p0[1] = (half_t)v[1];
            p1[0] = (half_t)v[2]; p1[1] = (half_t)v[3];
            u.hh[0] = p0; u.hh[1] = p1;
            *(double*)&Ch[(size_t)m * N + n0 + tx * 4] = u.dd;
        }
    }
}

// ---------------------------------------------------------------------------
// Fuse dec (linear 256->3136) with convt1 (convT 64->32 k4 s2 p1).
// Output rows PERMUTED to channel-minor: Wf[(px*32+o)][k], bf[px*32+o]
// so the decoder GEMM emits d1 in [sample][px][ch] layout for fdot2 conv1.
// ---------------------------------------------------------------------------
__global__ __launch_bounds__(256) void k_fuse(
    const float* __restrict__ wt1, const float* __restrict__ upt1_b,
    const float* __restrict__ dec_w, const float* __restrict__ dec_b,
    float* __restrict__ Wf, float* __restrict__ bf)
{
    const int n = blockIdx.x;
    const int k = threadIdx.x;
    const int o = n / 196, p = n % 196, y = p / 14, x = p % 14;
    float acc = 0.f, bacc = 0.f;
    for (int ky = 0; ky < 4; ++ky) {
        int iyn = y + 1 - ky;
        if (iyn < 0 || (iyn & 1)) continue;
        int iy = iyn >> 1;
        if (iy > 6) continue;
        for (int kx = 0; kx < 4; ++kx) {
            int ixn = x + 1 - kx;
            if (ixn < 0 || (ixn & 1)) continue;
            int ix = ixn >> 1;
            if (ix > 6) continue;
            for (int c = 0; c < 64; ++c) {
                float w = wt1[((c * 32 + o) * 4 + ky) * 4 + kx];
                int row = c * 49 + iy * 7 + ix;
                acc  = fmaf(w, dec_w[(size_t)row * 256 + k], acc);
                bacc = fmaf(w, dec_b[row], bacc);
            }
        }
    }
    Wf[(size_t)(p * 32 + o) * 256 + k] = acc;
    if (k == 0) bf[p * 32 + o] = bacc + upt1_b[o];
}

// ---------------------------------------------------------------------------
__global__ __launch_bounds__(256) void k_mnorm(const float* __restrict__ mem, float* __restrict__ inv_norm)
{
    __shared__ float red[256];
    const int row = blockIdx.x, tid = threadIdx.x;
    float v = mem[(size_t)row * 256 + tid];
    red[tid] = v * v;
    __syncthreads();
    for (int s = 128; s > 0; s >>= 1) {
        if (tid < s) red[tid] += red[tid + s];
        __syncthreads();
    }
    if (tid == 0) inv_norm[row] = 1.f / fmaxf(sqrtf(red[0]), 1e-12f);
}

// ---------------------------------------------------------------------------
__global__ __launch_bounds__(256) void k_memread(
    const float* __restrict__ latent, const float* __restrict__ dots,
    const float* __restrict__ inv_mn, const float* __restrict__ mem,
    float* __restrict__ out)
{
    __shared__ float red[256];
    __shared__ int   redi[256];
    __shared__ float inv_x_s;
    const int b = blockIdx.x, tid = threadIdx.x;
    float lx = latent[(size_t)b * 256 + tid];
    red[tid] = lx * lx;
    __syncthreads();
    for (int s = 128; s > 0; s >>= 1) {
        if (tid < s) red[tid] += red[tid + s];
        __syncthreads();
    }
    if (tid == 0) inv_x_s = 1.f / fmaxf(sqrtf(red[0]), 1e-12f);
    __syncthreads();
    const float inv_x = inv_x_s;

    float vals[16];
    for (int j = 0; j < 16; ++j) {
        int m = tid + j * 256;
        vals[j] = dots[(size_t)b * 4096 + m] * inv_mn[m] * inv_x;
    }
    float tv[10]; int ti[10];
    for (int t = 0; t < 10; ++t) {
        float bv = -1e30f; int bidx = 0x7fffffff;
        for (int j = 0; j < 16; ++j) {
            int m = tid + j * 256;
            float v = vals[j];
            if (v > bv || (v == bv && m < bidx)) { bv = v; bidx = m; }
        }
        red[tid] = bv; redi[tid] = bidx;
        __syncthreads();
        for (int s = 128; s > 0; s >>= 1) {
            if (tid < s) {
                float v2 = red[tid + s]; int i2 = redi[tid + s];
                if (v2 > red[tid] || (v2 == red[tid] && i2 < redi[tid])) { red[tid] = v2; redi[tid] = i2; }
            }
            __syncthreads();
        }
        int sel = redi[0];
        tv[t] = red[0]; ti[t] = sel;
        if ((sel & 255) == tid) vals[sel >> 8] = -1e30f;
        __syncthreads();
    }
    float w[10], wsum = 0.f;
    for (int t = 0; t < 10; ++t) { w[t] = expf(tv[t] - tv[0]); wsum += w[t]; }
    float inv_ws = 1.f / wsum;
    float acc = 0.f;
    for (int t = 0; t < 10; ++t) acc += (w[t] * inv_ws) * mem[(size_t)ti[t] * 256 + tid];
    out[(size_t)b * 256 + tid] = acc;
}

// ---------------------------------------------------------------------------
// Weight repack.
//   pk2h[(o*9+tap)*32+c] fp16  from c1_w   [32][32][3][3]  (ch-minor, fdot2)
//   pk3[c32][q4][tap4][o16]    from upt2_w [32][16][4][4]
//   pk4[c16][tap9][o8]         from c2_w   [8][16][3][3]
//   pk5[blk2][j128][c32]       from blk_ff2_w [2][32][128] (transpose)
// ---------------------------------------------------------------------------
__global__ __launch_bounds__(256) void k_pack(
    const float* __restrict__ wc1, const float* __restrict__ wt2,
    const float* __restrict__ wc2, const float* __restrict__ w2src,
    half_t* __restrict__ pk2h, float* __restrict__ pk3,
    float* __restrict__ pk4, float* __restrict__ pk5)
{
    int i = blockIdx.x * 256 + threadIdx.x;
    if (i < 9216) {
        int o = i / 288, tap = (i / 32) % 9, c = i & 31;
        pk2h[i] = (half_t)wc1[(o * 32 + c) * 9 + tap];
    }
    if (i < 8192) {
        int o = i & 15, t = (i >> 4) & 3, q = (i >> 6) & 3, c = i >> 8;
        int wy = t >> 1, wx = t & 1, py = q >> 1, px = q & 1;
        int ky = 3 - py - 2 * wy, kx = 3 - px - 2 * wx;
        pk3[i] = wt2[((c * 16 + o) * 4 + ky) * 4 + kx];
    }
    if (i < 1152) {
        int o = i & 7, tap = (i >> 3) % 9, c = i / 72;
        pk4[i] = wc2[(o * 16 + c) * 9 + tap];
    }
    if (i < 8192) {
        int c = i & 31, j = (i >> 5) & 127, bq = i >> 12;
        pk5[i] = w2src[bq * 4096 + c * 128 + j];
    }
}

// ---------------------------------------------------------------------------
// Conv2d 32->32 k3 p1, 14x14, ReLU. 2 samples/block. FDOT2 version:
// input d1 is fp16 channel-minor [sample][px][32]; dot over channels via
// v_dot2_f32_f16 (2 MACs/instr) -> 9216 fdot2/thread vs 18432 fp32 FMA.
// LDS tile [16 rows][16 cols][32ch] halves with pad strides (col 36 halves,
// row 584 halves) to break bank conflicts. Output d2 stays fp32 ch-major.
// ---------------------------------------------------------------------------
__global__ __launch_bounds__(256) void k_conv1(
    const half_t* __restrict__ in, const half_t* __restrict__ pk2h,
    const float* __restrict__ bias, float* __restrict__ out)
{
    __shared__ __align__(16) unsigned int P[9408];   // 37632 B (incl. overread pad)
    const int tid = threadIdx.x;
    const int wv = __builtin_amdgcn_readfirstlane(tid >> 6);
    const int og = wv & 1, s = wv >> 1;
    const int lane = tid & 63;
    const bool active = lane < 56;
    int row = lane >> 2, tx0 = (lane & 3) * 4;
    if (!active) { row = 0; tx0 = 0; }
    const size_t b = (size_t)blockIdx.x * 2 + s;

    for (int e = tid; e < 9408; e += 256) P[e] = 0u;
    __syncthreads();
    {
        const unsigned int* src = (const unsigned int*)in;
        for (int e = tid; e < 6272; e += 256) {
            int si = e / 3136, rem = e - si * 3136;
            int p = rem >> 4, c2 = rem & 15;
            P[si * 4672 + (p / 14 + 1) * 292 + (p % 14 + 1) * 18 + c2] =
                src[(size_t)(blockIdx.x * 2 + si) * 3136 + rem];
        }
    }
    __syncthreads();

    float acc[4][16];
    #pragma unroll
    for (int i = 0; i < 4; ++i)
        #pragma unroll
        for (int o = 0; o < 16; ++o) acc[i][o] = 0.f;

    union U64 { double d; h2 h[2]; };
    const unsigned int* Pb0 = P + s * 4672;
    for (int ky = 0; ky < 3; ++ky) {
        #pragma unroll
        for (int hf = 0; hf < 2; ++hf) {
            h2 v[6][8];
            #pragma unroll
            for (int m = 0; m < 6; ++m) {
                const double* vp = (const double*)(Pb0 + (row + ky) * 292 + (tx0 + m) * 18 + hf * 8);
                #pragma unroll
                for (int k2 = 0; k2 < 4; ++k2) {
                    U64 u; u.d = vp[k2];
                    v[m][2 * k2] = u.h[0]; v[m][2 * k2 + 1] = u.h[1];
                }
            }
            #pragma unroll
            for (int kx = 0; kx < 3; ++kx) {
                #pragma unroll
                for (int o = 0; o < 16; ++o) {
                    const h2* wt = (const h2*)pk2h + ((og * 16 + o) * 9 + ky * 3 + kx) * 16 + hf * 8;
                    #pragma unroll
                    for (int cc = 0; cc < 8; ++cc) {
                        h2 w = wt[cc];
                        acc[0][o] = FDOT2(v[kx + 0][cc], w, acc[0][o]);
                        acc[1][o] = FDOT2(v[kx + 1][cc], w, acc[1][o]);
                        acc[2][o] = FDOT2(v[kx + 2][cc], w, acc[2][o]);
                        acc[3][o] = FDOT2(v[kx + 3][cc], w, acc[3][o]);
                    }
                }
            }
        }
    }

    if (active) {
        #pragma unroll
        for (int o = 0; o < 16; ++o) {
            int oo = og * 16 + o;
            float bo = bias[oo];
            #pragma unroll
            for (int i = 0; i < 4; ++i) {
                int xx = tx0 + i;
                if (xx < 14)
                    out[(b * 32 + oo) * 196 + row * 14 + xx] = fmaxf(acc[i][o] + bo, 0.f);
            }
        }
    }
}

// ---------------------------------------------------------------------------
// FUSED: ConvTranspose2d 32->16 k4 s2 p1 (14x14->28x28, ReLU)
//        + Conv2d 16->8 k3 p1 (ReLU) + Conv2d 8->1 k1. One sample/block.
// Two 8-channel groups keep LDS at 40960 B -> 4 blocks/CU.
// ---------------------------------------------------------------------------
__global__ __launch_bounds__(256) void k_convt23(
    const float* __restrict__ in, const float* __restrict__ pk3,
    const float* __restrict__ bt2, const float* __restrict__ pk4,
    const float* __restrict__ b2, const float* __restrict__ w3,
    const float* __restrict__ b3, float* __restrict__ out)
{
    __shared__ __align__(16) float P[10240];   // 40960 B
    const int b = blockIdx.x, tid = threadIdx.x;

    // ---- Phase 1: convt2 from input tile [c32][16r][20c] ----
    for (int e = tid; e < 10240; e += 256) P[e] = 0.f;
    __syncthreads();
    for (int e = tid; e < 6272; e += 256) {
        int c = e / 196, p = e % 196;
        P[c * 320 + (p / 14 + 1) * 20 + (p % 14 + 1)] = in[(size_t)b * 6272 + e];
    }
    __syncthreads();

    const int q  = __builtin_amdgcn_readfirstlane(tid >> 6);
    const int py = q >> 1, px = q & 1;
    const int lane = tid & 63;
    const bool active = lane < 56;
    int ty = lane >> 2, tx0 = (lane & 3) * 4;
    if (!active) { ty = 0; tx0 = 0; }
    const int rbase = ty + py;

    float acc[4][16];
    #pragma unroll
    for (int i = 0; i < 4; ++i)
        #pragma unroll
        for (int o = 0; o < 16; ++o) acc[i][o] = 0.f;

    for (int c = 0; c < 32; ++c) {
        const float* Pb = &P[c * 320 + rbase * 20 + tx0];
        float raw[2][8];
        #pragma unroll
        for (int r2 = 0; r2 < 2; ++r2) {
            float4 a = *(const float4*)&Pb[r2 * 20];
            float4 bq = *(const float4*)&Pb[r2 * 20 + 4];
            raw[r2][0] = a.x; raw[r2][1] = a.y; raw[r2][2] = a.z; raw[r2][3] = a.w;
            raw[r2][4] = bq.x; raw[r2][5] = bq.y; raw[r2][6] = bq.z; raw[r2][7] = bq.w;
        }
        float rs[2][5];
        #pragma unroll
        for (int r2 = 0; r2 < 2; ++r2)
            #pragma unroll
            for (int j = 0; j < 5; ++j) rs[r2][j] = px ? raw[r2][j + 1] : raw[r2][j];
        const float* wq = pk3 + (size_t)((c * 4 + q) * 4) * 16;
        #pragma unroll
        for (int t = 0; t < 4; ++t) {
            int wy = t >> 1, wx = t & 1;
            const float* wt = wq + t * 16;
            #pragma unroll
            for (int o = 0; o < 16; ++o) {
                float w = wt[o];
                #pragma unroll
                for (int i = 0; i < 4; ++i)
                    acc[i][o] = fmaf(rs[wy][i + wx], w, acc[i][o]);
            }
        }
    }
    __syncthreads();   // all input-tile reads done; P reusable

    // ---- Phases 2+3 per 8-channel group ----
    const bool active2 = tid < 196;
    int row = active2 ? tid / 7 : 0;
    int tx0b = active2 ? (tid % 7) * 4 : 0;
    const int y = 2 * ty + py;

    float acc2[4][8];
    #pragma unroll
    for (int i = 0; i < 4; ++i)
        #pragma unroll
        for (int o = 0; o < 8; ++o) acc2[i][o] = 0.f;

    #pragma unroll
    for (int g = 0; g < 2; ++g) {
        for (int e = tid; e < 7680; e += 256) P[e] = 0.f;
        __syncthreads();
        if (active) {
            #pragma unroll
            for (int o8 = 0; o8 < 8; ++o8) {
                int o = g * 8 + o8;
                float bo = bt2[o];
                #pragma unroll
                for (int i = 0; i < 4; ++i) {
                    int xt = tx0 + i;
                    if (xt < 14)
                        P[(o8 * 30 + y + 1) * 32 + (2 * xt + px + 1)] = fmaxf(acc[i][o] + bo, 0.f);
                }
            }
        }
        __syncthreads();
        for (int cl = 0; cl < 8; ++cl) {
            const float* Pb = &P[(cl * 30 + row) * 32 + tx0b];
            const float* wb = pk4 + (size_t)(g * 8 + cl) * 72;
            #pragma unroll
            for (int ky = 0; ky < 3; ++ky) {
                float4 a = *(const float4*)&Pb[ky * 32];
                float4 bq = *(const float4*)&Pb[ky * 32 + 4];
                float rowb[8] = {a.x, a.y, a.z, a.w, bq.x, bq.y, bq.z, bq.w};
                #pragma unroll
                for (int kx = 0; kx < 3; ++kx) {
                    const float* wt = wb + (ky * 3 + kx) * 8;
                    #pragma unroll
                    for (int o = 0; o < 8; ++o) {
                        float w = wt[o];
                        #pragma unroll
                        for (int i = 0; i < 4; ++i)
                            acc2[i][o] = fmaf(rowb[i + kx], w, acc2[i][o]);
                    }
                }
            }
        }
        __syncthreads();   // group tile fully consumed before next zero-fill
    }

    // ---- conv3 (8->1, k1) + store ----
    if (active2) {
        const float bias3 = b3[0];
        #pragma unroll
        for (int i = 0; i < 4; ++i) {
            float r = bias3;
            #pragma unroll
            for (int o = 0; o < 8; ++o) r += fmaxf(acc2[i][o] + b2[o], 0.f) * w3[o];
            out[(size_t)b * 784 + row * 28 + tx0b + i] = r;
        }
    }
}

// ---------------------------------------------------------------------------
extern "C" void kernel_launch(void* const* d_in, const int* in_sizes, int n_in,
                              void* d_out, int out_size, void* d_ws, size_t ws_size,
                              hipStream_t stream)
{
    const float* x       = (const float*)d_in[0];
    const float* patch_w = (const float*)d_in[1];
    const float* patch_b = (const float*)d_in[2];
    const float* ln1g    = (const float*)d_in[3];
    const float* ln1b    = (const float*)d_in[4];
    const float* wi      = (const float*)d_in[5];
    const float* bi      = (const float*)d_in[6];
    const float* wo      = (const float*)d_in[7];
    const float* bo      = (const float*)d_in[8];
    const float* ln2g    = (const float*)d_in[9];
    const float* ln2b    = (const float*)d_in[10];
    const float* w1      = (const float*)d_in[11];
    const float* b1      = (const float*)d_in[12];
    const float* w2      = (const float*)d_in[13];
    const float* b2      = (const float*)d_in[14];
    const float* lat_w   = (const float*)d_in[15];
    const float* lat_b   = (const float*)d_in[16];
    const float* memory  = (const float*)d_in[17];
    const float* dec_w   = (const float*)d_in[18];
    const float* dec_b   = (const float*)d_in[19];
    const float* upt1_w  = (const float*)d_in[20];
    const float* upt1_b  = (const float*)d_in[21];
    const float* c1_w    = (const float*)d_in[22];
    const float* c1_b    = (const float*)d_in[23];
    const float* upt2_w  = (const float*)d_in[24];
    const float* upt2_b  = (const float*)d_in[25];
    const float* c2_w    = (const float*)d_in[26];
    const float* c2_b    = (const float*)d_in[27];
    const float* c3_w    = (const float*)d_in[28];
    const float* c3_b    = (const float*)d_in[29];
    float* outp = (float*)d_out;

    float* ws = (float*)d_ws;
    size_t off = 0;
    auto alloc = [&](size_t n) { float* p = ws + off; off += (n + 63) & ~(size_t)63; return p; };
    float* tokens     = alloc((size_t)B_TOT * 1568);
    float* latent     = alloc((size_t)B_TOT * 256);
    float* dots       = alloc((size_t)B_TOT * 4096);
    float* mem_latent = alloc((size_t)B_TOT * 256);
    float* inv_mn     = alloc(4096);
    half_t* pk2h      = (half_t*)alloc(4608);
    float* pk3        = alloc(8192);
    float* pk4        = alloc(1152);
    float* pk5        = alloc(8192);
    float* Wf         = alloc((size_t)6272 * 256);
    float* bf         = alloc(6272);
    half_t* d1h       = (half_t*)alloc((size_t)CHUNK * 6272 / 2);
    float* d2         = alloc((size_t)CHUNK * 6272);
    (void)in_sizes; (void)n_in; (void)out_size; (void)ws_size;

    // Weight repack + dec/convt1 algebraic fusion
    k_pack<<<36, 256, 0, stream>>>(c1_w, upt2_w, c2_w, w2, pk2h, pk3, pk4, pk5);
    k_fuse<<<6272, 256, 0, stream>>>(upt1_w, upt1_b, dec_w, dec_b, Wf, bf);

    // Encoder (wave-per-sample)
    k_tokens<<<B_TOT / 4, 256, 0, stream>>>(x, patch_w, patch_b, ln1g, ln1b, wi, bi,
                                            wo, bo, ln2g, ln2b, w1, b1, pk5, b2, tokens);
    k_gemm<<<dim3(256 / 64, B_TOT / 128), 256, 0, stream>>>(tokens, lat_w, lat_b, latent,
                                                            B_TOT, 256, 1568, 0, 0);
    k_mnorm<<<4096, 256, 0, stream>>>(memory, inv_mn);
    k_gemm<<<dim3(4096 / 64, B_TOT / 128), 256, 0, stream>>>(latent, memory, nullptr, dots,
                                                             B_TOT, 4096, 256, 0, 0);
    k_memread<<<B_TOT, 256, 0, stream>>>(latent, dots, inv_mn, memory, mem_latent);

    // Decoder, chunked over batch. GEMM emits fp16 ch-minor d1 for fdot2 conv1.
    for (int c = 0; c < B_TOT / CHUNK; ++c) {
        const float* ml = mem_latent + (size_t)c * CHUNK * 256;
        k_gemm<<<dim3(6272 / 64, CHUNK / 128), 256, 0, stream>>>(ml, Wf, bf, (float*)d1h,
                                                                 CHUNK, 6272, 256, 1, 1);
        k_conv1  <<<CHUNK / 2, 256, 0, stream>>>(d1h, pk2h, c1_b, d2);
        k_convt23<<<CHUNK, 256, 0, stream>>>(d2, pk3, upt2_b, pk4, c2_b, c3_w, c3_b,
                                             outp + (size_t)c * CHUNK * 784);
    }
}

// Round 9
// 1774.021 us; speedup vs baseline: 1.0562x; 1.0562x over previous
//
#include <hip/hip_runtime.h>
#include <math.h>

#define B_TOT 4096
#define CHUNK 1024

typedef _Float16 half_t;
typedef _Float16 h2 __attribute__((ext_vector_type(2)));

#if __has_builtin(__builtin_amdgcn_fdot2)
#define FDOT2(a, b, c) __builtin_amdgcn_fdot2((a), (b), (c), false)
#else
#define FDOT2(a, b, c) fmaf((float)(a)[1], (float)(b)[1], fmaf((float)(a)[0], (float)(b)[0], (c)))
#endif

// Per-wave LDS: K 49x36 halves (72B rows, fp16), V 49x34 floats (136B rows, fp32).
// Block: 4 waves KV (40768) + wi stage slot (12288) = 53056 B -> 3 blocks/CU.
// FF weights (32 KB) overlay [0,32768) (over KV) after attention, barrier-guarded.
// V stays fp32 (round-4: fp16 V broke topk selection, absmax 2.9e-3).
// Decoder conv1 stays fp32 FMA (round-8: fdot2 conv1 regressed ~80us — dot2
// appears not to be full-rate vs v_fma_f32; repack overhead uncompensated).
#define KSTR 36          // halves per K row
#define VSTR 34          // floats per V row
#define KBYTES (49 * 72)
#define WAVE_LDS (49 * 72 + 49 * 136)  // 10192
#define WI_OFF  (4 * WAVE_LDS)         // 40768
#define BLOCK_LDS (WI_OFF + 12288)     // 53056

// ---------------------------------------------------------------------------
// Fused: patch conv (1->32, k4 s4) + 2 transformer blocks.
// wi staged for blk0 at kernel top and for blk1 during blk0's FF-stage window
// (saves one barrier per blk and takes the stage off the critical path).
// ---------------------------------------------------------------------------
__global__ __launch_bounds__(256) void k_tokens(
    const float* __restrict__ x, const float* __restrict__ pw, const float* __restrict__ pb,
    const float* __restrict__ ln1g, const float* __restrict__ ln1b,
    const float* __restrict__ wi, const float* __restrict__ bi,
    const float* __restrict__ wo, const float* __restrict__ bo,
    const float* __restrict__ ln2g, const float* __restrict__ ln2b,
    const float* __restrict__ w1, const float* __restrict__ fb1,
    const float* __restrict__ w2t, const float* __restrict__ fb2,
    float* __restrict__ tokens)
{
    __shared__ __align__(16) unsigned char Lraw[BLOCK_LDS];
    const int tid = threadIdx.x;
    const int wv = tid >> 6, lane = tid & 63;
    const int b = blockIdx.x * 4 + wv;
    half_t* Kb = (half_t*)(Lraw + wv * WAVE_LDS);
    float*  Vb = (float*)(Lraw + wv * WAVE_LDS + KBYTES);
    const float* wiL = (const float*)(Lraw + WI_OFF);
    float* Lf = (float*)Lraw;            // FF-weight overlay (block-wide)
    const bool is_tok = lane < 49;
    const int s = is_tok ? lane : 48;
    const int py = s / 7, px = s % 7;

    // --- prologue: stage blk-0 qkv weights (visible after barrier (A)) ---
    {
        const float4* srcw = (const float4*)(wi);
        float4* dstw = (float4*)(Lraw + WI_OFF);
        for (int e = tid; e < 768; e += 256) dstw[e] = srcw[e];
    }

    // --- patch conv: direct float4 loads (rows are 16B-aligned) ---
    float xv[16];
    const float* xb = x + (size_t)b * 784 + py * 112 + px * 4;
    #pragma unroll
    for (int r = 0; r < 4; ++r) {
        float4 vq = *(const float4*)(xb + r * 28);
        xv[4 * r + 0] = vq.x; xv[4 * r + 1] = vq.y;
        xv[4 * r + 2] = vq.z; xv[4 * r + 3] = vq.w;
    }
    float t[32];
    #pragma unroll 4
    for (int c = 0; c < 32; ++c) {
        float a = pb[c];
        const float* wr = pw + c * 16;
        #pragma unroll
        for (int i = 0; i < 16; ++i) a = fmaf(xv[i], wr[i], a);
        t[c] = a;
    }

    for (int blk = 0; blk < 2; ++blk) {
        const float* bib = bi + blk * 96;

        // --- LN1 ---
        float mu = 0.f;
        #pragma unroll
        for (int c = 0; c < 32; ++c) mu += t[c];
        mu *= 0.03125f;
        float var = 0.f;
        #pragma unroll
        for (int c = 0; c < 32; ++c) { float d = t[c] - mu; var = fmaf(d, d, var); }
        float rstd = rsqrtf(var * 0.03125f + 1e-5f);
        float xn[32];
        #pragma unroll
        for (int c = 0; c < 32; ++c)
            xn[c] = (t[c] - mu) * rstd * ln1g[blk * 32 + c] + ln1b[blk * 32 + c];

        __syncthreads();   // (A) prior-phase LDS reads done; wi stage visible

        // --- K projection -> LDS fp16 (broadcast b128 weight reads) ---
        #pragma unroll 4
        for (int d = 0; d < 32; ++d) {
            const float* wr = wiL + (32 + d) * 32;
            float a0 = bib[32 + d], a1 = 0.f;
            #pragma unroll
            for (int c2 = 0; c2 < 4; ++c2) {
                float4 wq = *(const float4*)&wr[4 * c2];
                a0 = fmaf(xn[4 * c2],     wq.x, a0);
                a0 = fmaf(xn[4 * c2 + 1], wq.y, a0);
                a0 = fmaf(xn[4 * c2 + 2], wq.z, a0);
                a0 = fmaf(xn[4 * c2 + 3], wq.w, a0);
            }
            #pragma unroll
            for (int c2 = 4; c2 < 8; ++c2) {
                float4 wq = *(const float4*)&wr[4 * c2];
                a1 = fmaf(xn[4 * c2],     wq.x, a1);
                a1 = fmaf(xn[4 * c2 + 1], wq.y, a1);
                a1 = fmaf(xn[4 * c2 + 2], wq.z, a1);
                a1 = fmaf(xn[4 * c2 + 3], wq.w, a1);
            }
            if (is_tok) Kb[s * KSTR + d] = (half_t)(a0 + a1);
        }
        // --- V projection -> LDS fp32 ---
        #pragma unroll 4
        for (int d = 0; d < 32; ++d) {
            const float* wr = wiL + (64 + d) * 32;
            float a0 = bib[64 + d], a1 = 0.f;
            #pragma unroll
            for (int c2 = 0; c2 < 4; ++c2) {
                float4 wq = *(const float4*)&wr[4 * c2];
                a0 = fmaf(xn[4 * c2],     wq.x, a0);
                a0 = fmaf(xn[4 * c2 + 1], wq.y, a0);
                a0 = fmaf(xn[4 * c2 + 2], wq.z, a0);
                a0 = fmaf(xn[4 * c2 + 3], wq.w, a0);
            }
            #pragma unroll
            for (int c2 = 4; c2 < 8; ++c2) {
                float4 wq = *(const float4*)&wr[4 * c2];
                a1 = fmaf(xn[4 * c2],     wq.x, a1);
                a1 = fmaf(xn[4 * c2 + 1], wq.y, a1);
                a1 = fmaf(xn[4 * c2 + 2], wq.z, a1);
                a1 = fmaf(xn[4 * c2 + 3], wq.w, a1);
            }
            if (is_tok) Vb[s * VSTR + d] = a0 + a1;
        }
        // --- Q projection (scaled), packed to half2 for fdot2 ---
        float q0[32];
        #pragma unroll 4
        for (int d = 0; d < 32; ++d) {
            const float* wr = wiL + d * 32;
            float a0 = bib[d], a1 = 0.f;
            #pragma unroll
            for (int c2 = 0; c2 < 4; ++c2) {
                float4 wq = *(const float4*)&wr[4 * c2];
                a0 = fmaf(xn[4 * c2],     wq.x, a0);
                a0 = fmaf(xn[4 * c2 + 1], wq.y, a0);
                a0 = fmaf(xn[4 * c2 + 2], wq.z, a0);
                a0 = fmaf(xn[4 * c2 + 3], wq.w, a0);
            }
            #pragma unroll
            for (int c2 = 4; c2 < 8; ++c2) {
                float4 wq = *(const float4*)&wr[4 * c2];
                a1 = fmaf(xn[4 * c2],     wq.x, a1);
                a1 = fmaf(xn[4 * c2 + 1], wq.y, a1);
                a1 = fmaf(xn[4 * c2 + 2], wq.z, a1);
                a1 = fmaf(xn[4 * c2 + 3], wq.w, a1);
            }
            q0[d] = (a0 + a1) * 0.25f;
        }
        h2 qh[16];
        #pragma unroll
        for (int i = 0; i < 16; ++i) {
            h2 hh; hh[0] = (half_t)q0[2 * i]; hh[1] = (half_t)q0[2 * i + 1];
            qh[i] = hh;
        }

        // wave-local fence: own K/V ds_writes visible before broadcast reads
        __asm__ volatile("s_waitcnt lgkmcnt(0)" ::: "memory");

        // --- attention: 2 heads of 16 dims, softmax without running max ---
        float o[32];
        #pragma unroll
        for (int d = 0; d < 32; ++d) o[d] = 0.f;
        float l0 = 0.f, l1 = 0.f;
        union H4 { double qd; h2 p[2]; };
        for (int j = 0; j < 49; ++j) {
            const double* kr = (const double*)(Kb + j * KSTR);
            const float* vr = Vb + j * VSTR;
            H4 u0, u1, u2, u3, w0, w1h, w2h, w3;
            u0.qd = kr[0]; u1.qd = kr[1]; u2.qd = kr[2]; u3.qd = kr[3];
            w0.qd = kr[4]; w1h.qd = kr[5]; w2h.qd = kr[6]; w3.qd = kr[7];
            float s0a = 0.f, s0b = 0.f, s1a = 0.f, s1b = 0.f;
            s0a = FDOT2(u0.p[0], qh[0], s0a); s0a = FDOT2(u0.p[1], qh[1], s0a);
            s0b = FDOT2(u1.p[0], qh[2], s0b); s0b = FDOT2(u1.p[1], qh[3], s0b);
            s0a = FDOT2(u2.p[0], qh[4], s0a); s0a = FDOT2(u2.p[1], qh[5], s0a);
            s0b = FDOT2(u3.p[0], qh[6], s0b); s0b = FDOT2(u3.p[1], qh[7], s0b);
            s1a = FDOT2(w0.p[0], qh[8], s1a); s1a = FDOT2(w0.p[1], qh[9], s1a);
            s1b = FDOT2(w1h.p[0], qh[10], s1b); s1b = FDOT2(w1h.p[1], qh[11], s1b);
            s1a = FDOT2(w2h.p[0], qh[12], s1a); s1a = FDOT2(w2h.p[1], qh[13], s1a);
            s1b = FDOT2(w3.p[0], qh[14], s1b); s1b = FDOT2(w3.p[1], qh[15], s1b);
            float p0 = __expf(s0a + s0b), p1 = __expf(s1a + s1b);
            l0 += p0; l1 += p1;
            #pragma unroll
            for (int i = 0; i < 8; ++i) {
                float2 va = *(const float2*)&vr[2 * i];
                o[2 * i]     = fmaf(p0, va.x, o[2 * i]);
                o[2 * i + 1] = fmaf(p0, va.y, o[2 * i + 1]);
                float2 vc = *(const float2*)&vr[16 + 2 * i];
                o[16 + 2 * i]     = fmaf(p1, vc.x, o[16 + 2 * i]);
                o[16 + 2 * i + 1] = fmaf(p1, vc.y, o[16 + 2 * i + 1]);
            }
        }
        float il0 = 1.f / l0, il1 = 1.f / l1;
        #pragma unroll
        for (int d = 0; d < 16; ++d) { o[d] *= il0; o[16 + d] *= il1; }

        // --- out projection + residual (wave-uniform global weights, 4 KB) ---
        #pragma unroll
        for (int c = 0; c < 32; ++c) {
            const float* wr = wo + blk * 1024 + c * 32;
            float a = bo[blk * 32 + c];
            #pragma unroll
            for (int k2 = 0; k2 < 32; ++k2) a = fmaf(o[k2], wr[k2], a);
            t[c] += a;
        }

        // --- LN2 ---
        mu = 0.f;
        #pragma unroll
        for (int c = 0; c < 32; ++c) mu += t[c];
        mu *= 0.03125f;
        var = 0.f;
        #pragma unroll
        for (int c = 0; c < 32; ++c) { float d = t[c] - mu; var = fmaf(d, d, var); }
        rstd = rsqrtf(var * 0.03125f + 1e-5f);
        #pragma unroll
        for (int c = 0; c < 32; ++c)
            xn[c] = (t[c] - mu) * rstd * ln2g[blk * 32 + c] + ln2b[blk * 32 + c];

        __syncthreads();   // (C) all waves done reading K/V + wi

        // --- stage FF weights (overlay over KV) + next blk's wi ---
        {
            const float4* src1 = (const float4*)(w1 + blk * 4096);
            const float4* src2 = (const float4*)(w2t + blk * 4096);
            float4* dst = (float4*)Lraw;
            for (int e = tid; e < 1024; e += 256) dst[e] = src1[e];
            for (int e = tid; e < 1024; e += 256) dst[1024 + e] = src2[e];
            if (blk == 0) {
                const float4* srcw = (const float4*)(wi + 3072);
                float4* dstw = (float4*)(Lraw + WI_OFF);
                for (int e = tid; e < 768; e += 256) dstw[e] = srcw[e];
            }
        }
        __syncthreads();   // (D) FF weights (and wi for blk1) visible

        // --- FF from LDS: broadcast ds_read_b128 rows ---
        const float* w2L = Lf + 4096;
        #pragma unroll 2
        for (int j = 0; j < 128; ++j) {
            const float* wr = Lf + j * 32;
            float ha = fb1[blk * 128 + j], hb = 0.f;
            #pragma unroll
            for (int c2 = 0; c2 < 4; ++c2) {
                float4 wq = *(const float4*)&wr[4 * c2];
                ha = fmaf(xn[4 * c2],     wq.x, ha);
                ha = fmaf(xn[4 * c2 + 1], wq.y, ha);
                ha = fmaf(xn[4 * c2 + 2], wq.z, ha);
                ha = fmaf(xn[4 * c2 + 3], wq.w, ha);
            }
            #pragma unroll
            for (int c2 = 4; c2 < 8; ++c2) {
                float4 wq = *(const float4*)&wr[4 * c2];
                hb = fmaf(xn[4 * c2],     wq.x, hb);
                hb = fmaf(xn[4 * c2 + 1], wq.y, hb);
                hb = fmaf(xn[4 * c2 + 2], wq.z, hb);
                hb = fmaf(xn[4 * c2 + 3], wq.w, hb);
            }
            float h = ha + hb;
            h = 0.5f * h * (1.f + erff(h * 0.7071067811865476f));
            const float* w2r = w2L + j * 32;
            #pragma unroll
            for (int c2 = 0; c2 < 8; ++c2) {
                float4 wq = *(const float4*)&w2r[4 * c2];
                t[4 * c2]     = fmaf(h, wq.x, t[4 * c2]);
                t[4 * c2 + 1] = fmaf(h, wq.y, t[4 * c2 + 1]);
                t[4 * c2 + 2] = fmaf(h, wq.z, t[4 * c2 + 2]);
                t[4 * c2 + 3] = fmaf(h, wq.w, t[4 * c2 + 3]);
            }
        }
        #pragma unroll
        for (int c = 0; c < 32; ++c) t[c] += fb2[blk * 32 + c];
    }

    if (is_tok) {
        float* op = tokens + (size_t)b * 1568 + s * 32;
        #pragma unroll
        for (int c = 0; c < 32; c += 4) {
            float4 vv = make_float4(t[c], t[c + 1], t[c + 2], t[c + 3]);
            *(float4*)&op[c] = vv;
        }
    }
}

// ---------------------------------------------------------------------------
// C[M,N] = A[M,K] @ B[N,K]^T (+bias, optional ReLU). 128x64 tile, BK=16,
// 8x4 microtile.
// ---------------------------------------------------------------------------
__global__ __launch_bounds__(256) void k_gemm(
    const float* __restrict__ A, const float* __restrict__ Bm,
    const float* __restrict__ bias, float* __restrict__ C,
    int M, int N, int K, int relu)
{
    __shared__ float As[16 * 132];
    __shared__ float Bs[16 * 68];
    const int n0 = blockIdx.x * 64, m0 = blockIdx.y * 128;
    const int tid = threadIdx.x;
    const int tx = tid & 15, ty = tid >> 4;
    const int lr = tid >> 1, lk = (tid & 1) * 8;
    const int br = tid >> 2, bk = (tid & 3) * 4;
    float acc[8][4] = {{0.f}};
    for (int k0 = 0; k0 < K; k0 += 16) {
        float4 av0 = *(const float4*)&A[(size_t)(m0 + lr) * K + k0 + lk];
        float4 av1 = *(const float4*)&A[(size_t)(m0 + lr) * K + k0 + lk + 4];
        float4 bv0 = *(const float4*)&Bm[(size_t)(n0 + br) * K + k0 + bk];
        As[(lk + 0) * 132 + lr] = av0.x;
        As[(lk + 1) * 132 + lr] = av0.y;
        As[(lk + 2) * 132 + lr] = av0.z;
        As[(lk + 3) * 132 + lr] = av0.w;
        As[(lk + 4) * 132 + lr] = av1.x;
        As[(lk + 5) * 132 + lr] = av1.y;
        As[(lk + 6) * 132 + lr] = av1.z;
        As[(lk + 7) * 132 + lr] = av1.w;
        Bs[(bk + 0) * 68 + br] = bv0.x;
        Bs[(bk + 1) * 68 + br] = bv0.y;
        Bs[(bk + 2) * 68 + br] = bv0.z;
        Bs[(bk + 3) * 68 + br] = bv0.w;
        __syncthreads();
        #pragma unroll
        for (int k = 0; k < 16; ++k) {
            float4 a0 = *(const float4*)&As[k * 132 + ty * 8];
            float4 a1 = *(const float4*)&As[k * 132 + ty * 8 + 4];
            float4 bv = *(const float4*)&Bs[k * 68 + tx * 4];
            float a8[8] = {a0.x, a0.y, a0.z, a0.w, a1.x, a1.y, a1.z, a1.w};
            float b4[4] = {bv.x, bv.y, bv.z, bv.w};
            #pragma unroll
            for (int i = 0; i < 8; ++i)
                #pragma unroll
                for (int j = 0; j < 4; ++j)
                    acc[i][j] = fmaf(a8[i], b4[j], acc[i][j]);
        }
        __syncthreads();
    }
    #pragma unroll
    for (int i = 0; i < 8; ++i) {
        int m = m0 + ty * 8 + i;
        #pragma unroll
        for (int j = 0; j < 4; ++j) {
            int n = n0 + tx * 4 + j;
            float v = acc[i][j] + (bias ? bias[n] : 0.f);
            if (relu) v = fmaxf(v, 0.f);
            C[(size_t)m * N + n] = v;
        }
    }
}

// ---------------------------------------------------------------------------
// Fuse dec (linear 256->3136) with convt1 (convT 64->32 k4 s2 p1).
// ---------------------------------------------------------------------------
__global__ __launch_bounds__(256) void k_fuse(
    const float* __restrict__ wt1, const float* __restrict__ upt1_b,
    const float* __restrict__ dec_w, const float* __restrict__ dec_b,
    float* __restrict__ Wf, float* __restrict__ bf)
{
    const int n = blockIdx.x;
    const int k = threadIdx.x;
    const int o = n / 196, p = n % 196, y = p / 14, x = p % 14;
    float acc = 0.f, bacc = 0.f;
    for (int ky = 0; ky < 4; ++ky) {
        int iyn = y + 1 - ky;
        if (iyn < 0 || (iyn & 1)) continue;
        int iy = iyn >> 1;
        if (iy > 6) continue;
        for (int kx = 0; kx < 4; ++kx) {
            int ixn = x + 1 - kx;
            if (ixn < 0 || (ixn & 1)) continue;
            int ix = ixn >> 1;
            if (ix > 6) continue;
            for (int c = 0; c < 64; ++c) {
                float w = wt1[((c * 32 + o) * 4 + ky) * 4 + kx];
                int row = c * 49 + iy * 7 + ix;
                acc  = fmaf(w, dec_w[(size_t)row * 256 + k], acc);
                bacc = fmaf(w, dec_b[row], bacc);
            }
        }
    }
    Wf[(size_t)n * 256 + k] = acc;
    if (k == 0) bf[n] = bacc + upt1_b[o];
}

// ---------------------------------------------------------------------------
__global__ __launch_bounds__(256) void k_mnorm(const float* __restrict__ mem, float* __restrict__ inv_norm)
{
    __shared__ float red[256];
    const int row = blockIdx.x, tid = threadIdx.x;
    float v = mem[(size_t)row * 256 + tid];
    red[tid] = v * v;
    __syncthreads();
    for (int s = 128; s > 0; s >>= 1) {
        if (tid < s) red[tid] += red[tid + s];
        __syncthreads();
    }
    if (tid == 0) inv_norm[row] = 1.f / fmaxf(sqrtf(red[0]), 1e-12f);
}

// ---------------------------------------------------------------------------
__global__ __launch_bounds__(256) void k_memread(
    const float* __restrict__ latent, const float* __restrict__ dots,
    const float* __restrict__ inv_mn, const float* __restrict__ mem,
    float* __restrict__ out)
{
    __shared__ float red[256];
    __shared__ int   redi[256];
    __shared__ float inv_x_s;
    const int b = blockIdx.x, tid = threadIdx.x;
    float lx = latent[(size_t)b * 256 + tid];
    red[tid] = lx * lx;
    __syncthreads();
    for (int s = 128; s > 0; s >>= 1) {
        if (tid < s) red[tid] += red[tid + s];
        __syncthreads();
    }
    if (tid == 0) inv_x_s = 1.f / fmaxf(sqrtf(red[0]), 1e-12f);
    __syncthreads();
    const float inv_x = inv_x_s;

    float vals[16];
    for (int j = 0; j < 16; ++j) {
        int m = tid + j * 256;
        vals[j] = dots[(size_t)b * 4096 + m] * inv_mn[m] * inv_x;
    }
    float tv[10]; int ti[10];
    for (int t = 0; t < 10; ++t) {
        float bv = -1e30f; int bidx = 0x7fffffff;
        for (int j = 0; j < 16; ++j) {
            int m = tid + j * 256;
            float v = vals[j];
            if (v > bv || (v == bv && m < bidx)) { bv = v; bidx = m; }
        }
        red[tid] = bv; redi[tid] = bidx;
        __syncthreads();
        for (int s = 128; s > 0; s >>= 1) {
            if (tid < s) {
                float v2 = red[tid + s]; int i2 = redi[tid + s];
                if (v2 > red[tid] || (v2 == red[tid] && i2 < redi[tid])) { red[tid] = v2; redi[tid] = i2; }
            }
            __syncthreads();
        }
        int sel = redi[0];
        tv[t] = red[0]; ti[t] = sel;
        if ((sel & 255) == tid) vals[sel >> 8] = -1e30f;
        __syncthreads();
    }
    float w[10], wsum = 0.f;
    for (int t = 0; t < 10; ++t) { w[t] = expf(tv[t] - tv[0]); wsum += w[t]; }
    float inv_ws = 1.f / wsum;
    float acc = 0.f;
    for (int t = 0; t < 10; ++t) acc += (w[t] * inv_ws) * mem[(size_t)ti[t] * 256 + tid];
    out[(size_t)b * 256 + tid] = acc;
}

// ---------------------------------------------------------------------------
// Weight repack.
//   pk2[c32][tap9][o32]      from c1_w   [32][32][3][3]
//   pk3[c32][q4][tap4][o16]  from upt2_w [32][16][4][4]
//   pk4[c16][tap9][o8]       from c2_w   [8][16][3][3]
//   pk5[blk2][j128][c32]     from blk_ff2_w [2][32][128]  (transpose)
// ---------------------------------------------------------------------------
__global__ __launch_bounds__(256) void k_pack(
    const float* __restrict__ wc1, const float* __restrict__ wt2,
    const float* __restrict__ wc2, const float* __restrict__ w2src,
    float* __restrict__ pk2, float* __restrict__ pk3,
    float* __restrict__ pk4, float* __restrict__ pk5)
{
    int i = blockIdx.x * 256 + threadIdx.x;
    if (i < 9216) {
        int o = i & 31, tap = (i >> 5) % 9, c = i / 288;
        pk2[i] = wc1[(o * 32 + c) * 9 + tap];
    }
    if (i < 8192) {
        int o = i & 15, t = (i >> 4) & 3, q = (i >> 6) & 3, c = i >> 8;
        int wy = t >> 1, wx = t & 1, py = q >> 1, px = q & 1;
        int ky = 3 - py - 2 * wy, kx = 3 - px - 2 * wx;
        pk3[i] = wt2[((c * 16 + o) * 4 + ky) * 4 + kx];
    }
    if (i < 1152) {
        int o = i & 7, tap = (i >> 3) % 9, c = i / 72;
        pk4[i] = wc2[(o * 16 + c) * 9 + tap];
    }
    if (i < 8192) {
        int c = i & 31, j = (i >> 5) & 127, bq = i >> 12;
        pk5[i] = w2src[bq * 4096 + c * 128 + j];
    }
}

// ---------------------------------------------------------------------------
// Conv2d 32->32 k3 p1, 14x14, ReLU. 2 samples/block.
// ---------------------------------------------------------------------------
__global__ __launch_bounds__(256) void k_conv1(
    const float* __restrict__ in, const float* __restrict__ pk2,
    const float* __restrict__ bias, float* __restrict__ out)
{
    __shared__ float P[8208];   // [s2][c16][16 rows][16 cols] + overread pad
    const int tid = threadIdx.x;
    const int wv = __builtin_amdgcn_readfirstlane(tid >> 6);
    const int og = wv & 1, s = wv >> 1;
    const int lane = tid & 63;
    const bool active = lane < 56;
    int row = lane >> 2, tx0 = (lane & 3) * 4;
    if (!active) { row = 0; tx0 = 0; }
    const size_t b = (size_t)blockIdx.x * 2 + s;

    float acc[4][16];
    #pragma unroll
    for (int i = 0; i < 4; ++i)
        #pragma unroll
        for (int o = 0; o < 16; ++o) acc[i][o] = 0.f;

    for (int cc = 0; cc < 32; cc += 16) {
        __syncthreads();
        for (int e = tid; e < 8208; e += 256) P[e] = 0.f;
        __syncthreads();
        for (int e = tid; e < 6272; e += 256) {
            int si = e / 3136, rem = e - si * 3136;
            int c = rem / 196, p = rem % 196;
            P[((si * 16 + c) * 16 + p / 14 + 1) * 16 + (p % 14 + 1)] =
                in[((size_t)(blockIdx.x * 2 + si) * 32 + cc + c) * 196 + p];
        }
        __syncthreads();
        for (int cl = 0; cl < 16; ++cl) {
            const float* Pb = &P[((s * 16 + cl) * 16 + row) * 16 + tx0];
            float rowb[3][8];
            #pragma unroll
            for (int ky = 0; ky < 3; ++ky) {
                float4 a = *(const float4*)&Pb[ky * 16];
                float4 bq = *(const float4*)&Pb[ky * 16 + 4];
                rowb[ky][0] = a.x; rowb[ky][1] = a.y; rowb[ky][2] = a.z; rowb[ky][3] = a.w;
                rowb[ky][4] = bq.x; rowb[ky][5] = bq.y; rowb[ky][6] = bq.z; rowb[ky][7] = bq.w;
            }
            const float* wbase = pk2 + (size_t)(cc + cl) * 288 + og * 16;
            #pragma unroll
            for (int ky = 0; ky < 3; ++ky) {
                #pragma unroll
                for (int kx = 0; kx < 3; ++kx) {
                    const float* wt = wbase + (ky * 3 + kx) * 32;
                    #pragma unroll
                    for (int o = 0; o < 16; ++o) {
                        float w = wt[o];
                        #pragma unroll
                        for (int i = 0; i < 4; ++i)
                            acc[i][o] = fmaf(rowb[ky][i + kx], w, acc[i][o]);
                    }
                }
            }
        }
    }
    if (active) {
        #pragma unroll
        for (int o = 0; o < 16; ++o) {
            int oo = og * 16 + o;
            float bo = bias[oo];
            #pragma unroll
            for (int i = 0; i < 4; ++i) {
                int xx = tx0 + i;
                if (xx < 14)
                    out[(b * 32 + oo) * 196 + row * 14 + xx] = fmaxf(acc[i][o] + bo, 0.f);
            }
        }
    }
}

// ---------------------------------------------------------------------------
// FUSED: ConvTranspose2d 32->16 k4 s2 p1 (14x14->28x28, ReLU)
//        + Conv2d 16->8 k3 p1 (ReLU) + Conv2d 8->1 k1. One sample/block.
// Two 8-channel groups keep LDS at 40960 B -> 4 blocks/CU.
// ---------------------------------------------------------------------------
__global__ __launch_bounds__(256) void k_convt23(
    const float* __restrict__ in, const float* __restrict__ pk3,
    const float* __restrict__ bt2, const float* __restrict__ pk4,
    const float* __restrict__ b2, const float* __restrict__ w3,
    const float* __restrict__ b3, float* __restrict__ out)
{
    __shared__ __align__(16) float P[10240];   // 40960 B
    const int b = blockIdx.x, tid = threadIdx.x;

    // ---- Phase 1: convt2 from input tile [c32][16r][20c] ----
    for (int e = tid; e < 10240; e += 256) P[e] = 0.f;
    __syncthreads();
    for (int e = tid; e < 6272; e += 256) {
        int c = e / 196, p = e % 196;
        P[c * 320 + (p / 14 + 1) * 20 + (p % 14 + 1)] = in[(size_t)b * 6272 + e];
    }
    __syncthreads();

    const int q  = __builtin_amdgcn_readfirstlane(tid >> 6);
    const int py = q >> 1, px = q & 1;
    const int lane = tid & 63;
    const bool active = lane < 56;
    int ty = lane >> 2, tx0 = (lane & 3) * 4;
    if (!active) { ty = 0; tx0 = 0; }
    const int rbase = ty + py;

    float acc[4][16];
    #pragma unroll
    for (int i = 0; i < 4; ++i)
        #pragma unroll
        for (int o = 0; o < 16; ++o) acc[i][o] = 0.f;

    for (int c = 0; c < 32; ++c) {
        const float* Pb = &P[c * 320 + rbase * 20 + tx0];
        float raw[2][8];
        #pragma unroll
        for (int r2 = 0; r2 < 2; ++r2) {
            float4 a = *(const float4*)&Pb[r2 * 20];
            float4 bq = *(const float4*)&Pb[r2 * 20 + 4];
            raw[r2][0] = a.x; raw[r2][1] = a.y; raw[r2][2] = a.z; raw[r2][3] = a.w;
            raw[r2][4] = bq.x; raw[r2][5] = bq.y; raw[r2][6] = bq.z; raw[r2][7] = bq.w;
        }
        float rs[2][5];
        #pragma unroll
        for (int r2 = 0; r2 < 2; ++r2)
            #pragma unroll
            for (int j = 0; j < 5; ++j) rs[r2][j] = px ? raw[r2][j + 1] : raw[r2][j];
        const float* wq = pk3 + (size_t)((c * 4 + q) * 4) * 16;
        #pragma unroll
        for (int t = 0; t < 4; ++t) {
            int wy = t >> 1, wx = t & 1;
            const float* wt = wq + t * 16;
            #pragma unroll
            for (int o = 0; o < 16; ++o) {
                float w = wt[o];
                #pragma unroll
                for (int i = 0; i < 4; ++i)
                    acc[i][o] = fmaf(rs[wy][i + wx], w, acc[i][o]);
            }
        }
    }
    __syncthreads();   // all input-tile reads done; P reusable

    // ---- Phases 2+3 per 8-channel group ----
    const bool active2 = tid < 196;
    int row = active2 ? tid / 7 : 0;
    int tx0b = active2 ? (tid % 7) * 4 : 0;
    const int y = 2 * ty + py;

    float acc2[4][8];
    #pragma unroll
    for (int i = 0; i < 4; ++i)
        #pragma unroll
        for (int o = 0; o < 8; ++o) acc2[i][o] = 0.f;

    #pragma unroll
    for (int g = 0; g < 2; ++g) {
        for (int e = tid; e < 7680; e += 256) P[e] = 0.f;
        __syncthreads();
        if (active) {
            #pragma unroll
            for (int o8 = 0; o8 < 8; ++o8) {
                int o = g * 8 + o8;
                float bo = bt2[o];
                #pragma unroll
                for (int i = 0; i < 4; ++i) {
                    int xt = tx0 + i;
                    if (xt < 14)
                        P[(o8 * 30 + y + 1) * 32 + (2 * xt + px + 1)] = fmaxf(acc[i][o] + bo, 0.f);
                }
            }
        }
        __syncthreads();
        for (int cl = 0; cl < 8; ++cl) {
            const float* Pb = &P[(cl * 30 + row) * 32 + tx0b];
            const float* wb = pk4 + (size_t)(g * 8 + cl) * 72;
            #pragma unroll
            for (int ky = 0; ky < 3; ++ky) {
                float4 a = *(const float4*)&Pb[ky * 32];
                float4 bq = *(const float4*)&Pb[ky * 32 + 4];
                float rowb[8] = {a.x, a.y, a.z, a.w, bq.x, bq.y, bq.z, bq.w};
                #pragma unroll
                for (int kx = 0; kx < 3; ++kx) {
                    const float* wt = wb + (ky * 3 + kx) * 8;
                    #pragma unroll
                    for (int o = 0; o < 8; ++o) {
                        float w = wt[o];
                        #pragma unroll
                        for (int i = 0; i < 4; ++i)
                            acc2[i][o] = fmaf(rowb[i + kx], w, acc2[i][o]);
                    }
                }
            }
        }
        __syncthreads();   // group tile fully consumed before next zero-fill
    }

    // ---- conv3 (8->1, k1) + store ----
    if (active2) {
        const float bias3 = b3[0];
        #pragma unroll
        for (int i = 0; i < 4; ++i) {
            float r = bias3;
            #pragma unroll
            for (int o = 0; o < 8; ++o) r += fmaxf(acc2[i][o] + b2[o], 0.f) * w3[o];
            out[(size_t)b * 784 + row * 28 + tx0b + i] = r;
        }
    }
}

// ---------------------------------------------------------------------------
extern "C" void kernel_launch(void* const* d_in, const int* in_sizes, int n_in,
                              void* d_out, int out_size, void* d_ws, size_t ws_size,
                              hipStream_t stream)
{
    const float* x       = (const float*)d_in[0];
    const float* patch_w = (const float*)d_in[1];
    const float* patch_b = (const float*)d_in[2];
    const float* ln1g    = (const float*)d_in[3];
    const float* ln1b    = (const float*)d_in[4];
    const float* wi      = (const float*)d_in[5];
    const float* bi      = (const float*)d_in[6];
    const float* wo      = (const float*)d_in[7];
    const float* bo      = (const float*)d_in[8];
    const float* ln2g    = (const float*)d_in[9];
    const float* ln2b    = (const float*)d_in[10];
    const float* w1      = (const float*)d_in[11];
    const float* b1      = (const float*)d_in[12];
    const float* w2      = (const float*)d_in[13];
    const float* b2      = (const float*)d_in[14];
    const float* lat_w   = (const float*)d_in[15];
    const float* lat_b   = (const float*)d_in[16];
    const float* memory  = (const float*)d_in[17];
    const float* dec_w   = (const float*)d_in[18];
    const float* dec_b   = (const float*)d_in[19];
    const float* upt1_w  = (const float*)d_in[20];
    const float* upt1_b  = (const float*)d_in[21];
    const float* c1_w    = (const float*)d_in[22];
    const float* c1_b    = (const float*)d_in[23];
    const float* upt2_w  = (const float*)d_in[24];
    const float* upt2_b  = (const float*)d_in[25];
    const float* c2_w    = (const float*)d_in[26];
    const float* c2_b    = (const float*)d_in[27];
    const float* c3_w    = (const float*)d_in[28];
    const float* c3_b    = (const float*)d_in[29];
    float* outp = (float*)d_out;

    float* ws = (float*)d_ws;
    size_t off = 0;
    auto alloc = [&](size_t n) { float* p = ws + off; off += (n + 63) & ~(size_t)63; return p; };
    float* tokens     = alloc((size_t)B_TOT * 1568);
    float* latent     = alloc((size_t)B_TOT * 256);
    float* dots       = alloc((size_t)B_TOT * 4096);
    float* mem_latent = alloc((size_t)B_TOT * 256);
    float* inv_mn     = alloc(4096);
    float* pk2        = alloc(9216);
    float* pk3        = alloc(8192);
    float* pk4        = alloc(1152);
    float* pk5        = alloc(8192);
    float* Wf         = alloc((size_t)6272 * 256);
    float* bf         = alloc(6272);
    float* d1         = alloc((size_t)CHUNK * 6272);
    float* d2         = alloc((size_t)CHUNK * 6272);
    (void)in_sizes; (void)n_in; (void)out_size; (void)ws_size;

    // Weight repack + dec/convt1 algebraic fusion
    k_pack<<<36, 256, 0, stream>>>(c1_w, upt2_w, c2_w, w2, pk2, pk3, pk4, pk5);
    k_fuse<<<6272, 256, 0, stream>>>(upt1_w, upt1_b, dec_w, dec_b, Wf, bf);

    // Encoder (wave-per-sample)
    k_tokens<<<B_TOT / 4, 256, 0, stream>>>(x, patch_w, patch_b, ln1g, ln1b, wi, bi,
                                            wo, bo, ln2g, ln2b, w1, b1, pk5, b2, tokens);
    k_gemm<<<dim3(256 / 64, B_TOT / 128), 256, 0, stream>>>(tokens, lat_w, lat_b, latent,
                                                            B_TOT, 256, 1568, 0);
    k_mnorm<<<4096, 256, 0, stream>>>(memory, inv_mn);
    k_gemm<<<dim3(4096 / 64, B_TOT / 128), 256, 0, stream>>>(latent, memory, nullptr, dots,
                                                             B_TOT, 4096, 256, 0);
    k_memread<<<B_TOT, 256, 0, stream>>>(latent, dots, inv_mn, memory, mem_latent);

    // Decoder, chunked over batch. Fused dec+convt1 GEMM -> d1; conv1 -> d2;
    // fused convt2+conv2+conv3 -> output (no d3 round-trip).
    for (int c = 0; c < B_TOT / CHUNK; ++c) {
        const float* ml = mem_latent + (size_t)c * CHUNK * 256;
        k_gemm<<<dim3(6272 / 64, CHUNK / 128), 256, 0, stream>>>(ml, Wf, bf, d1,
                                                                 CHUNK, 6272, 256, 1);
        k_conv1  <<<CHUNK / 2, 256, 0, stream>>>(d1, pk2, c1_b, d2);
        k_convt23<<<CHUNK, 256, 0, stream>>>(d2, pk3, upt2_b, pk4, c2_b, c3_w, c3_b,
                                             outp + (size_t)c * CHUNK * 784);
    }
}

// Round 10
// 1643.499 us; speedup vs baseline: 1.1401x; 1.0794x over previous
//
#include <hip/hip_runtime.h>
#include <math.h>

#define B_TOT 4096
#define CHUNK 1024

typedef _Float16 half_t;
typedef _Float16 h2 __attribute__((ext_vector_type(2)));
typedef _Float16 h8v __attribute__((ext_vector_type(8)));
typedef float f4v __attribute__((ext_vector_type(4)));

#if __has_builtin(__builtin_amdgcn_fdot2)
#define FDOT2(a, b, c) __builtin_amdgcn_fdot2((a), (b), (c), false)
#else
#define FDOT2(a, b, c) fmaf((float)(a)[1], (float)(b)[1], fmaf((float)(a)[0], (float)(b)[0], (c)))
#endif

// Per-wave LDS: K 49x36 halves (72B rows, fp16), V 49x34 floats (136B rows, fp32).
// Block: 4 waves KV (40768) + wi stage slot (12288) = 53056 B -> 3 blocks/CU.
// V stays fp32 (round-4: fp16 V broke topk selection).
// Decoder GEMM uses fp16 MFMA (round-8 validated fp16-level rounding there).
#define KSTR 36          // halves per K row
#define VSTR 34          // floats per V row
#define KBYTES (49 * 72)
#define WAVE_LDS (49 * 72 + 49 * 136)  // 10192
#define WI_OFF  (4 * WAVE_LDS)         // 40768
#define BLOCK_LDS (WI_OFF + 12288)     // 53056

// ---------------------------------------------------------------------------
// Fused: patch conv (1->32, k4 s4) + 2 transformer blocks.
// ---------------------------------------------------------------------------
__global__ __launch_bounds__(256) void k_tokens(
    const float* __restrict__ x, const float* __restrict__ pw, const float* __restrict__ pb,
    const float* __restrict__ ln1g, const float* __restrict__ ln1b,
    const float* __restrict__ wi, const float* __restrict__ bi,
    const float* __restrict__ wo, const float* __restrict__ bo,
    const float* __restrict__ ln2g, const float* __restrict__ ln2b,
    const float* __restrict__ w1, const float* __restrict__ fb1,
    const float* __restrict__ w2t, const float* __restrict__ fb2,
    float* __restrict__ tokens)
{
    __shared__ __align__(16) unsigned char Lraw[BLOCK_LDS];
    const int tid = threadIdx.x;
    const int wv = tid >> 6, lane = tid & 63;
    const int b = blockIdx.x * 4 + wv;
    half_t* Kb = (half_t*)(Lraw + wv * WAVE_LDS);
    float*  Vb = (float*)(Lraw + wv * WAVE_LDS + KBYTES);
    const float* wiL = (const float*)(Lraw + WI_OFF);
    float* Lf = (float*)Lraw;            // FF-weight overlay (block-wide)
    const bool is_tok = lane < 49;
    const int s = is_tok ? lane : 48;
    const int py = s / 7, px = s % 7;

    // --- prologue: stage blk-0 qkv weights (visible after barrier (A)) ---
    {
        const float4* srcw = (const float4*)(wi);
        float4* dstw = (float4*)(Lraw + WI_OFF);
        for (int e = tid; e < 768; e += 256) dstw[e] = srcw[e];
    }

    // --- patch conv: direct float4 loads (rows are 16B-aligned) ---
    float xv[16];
    const float* xb = x + (size_t)b * 784 + py * 112 + px * 4;
    #pragma unroll
    for (int r = 0; r < 4; ++r) {
        float4 vq = *(const float4*)(xb + r * 28);
        xv[4 * r + 0] = vq.x; xv[4 * r + 1] = vq.y;
        xv[4 * r + 2] = vq.z; xv[4 * r + 3] = vq.w;
    }
    float t[32];
    #pragma unroll 4
    for (int c = 0; c < 32; ++c) {
        float a = pb[c];
        const float* wr = pw + c * 16;
        #pragma unroll
        for (int i = 0; i < 16; ++i) a = fmaf(xv[i], wr[i], a);
        t[c] = a;
    }

    for (int blk = 0; blk < 2; ++blk) {
        const float* bib = bi + blk * 96;

        // --- LN1 ---
        float mu = 0.f;
        #pragma unroll
        for (int c = 0; c < 32; ++c) mu += t[c];
        mu *= 0.03125f;
        float var = 0.f;
        #pragma unroll
        for (int c = 0; c < 32; ++c) { float d = t[c] - mu; var = fmaf(d, d, var); }
        float rstd = rsqrtf(var * 0.03125f + 1e-5f);
        float xn[32];
        #pragma unroll
        for (int c = 0; c < 32; ++c)
            xn[c] = (t[c] - mu) * rstd * ln1g[blk * 32 + c] + ln1b[blk * 32 + c];

        __syncthreads();   // (A) prior-phase LDS reads done; wi stage visible

        // --- K projection -> LDS fp16 (broadcast b128 weight reads) ---
        #pragma unroll 4
        for (int d = 0; d < 32; ++d) {
            const float* wr = wiL + (32 + d) * 32;
            float a0 = bib[32 + d], a1 = 0.f;
            #pragma unroll
            for (int c2 = 0; c2 < 4; ++c2) {
                float4 wq = *(const float4*)&wr[4 * c2];
                a0 = fmaf(xn[4 * c2],     wq.x, a0);
                a0 = fmaf(xn[4 * c2 + 1], wq.y, a0);
                a0 = fmaf(xn[4 * c2 + 2], wq.z, a0);
                a0 = fmaf(xn[4 * c2 + 3], wq.w, a0);
            }
            #pragma unroll
            for (int c2 = 4; c2 < 8; ++c2) {
                float4 wq = *(const float4*)&wr[4 * c2];
                a1 = fmaf(xn[4 * c2],     wq.x, a1);
                a1 = fmaf(xn[4 * c2 + 1], wq.y, a1);
                a1 = fmaf(xn[4 * c2 + 2], wq.z, a1);
                a1 = fmaf(xn[4 * c2 + 3], wq.w, a1);
            }
            if (is_tok) Kb[s * KSTR + d] = (half_t)(a0 + a1);
        }
        // --- V projection -> LDS fp32 ---
        #pragma unroll 4
        for (int d = 0; d < 32; ++d) {
            const float* wr = wiL + (64 + d) * 32;
            float a0 = bib[64 + d], a1 = 0.f;
            #pragma unroll
            for (int c2 = 0; c2 < 4; ++c2) {
                float4 wq = *(const float4*)&wr[4 * c2];
                a0 = fmaf(xn[4 * c2],     wq.x, a0);
                a0 = fmaf(xn[4 * c2 + 1], wq.y, a0);
                a0 = fmaf(xn[4 * c2 + 2], wq.z, a0);
                a0 = fmaf(xn[4 * c2 + 3], wq.w, a0);
            }
            #pragma unroll
            for (int c2 = 4; c2 < 8; ++c2) {
                float4 wq = *(const float4*)&wr[4 * c2];
                a1 = fmaf(xn[4 * c2],     wq.x, a1);
                a1 = fmaf(xn[4 * c2 + 1], wq.y, a1);
                a1 = fmaf(xn[4 * c2 + 2], wq.z, a1);
                a1 = fmaf(xn[4 * c2 + 3], wq.w, a1);
            }
            if (is_tok) Vb[s * VSTR + d] = a0 + a1;
        }
        // --- Q projection (scaled), packed to half2 for fdot2 ---
        float q0[32];
        #pragma unroll 4
        for (int d = 0; d < 32; ++d) {
            const float* wr = wiL + d * 32;
            float a0 = bib[d], a1 = 0.f;
            #pragma unroll
            for (int c2 = 0; c2 < 4; ++c2) {
                float4 wq = *(const float4*)&wr[4 * c2];
                a0 = fmaf(xn[4 * c2],     wq.x, a0);
                a0 = fmaf(xn[4 * c2 + 1], wq.y, a0);
                a0 = fmaf(xn[4 * c2 + 2], wq.z, a0);
                a0 = fmaf(xn[4 * c2 + 3], wq.w, a0);
            }
            #pragma unroll
            for (int c2 = 4; c2 < 8; ++c2) {
                float4 wq = *(const float4*)&wr[4 * c2];
                a1 = fmaf(xn[4 * c2],     wq.x, a1);
                a1 = fmaf(xn[4 * c2 + 1], wq.y, a1);
                a1 = fmaf(xn[4 * c2 + 2], wq.z, a1);
                a1 = fmaf(xn[4 * c2 + 3], wq.w, a1);
            }
            q0[d] = (a0 + a1) * 0.25f;
        }
        h2 qh[16];
        #pragma unroll
        for (int i = 0; i < 16; ++i) {
            h2 hh; hh[0] = (half_t)q0[2 * i]; hh[1] = (half_t)q0[2 * i + 1];
            qh[i] = hh;
        }

        // wave-local fence: own K/V ds_writes visible before broadcast reads
        __asm__ volatile("s_waitcnt lgkmcnt(0)" ::: "memory");

        // --- attention: 2 heads of 16 dims, softmax without running max ---
        float o[32];
        #pragma unroll
        for (int d = 0; d < 32; ++d) o[d] = 0.f;
        float l0 = 0.f, l1 = 0.f;
        union H4 { double qd; h2 p[2]; };
        for (int j = 0; j < 49; ++j) {
            const double* kr = (const double*)(Kb + j * KSTR);
            const float* vr = Vb + j * VSTR;
            H4 u0, u1, u2, u3, w0, w1h, w2h, w3;
            u0.qd = kr[0]; u1.qd = kr[1]; u2.qd = kr[2]; u3.qd = kr[3];
            w0.qd = kr[4]; w1h.qd = kr[5]; w2h.qd = kr[6]; w3.qd = kr[7];
            float s0a = 0.f, s0b = 0.f, s1a = 0.f, s1b = 0.f;
            s0a = FDOT2(u0.p[0], qh[0], s0a); s0a = FDOT2(u0.p[1], qh[1], s0a);
            s0b = FDOT2(u1.p[0], qh[2], s0b); s0b = FDOT2(u1.p[1], qh[3], s0b);
            s0a = FDOT2(u2.p[0], qh[4], s0a); s0a = FDOT2(u2.p[1], qh[5], s0a);
            s0b = FDOT2(u3.p[0], qh[6], s0b); s0b = FDOT2(u3.p[1], qh[7], s0b);
            s1a = FDOT2(w0.p[0], qh[8], s1a); s1a = FDOT2(w0.p[1], qh[9], s1a);
            s1b = FDOT2(w1h.p[0], qh[10], s1b); s1b = FDOT2(w1h.p[1], qh[11], s1b);
            s1a = FDOT2(w2h.p[0], qh[12], s1a); s1a = FDOT2(w2h.p[1], qh[13], s1a);
            s1b = FDOT2(w3.p[0], qh[14], s1b); s1b = FDOT2(w3.p[1], qh[15], s1b);
            float p0 = __expf(s0a + s0b), p1 = __expf(s1a + s1b);
            l0 += p0; l1 += p1;
            #pragma unroll
            for (int i = 0; i < 8; ++i) {
                float2 va = *(const float2*)&vr[2 * i];
                o[2 * i]     = fmaf(p0, va.x, o[2 * i]);
                o[2 * i + 1] = fmaf(p0, va.y, o[2 * i + 1]);
                float2 vc = *(const float2*)&vr[16 + 2 * i];
                o[16 + 2 * i]     = fmaf(p1, vc.x, o[16 + 2 * i]);
                o[16 + 2 * i + 1] = fmaf(p1, vc.y, o[16 + 2 * i + 1]);
            }
        }
        float il0 = 1.f / l0, il1 = 1.f / l1;
        #pragma unroll
        for (int d = 0; d < 16; ++d) { o[d] *= il0; o[16 + d] *= il1; }

        // --- out projection + residual (wave-uniform global weights, 4 KB) ---
        #pragma unroll
        for (int c = 0; c < 32; ++c) {
            const float* wr = wo + blk * 1024 + c * 32;
            float a = bo[blk * 32 + c];
            #pragma unroll
            for (int k2 = 0; k2 < 32; ++k2) a = fmaf(o[k2], wr[k2], a);
            t[c] += a;
        }

        // --- LN2 ---
        mu = 0.f;
        #pragma unroll
        for (int c = 0; c < 32; ++c) mu += t[c];
        mu *= 0.03125f;
        var = 0.f;
        #pragma unroll
        for (int c = 0; c < 32; ++c) { float d = t[c] - mu; var = fmaf(d, d, var); }
        rstd = rsqrtf(var * 0.03125f + 1e-5f);
        #pragma unroll
        for (int c = 0; c < 32; ++c)
            xn[c] = (t[c] - mu) * rstd * ln2g[blk * 32 + c] + ln2b[blk * 32 + c];

        __syncthreads();   // (C) all waves done reading K/V + wi

        // --- stage FF weights (overlay over KV) + next blk's wi ---
        {
            const float4* src1 = (const float4*)(w1 + blk * 4096);
            const float4* src2 = (const float4*)(w2t + blk * 4096);
            float4* dst = (float4*)Lraw;
            for (int e = tid; e < 1024; e += 256) dst[e] = src1[e];
            for (int e = tid; e < 1024; e += 256) dst[1024 + e] = src2[e];
            if (blk == 0) {
                const float4* srcw = (const float4*)(wi + 3072);
                float4* dstw = (float4*)(Lraw + WI_OFF);
                for (int e = tid; e < 768; e += 256) dstw[e] = srcw[e];
            }
        }
        __syncthreads();   // (D) FF weights (and wi for blk1) visible

        // --- FF from LDS: broadcast ds_read_b128 rows ---
        const float* w2L = Lf + 4096;
        #pragma unroll 2
        for (int j = 0; j < 128; ++j) {
            const float* wr = Lf + j * 32;
            float ha = fb1[blk * 128 + j], hb = 0.f;
            #pragma unroll
            for (int c2 = 0; c2 < 4; ++c2) {
                float4 wq = *(const float4*)&wr[4 * c2];
                ha = fmaf(xn[4 * c2],     wq.x, ha);
                ha = fmaf(xn[4 * c2 + 1], wq.y, ha);
                ha = fmaf(xn[4 * c2 + 2], wq.z, ha);
                ha = fmaf(xn[4 * c2 + 3], wq.w, ha);
            }
            #pragma unroll
            for (int c2 = 4; c2 < 8; ++c2) {
                float4 wq = *(const float4*)&wr[4 * c2];
                hb = fmaf(xn[4 * c2],     wq.x, hb);
                hb = fmaf(xn[4 * c2 + 1], wq.y, hb);
                hb = fmaf(xn[4 * c2 + 2], wq.z, hb);
                hb = fmaf(xn[4 * c2 + 3], wq.w, hb);
            }
            float h = ha + hb;
            h = 0.5f * h * (1.f + erff(h * 0.7071067811865476f));
            const float* w2r = w2L + j * 32;
            #pragma unroll
            for (int c2 = 0; c2 < 8; ++c2) {
                float4 wq = *(const float4*)&w2r[4 * c2];
                t[4 * c2]     = fmaf(h, wq.x, t[4 * c2]);
                t[4 * c2 + 1] = fmaf(h, wq.y, t[4 * c2 + 1]);
                t[4 * c2 + 2] = fmaf(h, wq.z, t[4 * c2 + 2]);
                t[4 * c2 + 3] = fmaf(h, wq.w, t[4 * c2 + 3]);
            }
        }
        #pragma unroll
        for (int c = 0; c < 32; ++c) t[c] += fb2[blk * 32 + c];
    }

    if (is_tok) {
        float* op = tokens + (size_t)b * 1568 + s * 32;
        #pragma unroll
        for (int c = 0; c < 32; c += 4) {
            float4 vv = make_float4(t[c], t[c + 1], t[c + 2], t[c + 3]);
            *(float4*)&op[c] = vv;
        }
    }
}

// ---------------------------------------------------------------------------
// C[M,N] = A[M,K] @ B[N,K]^T (+bias, optional ReLU). 128x64 tile, BK=16,
// 8x4 microtile. fp32 (used for the topk-upstream GEMMs).
// ---------------------------------------------------------------------------
__global__ __launch_bounds__(256) void k_gemm(
    const float* __restrict__ A, const float* __restrict__ Bm,
    const float* __restrict__ bias, float* __restrict__ C,
    int M, int N, int K, int relu)
{
    __shared__ float As[16 * 132];
    __shared__ float Bs[16 * 68];
    const int n0 = blockIdx.x * 64, m0 = blockIdx.y * 128;
    const int tid = threadIdx.x;
    const int tx = tid & 15, ty = tid >> 4;
    const int lr = tid >> 1, lk = (tid & 1) * 8;
    const int br = tid >> 2, bk = (tid & 3) * 4;
    float acc[8][4] = {{0.f}};
    for (int k0 = 0; k0 < K; k0 += 16) {
        float4 av0 = *(const float4*)&A[(size_t)(m0 + lr) * K + k0 + lk];
        float4 av1 = *(const float4*)&A[(size_t)(m0 + lr) * K + k0 + lk + 4];
        float4 bv0 = *(const float4*)&Bm[(size_t)(n0 + br) * K + k0 + bk];
        As[(lk + 0) * 132 + lr] = av0.x;
        As[(lk + 1) * 132 + lr] = av0.y;
        As[(lk + 2) * 132 + lr] = av0.z;
        As[(lk + 3) * 132 + lr] = av0.w;
        As[(lk + 4) * 132 + lr] = av1.x;
        As[(lk + 5) * 132 + lr] = av1.y;
        As[(lk + 6) * 132 + lr] = av1.z;
        As[(lk + 7) * 132 + lr] = av1.w;
        Bs[(bk + 0) * 68 + br] = bv0.x;
        Bs[(bk + 1) * 68 + br] = bv0.y;
        Bs[(bk + 2) * 68 + br] = bv0.z;
        Bs[(bk + 3) * 68 + br] = bv0.w;
        __syncthreads();
        #pragma unroll
        for (int k = 0; k < 16; ++k) {
            float4 a0 = *(const float4*)&As[k * 132 + ty * 8];
            float4 a1 = *(const float4*)&As[k * 132 + ty * 8 + 4];
            float4 bv = *(const float4*)&Bs[k * 68 + tx * 4];
            float a8[8] = {a0.x, a0.y, a0.z, a0.w, a1.x, a1.y, a1.z, a1.w};
            float b4[4] = {bv.x, bv.y, bv.z, bv.w};
            #pragma unroll
            for (int i = 0; i < 8; ++i)
                #pragma unroll
                for (int j = 0; j < 4; ++j)
                    acc[i][j] = fmaf(a8[i], b4[j], acc[i][j]);
        }
        __syncthreads();
    }
    #pragma unroll
    for (int i = 0; i < 8; ++i) {
        int m = m0 + ty * 8 + i;
        #pragma unroll
        for (int j = 0; j < 4; ++j) {
            int n = n0 + tx * 4 + j;
            float v = acc[i][j] + (bias ? bias[n] : 0.f);
            if (relu) v = fmaxf(v, 0.f);
            C[(size_t)m * N + n] = v;
        }
    }
}

// ---------------------------------------------------------------------------
// MFMA decoder GEMM: C[M,N] = relu(A[M,K] @ B[N,K]^T + bias), fp16 MFMA
// 16x16x32 with fp32 accum. A,B fp32 in global, converted during LDS staging
// (only fp16 rounding sources are the two MFMA inputs — round-8 validated
// fp16-level rounding at this point of the graph). Block tile 64(M)x128(N),
// 4 waves of 32x64, LDS rows padded to 40 halves (80 B: 16B-aligned b128
// frags, bank-rotating). Downstream of topk ONLY — latent/dots stay fp32.
// ---------------------------------------------------------------------------
__global__ __launch_bounds__(256) void k_dgemm(
    const float* __restrict__ A, const float* __restrict__ Bm,
    const float* __restrict__ bias, float* __restrict__ C,
    int M, int N, int K)
{
    __shared__ __align__(16) half_t As[64 * 40];
    __shared__ __align__(16) half_t Bs[128 * 40];
    const int tid = threadIdx.x;
    const int n0 = blockIdx.x * 128, m0 = blockIdx.y * 64;
    const int w = tid >> 6, lane = tid & 63;
    const int wm = (w >> 1) * 32, wn = (w & 1) * 64;
    const int lr = lane & 15, lk = lane >> 4;

    const int ar = tid >> 2, aseg = (tid & 3) * 8;   // A stage: 64 rows x 32 k
    const int br = tid >> 1, bseg = (tid & 1) * 16;  // B stage: 128 rows x 32 k

    f4v acc[2][4];
    #pragma unroll
    for (int i = 0; i < 2; ++i)
        #pragma unroll
        for (int j = 0; j < 4; ++j) acc[i][j] = (f4v){0.f, 0.f, 0.f, 0.f};

    for (int k0 = 0; k0 < K; k0 += 32) {
        {
            const float* ap = A + (size_t)(m0 + ar) * K + k0 + aseg;
            float4 a0 = *(const float4*)ap;
            float4 a1 = *(const float4*)(ap + 4);
            h8v ha;
            ha[0] = (half_t)a0.x; ha[1] = (half_t)a0.y;
            ha[2] = (half_t)a0.z; ha[3] = (half_t)a0.w;
            ha[4] = (half_t)a1.x; ha[5] = (half_t)a1.y;
            ha[6] = (half_t)a1.z; ha[7] = (half_t)a1.w;
            *(h8v*)&As[ar * 40 + aseg] = ha;

            const float* bp = Bm + (size_t)(n0 + br) * K + k0 + bseg;
            float4 b0 = *(const float4*)bp;
            float4 b1 = *(const float4*)(bp + 4);
            float4 b2 = *(const float4*)(bp + 8);
            float4 b3 = *(const float4*)(bp + 12);
            h8v hb0, hb1;
            hb0[0] = (half_t)b0.x; hb0[1] = (half_t)b0.y;
            hb0[2] = (half_t)b0.z; hb0[3] = (half_t)b0.w;
            hb0[4] = (half_t)b1.x; hb0[5] = (half_t)b1.y;
            hb0[6] = (half_t)b1.z; hb0[7] = (half_t)b1.w;
            hb1[0] = (half_t)b2.x; hb1[1] = (half_t)b2.y;
            hb1[2] = (half_t)b2.z; hb1[3] = (half_t)b2.w;
            hb1[4] = (half_t)b3.x; hb1[5] = (half_t)b3.y;
            hb1[6] = (half_t)b3.z; hb1[7] = (half_t)b3.w;
            *(h8v*)&Bs[br * 40 + bseg] = hb0;
            *(h8v*)&Bs[br * 40 + bseg + 8] = hb1;
        }
        __syncthreads();
        h8v af[2], bfr[4];
        #pragma unroll
        for (int i = 0; i < 2; ++i)
            af[i] = *(const h8v*)&As[(wm + i * 16 + lr) * 40 + lk * 8];
        #pragma unroll
        for (int j = 0; j < 4; ++j)
            bfr[j] = *(const h8v*)&Bs[(wn + j * 16 + lr) * 40 + lk * 8];
        #pragma unroll
        for (int i = 0; i < 2; ++i)
            #pragma unroll
            for (int j = 0; j < 4; ++j)
                acc[i][j] = __builtin_amdgcn_mfma_f32_16x16x32_f16(af[i], bfr[j], acc[i][j], 0, 0, 0);
        __syncthreads();
    }

    // Epilogue: C/D layout col=lane&15, row=(lane>>4)*4+reg (guide-verified).
    #pragma unroll
    for (int j = 0; j < 4; ++j) {
        int n = n0 + wn + j * 16 + lr;
        float bv = bias[n];
        #pragma unroll
        for (int i = 0; i < 2; ++i) {
            #pragma unroll
            for (int r = 0; r < 4; ++r) {
                int m = m0 + wm + i * 16 + lk * 4 + r;
                C[(size_t)m * N + n] = fmaxf(acc[i][j][r] + bv, 0.f);
            }
        }
    }
}

// ---------------------------------------------------------------------------
// Fuse dec (linear 256->3136) with convt1 (convT 64->32 k4 s2 p1).
// ---------------------------------------------------------------------------
__global__ __launch_bounds__(256) void k_fuse(
    const float* __restrict__ wt1, const float* __restrict__ upt1_b,
    const float* __restrict__ dec_w, const float* __restrict__ dec_b,
    float* __restrict__ Wf, float* __restrict__ bf)
{
    const int n = blockIdx.x;
    const int k = threadIdx.x;
    const int o = n / 196, p = n % 196, y = p / 14, x = p % 14;
    float acc = 0.f, bacc = 0.f;
    for (int ky = 0; ky < 4; ++ky) {
        int iyn = y + 1 - ky;
        if (iyn < 0 || (iyn & 1)) continue;
        int iy = iyn >> 1;
        if (iy > 6) continue;
        for (int kx = 0; kx < 4; ++kx) {
            int ixn = x + 1 - kx;
            if (ixn < 0 || (ixn & 1)) continue;
            int ix = ixn >> 1;
            if (ix > 6) continue;
            for (int c = 0; c < 64; ++c) {
                float w = wt1[((c * 32 + o) * 4 + ky) * 4 + kx];
                int row = c * 49 + iy * 7 + ix;
                acc  = fmaf(w, dec_w[(size_t)row * 256 + k], acc);
                bacc = fmaf(w, dec_b[row], bacc);
            }
        }
    }
    Wf[(size_t)n * 256 + k] = acc;
    if (k == 0) bf[n] = bacc + upt1_b[o];
}

// ---------------------------------------------------------------------------
__global__ __launch_bounds__(256) void k_mnorm(const float* __restrict__ mem, float* __restrict__ inv_norm)
{
    __shared__ float red[256];
    const int row = blockIdx.x, tid = threadIdx.x;
    float v = mem[(size_t)row * 256 + tid];
    red[tid] = v * v;
    __syncthreads();
    for (int s = 128; s > 0; s >>= 1) {
        if (tid < s) red[tid] += red[tid + s];
        __syncthreads();
    }
    if (tid == 0) inv_norm[row] = 1.f / fmaxf(sqrtf(red[0]), 1e-12f);
}

// ---------------------------------------------------------------------------
__global__ __launch_bounds__(256) void k_memread(
    const float* __restrict__ latent, const float* __restrict__ dots,
    const float* __restrict__ inv_mn, const float* __restrict__ mem,
    float* __restrict__ out)
{
    __shared__ float red[256];
    __shared__ int   redi[256];
    __shared__ float inv_x_s;
    const int b = blockIdx.x, tid = threadIdx.x;
    float lx = latent[(size_t)b * 256 + tid];
    red[tid] = lx * lx;
    __syncthreads();
    for (int s = 128; s > 0; s >>= 1) {
        if (tid < s) red[tid] += red[tid + s];
        __syncthreads();
    }
    if (tid == 0) inv_x_s = 1.f / fmaxf(sqrtf(red[0]), 1e-12f);
    __syncthreads();
    const float inv_x = inv_x_s;

    float vals[16];
    for (int j = 0; j < 16; ++j) {
        int m = tid + j * 256;
        vals[j] = dots[(size_t)b * 4096 + m] * inv_mn[m] * inv_x;
    }
    float tv[10]; int ti[10];
    for (int t = 0; t < 10; ++t) {
        float bv = -1e30f; int bidx = 0x7fffffff;
        for (int j = 0; j < 16; ++j) {
            int m = tid + j * 256;
            float v = vals[j];
            if (v > bv || (v == bv && m < bidx)) { bv = v; bidx = m; }
        }
        red[tid] = bv; redi[tid] = bidx;
        __syncthreads();
        for (int s = 128; s > 0; s >>= 1) {
            if (tid < s) {
                float v2 = red[tid + s]; int i2 = redi[tid + s];
                if (v2 > red[tid] || (v2 == red[tid] && i2 < redi[tid])) { red[tid] = v2; redi[tid] = i2; }
            }
            __syncthreads();
        }
        int sel = redi[0];
        tv[t] = red[0]; ti[t] = sel;
        if ((sel & 255) == tid) vals[sel >> 8] = -1e30f;
        __syncthreads();
    }
    float w[10], wsum = 0.f;
    for (int t = 0; t < 10; ++t) { w[t] = expf(tv[t] - tv[0]); wsum += w[t]; }
    float inv_ws = 1.f / wsum;
    float acc = 0.f;
    for (int t = 0; t < 10; ++t) acc += (w[t] * inv_ws) * mem[(size_t)ti[t] * 256 + tid];
    out[(size_t)b * 256 + tid] = acc;
}

// ---------------------------------------------------------------------------
// Weight repack.
// ---------------------------------------------------------------------------
__global__ __launch_bounds__(256) void k_pack(
    const float* __restrict__ wc1, const float* __restrict__ wt2,
    const float* __restrict__ wc2, const float* __restrict__ w2src,
    float* __restrict__ pk2, float* __restrict__ pk3,
    float* __restrict__ pk4, float* __restrict__ pk5)
{
    int i = blockIdx.x * 256 + threadIdx.x;
    if (i < 9216) {
        int o = i & 31, tap = (i >> 5) % 9, c = i / 288;
        pk2[i] = wc1[(o * 32 + c) * 9 + tap];
    }
    if (i < 8192) {
        int o = i & 15, t = (i >> 4) & 3, q = (i >> 6) & 3, c = i >> 8;
        int wy = t >> 1, wx = t & 1, py = q >> 1, px = q & 1;
        int ky = 3 - py - 2 * wy, kx = 3 - px - 2 * wx;
        pk3[i] = wt2[((c * 16 + o) * 4 + ky) * 4 + kx];
    }
    if (i < 1152) {
        int o = i & 7, tap = (i >> 3) % 9, c = i / 72;
        pk4[i] = wc2[(o * 16 + c) * 9 + tap];
    }
    if (i < 8192) {
        int c = i & 31, j = (i >> 5) & 127, bq = i >> 12;
        pk5[i] = w2src[bq * 4096 + c * 128 + j];
    }
}

// ---------------------------------------------------------------------------
// Conv2d 32->32 k3 p1, 14x14, ReLU. 2 samples/block.
// ---------------------------------------------------------------------------
__global__ __launch_bounds__(256) void k_conv1(
    const float* __restrict__ in, const float* __restrict__ pk2,
    const float* __restrict__ bias, float* __restrict__ out)
{
    __shared__ float P[8208];   // [s2][c16][16 rows][16 cols] + overread pad
    const int tid = threadIdx.x;
    const int wv = __builtin_amdgcn_readfirstlane(tid >> 6);
    const int og = wv & 1, s = wv >> 1;
    const int lane = tid & 63;
    const bool active = lane < 56;
    int row = lane >> 2, tx0 = (lane & 3) * 4;
    if (!active) { row = 0; tx0 = 0; }
    const size_t b = (size_t)blockIdx.x * 2 + s;

    float acc[4][16];
    #pragma unroll
    for (int i = 0; i < 4; ++i)
        #pragma unroll
        for (int o = 0; o < 16; ++o) acc[i][o] = 0.f;

    for (int cc = 0; cc < 32; cc += 16) {
        __syncthreads();
        for (int e = tid; e < 8208; e += 256) P[e] = 0.f;
        __syncthreads();
        for (int e = tid; e < 6272; e += 256) {
            int si = e / 3136, rem = e - si * 3136;
            int c = rem / 196, p = rem % 196;
            P[((si * 16 + c) * 16 + p / 14 + 1) * 16 + (p % 14 + 1)] =
                in[((size_t)(blockIdx.x * 2 + si) * 32 + cc + c) * 196 + p];
        }
        __syncthreads();
        for (int cl = 0; cl < 16; ++cl) {
            const float* Pb = &P[((s * 16 + cl) * 16 + row) * 16 + tx0];
            float rowb[3][8];
            #pragma unroll
            for (int ky = 0; ky < 3; ++ky) {
                float4 a = *(const float4*)&Pb[ky * 16];
                float4 bq = *(const float4*)&Pb[ky * 16 + 4];
                rowb[ky][0] = a.x; rowb[ky][1] = a.y; rowb[ky][2] = a.z; rowb[ky][3] = a.w;
                rowb[ky][4] = bq.x; rowb[ky][5] = bq.y; rowb[ky][6] = bq.z; rowb[ky][7] = bq.w;
            }
            const float* wbase = pk2 + (size_t)(cc + cl) * 288 + og * 16;
            #pragma unroll
            for (int ky = 0; ky < 3; ++ky) {
                #pragma unroll
                for (int kx = 0; kx < 3; ++kx) {
                    const float* wt = wbase + (ky * 3 + kx) * 32;
                    #pragma unroll
                    for (int o = 0; o < 16; ++o) {
                        float w = wt[o];
                        #pragma unroll
                        for (int i = 0; i < 4; ++i)
                            acc[i][o] = fmaf(rowb[ky][i + kx], w, acc[i][o]);
                    }
                }
            }
        }
    }
    if (active) {
        #pragma unroll
        for (int o = 0; o < 16; ++o) {
            int oo = og * 16 + o;
            float bo = bias[oo];
            #pragma unroll
            for (int i = 0; i < 4; ++i) {
                int xx = tx0 + i;
                if (xx < 14)
                    out[(b * 32 + oo) * 196 + row * 14 + xx] = fmaxf(acc[i][o] + bo, 0.f);
            }
        }
    }
}

// ---------------------------------------------------------------------------
// FUSED: ConvTranspose2d 32->16 k4 s2 p1 (14x14->28x28, ReLU)
//        + Conv2d 16->8 k3 p1 (ReLU) + Conv2d 8->1 k1. One sample/block.
// Two 8-channel groups keep LDS at 40960 B -> 4 blocks/CU.
// ---------------------------------------------------------------------------
__global__ __launch_bounds__(256) void k_convt23(
    const float* __restrict__ in, const float* __restrict__ pk3,
    const float* __restrict__ bt2, const float* __restrict__ pk4,
    const float* __restrict__ b2, const float* __restrict__ w3,
    const float* __restrict__ b3, float* __restrict__ out)
{
    __shared__ __align__(16) float P[10240];   // 40960 B
    const int b = blockIdx.x, tid = threadIdx.x;

    // ---- Phase 1: convt2 from input tile [c32][16r][20c] ----
    for (int e = tid; e < 10240; e += 256) P[e] = 0.f;
    __syncthreads();
    for (int e = tid; e < 6272; e += 256) {
        int c = e / 196, p = e % 196;
        P[c * 320 + (p / 14 + 1) * 20 + (p % 14 + 1)] = in[(size_t)b * 6272 + e];
    }
    __syncthreads();

    const int q  = __builtin_amdgcn_readfirstlane(tid >> 6);
    const int py = q >> 1, px = q & 1;
    const int lane = tid & 63;
    const bool active = lane < 56;
    int ty = lane >> 2, tx0 = (lane & 3) * 4;
    if (!active) { ty = 0; tx0 = 0; }
    const int rbase = ty + py;

    float acc[4][16];
    #pragma unroll
    for (int i = 0; i < 4; ++i)
        #pragma unroll
        for (int o = 0; o < 16; ++o) acc[i][o] = 0.f;

    for (int c = 0; c < 32; ++c) {
        const float* Pb = &P[c * 320 + rbase * 20 + tx0];
        float raw[2][8];
        #pragma unroll
        for (int r2 = 0; r2 < 2; ++r2) {
            float4 a = *(const float4*)&Pb[r2 * 20];
            float4 bq = *(const float4*)&Pb[r2 * 20 + 4];
            raw[r2][0] = a.x; raw[r2][1] = a.y; raw[r2][2] = a.z; raw[r2][3] = a.w;
            raw[r2][4] = bq.x; raw[r2][5] = bq.y; raw[r2][6] = bq.z; raw[r2][7] = bq.w;
        }
        float rs[2][5];
        #pragma unroll
        for (int r2 = 0; r2 < 2; ++r2)
            #pragma unroll
            for (int j = 0; j < 5; ++j) rs[r2][j] = px ? raw[r2][j + 1] : raw[r2][j];
        const float* wq = pk3 + (size_t)((c * 4 + q) * 4) * 16;
        #pragma unroll
        for (int t = 0; t < 4; ++t) {
            int wy = t >> 1, wx = t & 1;
            const float* wt = wq + t * 16;
            #pragma unroll
            for (int o = 0; o < 16; ++o) {
                float w = wt[o];
                #pragma unroll
                for (int i = 0; i < 4; ++i)
                    acc[i][o] = fmaf(rs[wy][i + wx], w, acc[i][o]);
            }
        }
    }
    __syncthreads();   // all input-tile reads done; P reusable

    // ---- Phases 2+3 per 8-channel group ----
    const bool active2 = tid < 196;
    int row = active2 ? tid / 7 : 0;
    int tx0b = active2 ? (tid % 7) * 4 : 0;
    const int y = 2 * ty + py;

    float acc2[4][8];
    #pragma unroll
    for (int i = 0; i < 4; ++i)
        #pragma unroll
        for (int o = 0; o < 8; ++o) acc2[i][o] = 0.f;

    #pragma unroll
    for (int g = 0; g < 2; ++g) {
        for (int e = tid; e < 7680; e += 256) P[e] = 0.f;
        __syncthreads();
        if (active) {
            #pragma unroll
            for (int o8 = 0; o8 < 8; ++o8) {
                int o = g * 8 + o8;
                float bo = bt2[o];
                #pragma unroll
                for (int i = 0; i < 4; ++i) {
                    int xt = tx0 + i;
                    if (xt < 14)
                        P[(o8 * 30 + y + 1) * 32 + (2 * xt + px + 1)] = fmaxf(acc[i][o] + bo, 0.f);
                }
            }
        }
        __syncthreads();
        for (int cl = 0; cl < 8; ++cl) {
            const float* Pb = &P[(cl * 30 + row) * 32 + tx0b];
            const float* wb = pk4 + (size_t)(g * 8 + cl) * 72;
            #pragma unroll
            for (int ky = 0; ky < 3; ++ky) {
                float4 a = *(const float4*)&Pb[ky * 32];
                float4 bq = *(const float4*)&Pb[ky * 32 + 4];
                float rowb[8] = {a.x, a.y, a.z, a.w, bq.x, bq.y, bq.z, bq.w};
                #pragma unroll
                for (int kx = 0; kx < 3; ++kx) {
                    const float* wt = wb + (ky * 3 + kx) * 8;
                    #pragma unroll
                    for (int o = 0; o < 8; ++o) {
                        float w = wt[o];
                        #pragma unroll
                        for (int i = 0; i < 4; ++i)
                            acc2[i][o] = fmaf(rowb[i + kx], w, acc2[i][o]);
                    }
                }
            }
        }
        __syncthreads();   // group tile fully consumed before next zero-fill
    }

    // ---- conv3 (8->1, k1) + store ----
    if (active2) {
        const float bias3 = b3[0];
        #pragma unroll
        for (int i = 0; i < 4; ++i) {
            float r = bias3;
            #pragma unroll
            for (int o = 0; o < 8; ++o) r += fmaxf(acc2[i][o] + b2[o], 0.f) * w3[o];
            out[(size_t)b * 784 + row * 28 + tx0b + i] = r;
        }
    }
}

// ---------------------------------------------------------------------------
extern "C" void kernel_launch(void* const* d_in, const int* in_sizes, int n_in,
                              void* d_out, int out_size, void* d_ws, size_t ws_size,
                              hipStream_t stream)
{
    const float* x       = (const float*)d_in[0];
    const float* patch_w = (const float*)d_in[1];
    const float* patch_b = (const float*)d_in[2];
    const float* ln1g    = (const float*)d_in[3];
    const float* ln1b    = (const float*)d_in[4];
    const float* wi      = (const float*)d_in[5];
    const float* bi      = (const float*)d_in[6];
    const float* wo      = (const float*)d_in[7];
    const float* bo      = (const float*)d_in[8];
    const float* ln2g    = (const float*)d_in[9];
    const float* ln2b    = (const float*)d_in[10];
    const float* w1      = (const float*)d_in[11];
    const float* b1      = (const float*)d_in[12];
    const float* w2      = (const float*)d_in[13];
    const float* b2      = (const float*)d_in[14];
    const float* lat_w   = (const float*)d_in[15];
    const float* lat_b   = (const float*)d_in[16];
    const float* memory  = (const float*)d_in[17];
    const float* dec_w   = (const float*)d_in[18];
    const float* dec_b   = (const float*)d_in[19];
    const float* upt1_w  = (const float*)d_in[20];
    const float* upt1_b  = (const float*)d_in[21];
    const float* c1_w    = (const float*)d_in[22];
    const float* c1_b    = (const float*)d_in[23];
    const float* upt2_w  = (const float*)d_in[24];
    const float* upt2_b  = (const float*)d_in[25];
    const float* c2_w    = (const float*)d_in[26];
    const float* c2_b    = (const float*)d_in[27];
    const float* c3_w    = (const float*)d_in[28];
    const float* c3_b    = (const float*)d_in[29];
    float* outp = (float*)d_out;

    float* ws = (float*)d_ws;
    size_t off = 0;
    auto alloc = [&](size_t n) { float* p = ws + off; off += (n + 63) & ~(size_t)63; return p; };
    float* tokens     = alloc((size_t)B_TOT * 1568);
    float* latent     = alloc((size_t)B_TOT * 256);
    float* dots       = alloc((size_t)B_TOT * 4096);
    float* mem_latent = alloc((size_t)B_TOT * 256);
    float* inv_mn     = alloc(4096);
    float* pk2        = alloc(9216);
    float* pk3        = alloc(8192);
    float* pk4        = alloc(1152);
    float* pk5        = alloc(8192);
    float* Wf         = alloc((size_t)6272 * 256);
    float* bf         = alloc(6272);
    float* d1         = alloc((size_t)CHUNK * 6272);
    float* d2         = alloc((size_t)CHUNK * 6272);
    (void)in_sizes; (void)n_in; (void)out_size; (void)ws_size;

    // Weight repack + dec/convt1 algebraic fusion
    k_pack<<<36, 256, 0, stream>>>(c1_w, upt2_w, c2_w, w2, pk2, pk3, pk4, pk5);
    k_fuse<<<6272, 256, 0, stream>>>(upt1_w, upt1_b, dec_w, dec_b, Wf, bf);

    // Encoder (wave-per-sample)
    k_tokens<<<B_TOT / 4, 256, 0, stream>>>(x, patch_w, patch_b, ln1g, ln1b, wi, bi,
                                            wo, bo, ln2g, ln2b, w1, b1, pk5, b2, tokens);
    k_gemm<<<dim3(256 / 64, B_TOT / 128), 256, 0, stream>>>(tokens, lat_w, lat_b, latent,
                                                            B_TOT, 256, 1568, 0);
    k_mnorm<<<4096, 256, 0, stream>>>(memory, inv_mn);
    k_gemm<<<dim3(4096 / 64, B_TOT / 128), 256, 0, stream>>>(latent, memory, nullptr, dots,
                                                             B_TOT, 4096, 256, 0);
    k_memread<<<B_TOT, 256, 0, stream>>>(latent, dots, inv_mn, memory, mem_latent);

    // Decoder, chunked over batch. MFMA fp16 GEMM -> d1; conv1 -> d2;
    // fused convt2+conv2+conv3 -> output.
    for (int c = 0; c < B_TOT / CHUNK; ++c) {
        const float* ml = mem_latent + (size_t)c * CHUNK * 256;
        k_dgemm<<<dim3(6272 / 128, CHUNK / 64), 256, 0, stream>>>(ml, Wf, bf, d1,
                                                                  CHUNK, 6272, 256);
        k_conv1  <<<CHUNK / 2, 256, 0, stream>>>(d1, pk2, c1_b, d2);
        k_convt23<<<CHUNK, 256, 0, stream>>>(d2, pk3, upt2_b, pk4, c2_b, c3_w, c3_b,
                                             outp + (size_t)c * CHUNK * 784);
    }
}

// Round 11
// 1519.538 us; speedup vs baseline: 1.2331x; 1.0816x over previous
//
#include <hip/hip_runtime.h>
#include <math.h>

#define B_TOT 4096
#define CHUNK 1024

typedef _Float16 half_t;
typedef _Float16 h2 __attribute__((ext_vector_type(2)));
typedef _Float16 h8v __attribute__((ext_vector_type(8)));
typedef float f4v __attribute__((ext_vector_type(4)));

#if __has_builtin(__builtin_amdgcn_fdot2)
#define FDOT2(a, b, c) __builtin_amdgcn_fdot2((a), (b), (c), false)
#else
#define FDOT2(a, b, c) fmaf((float)(a)[1], (float)(b)[1], fmaf((float)(a)[0], (float)(b)[0], (c)))
#endif

// k_tokens LDS: K 49x36 halves fp16, V 49x34 floats fp32 per wave; wi slot.
// V stays fp32 (round-4: fp16 V broke topk selection).
// Decoder (downstream of topk) uses fp16 MFMA: d1 fp16 validated round 8,
// MFMA 16x16x32 fragment layout validated round 10.
#define KSTR 36
#define VSTR 34
#define KBYTES (49 * 72)
#define WAVE_LDS (49 * 72 + 49 * 136)  // 10192
#define WI_OFF  (4 * WAVE_LDS)         // 40768
#define BLOCK_LDS (WI_OFF + 12288)     // 53056

// ---------------------------------------------------------------------------
// Fused: patch conv (1->32, k4 s4) + 2 transformer blocks.
// ---------------------------------------------------------------------------
__global__ __launch_bounds__(256) void k_tokens(
    const float* __restrict__ x, const float* __restrict__ pw, const float* __restrict__ pb,
    const float* __restrict__ ln1g, const float* __restrict__ ln1b,
    const float* __restrict__ wi, const float* __restrict__ bi,
    const float* __restrict__ wo, const float* __restrict__ bo,
    const float* __restrict__ ln2g, const float* __restrict__ ln2b,
    const float* __restrict__ w1, const float* __restrict__ fb1,
    const float* __restrict__ w2t, const float* __restrict__ fb2,
    float* __restrict__ tokens)
{
    __shared__ __align__(16) unsigned char Lraw[BLOCK_LDS];
    const int tid = threadIdx.x;
    const int wv = tid >> 6, lane = tid & 63;
    const int b = blockIdx.x * 4 + wv;
    half_t* Kb = (half_t*)(Lraw + wv * WAVE_LDS);
    float*  Vb = (float*)(Lraw + wv * WAVE_LDS + KBYTES);
    const float* wiL = (const float*)(Lraw + WI_OFF);
    float* Lf = (float*)Lraw;            // FF-weight overlay (block-wide)
    const bool is_tok = lane < 49;
    const int s = is_tok ? lane : 48;
    const int py = s / 7, px = s % 7;

    // --- prologue: stage blk-0 qkv weights (visible after barrier (A)) ---
    {
        const float4* srcw = (const float4*)(wi);
        float4* dstw = (float4*)(Lraw + WI_OFF);
        for (int e = tid; e < 768; e += 256) dstw[e] = srcw[e];
    }

    // --- patch conv: direct float4 loads (rows are 16B-aligned) ---
    float xv[16];
    const float* xb = x + (size_t)b * 784 + py * 112 + px * 4;
    #pragma unroll
    for (int r = 0; r < 4; ++r) {
        float4 vq = *(const float4*)(xb + r * 28);
        xv[4 * r + 0] = vq.x; xv[4 * r + 1] = vq.y;
        xv[4 * r + 2] = vq.z; xv[4 * r + 3] = vq.w;
    }
    float t[32];
    #pragma unroll 4
    for (int c = 0; c < 32; ++c) {
        float a = pb[c];
        const float* wr = pw + c * 16;
        #pragma unroll
        for (int i = 0; i < 16; ++i) a = fmaf(xv[i], wr[i], a);
        t[c] = a;
    }

    for (int blk = 0; blk < 2; ++blk) {
        const float* bib = bi + blk * 96;

        // --- LN1 ---
        float mu = 0.f;
        #pragma unroll
        for (int c = 0; c < 32; ++c) mu += t[c];
        mu *= 0.03125f;
        float var = 0.f;
        #pragma unroll
        for (int c = 0; c < 32; ++c) { float d = t[c] - mu; var = fmaf(d, d, var); }
        float rstd = rsqrtf(var * 0.03125f + 1e-5f);
        float xn[32];
        #pragma unroll
        for (int c = 0; c < 32; ++c)
            xn[c] = (t[c] - mu) * rstd * ln1g[blk * 32 + c] + ln1b[blk * 32 + c];

        __syncthreads();   // (A) prior-phase LDS reads done; wi stage visible

        // --- K projection -> LDS fp16 (broadcast b128 weight reads) ---
        #pragma unroll 4
        for (int d = 0; d < 32; ++d) {
            const float* wr = wiL + (32 + d) * 32;
            float a0 = bib[32 + d], a1 = 0.f;
            #pragma unroll
            for (int c2 = 0; c2 < 4; ++c2) {
                float4 wq = *(const float4*)&wr[4 * c2];
                a0 = fmaf(xn[4 * c2],     wq.x, a0);
                a0 = fmaf(xn[4 * c2 + 1], wq.y, a0);
                a0 = fmaf(xn[4 * c2 + 2], wq.z, a0);
                a0 = fmaf(xn[4 * c2 + 3], wq.w, a0);
            }
            #pragma unroll
            for (int c2 = 4; c2 < 8; ++c2) {
                float4 wq = *(const float4*)&wr[4 * c2];
                a1 = fmaf(xn[4 * c2],     wq.x, a1);
                a1 = fmaf(xn[4 * c2 + 1], wq.y, a1);
                a1 = fmaf(xn[4 * c2 + 2], wq.z, a1);
                a1 = fmaf(xn[4 * c2 + 3], wq.w, a1);
            }
            if (is_tok) Kb[s * KSTR + d] = (half_t)(a0 + a1);
        }
        // --- V projection -> LDS fp32 ---
        #pragma unroll 4
        for (int d = 0; d < 32; ++d) {
            const float* wr = wiL + (64 + d) * 32;
            float a0 = bib[64 + d], a1 = 0.f;
            #pragma unroll
            for (int c2 = 0; c2 < 4; ++c2) {
                float4 wq = *(const float4*)&wr[4 * c2];
                a0 = fmaf(xn[4 * c2],     wq.x, a0);
                a0 = fmaf(xn[4 * c2 + 1], wq.y, a0);
                a0 = fmaf(xn[4 * c2 + 2], wq.z, a0);
                a0 = fmaf(xn[4 * c2 + 3], wq.w, a0);
            }
            #pragma unroll
            for (int c2 = 4; c2 < 8; ++c2) {
                float4 wq = *(const float4*)&wr[4 * c2];
                a1 = fmaf(xn[4 * c2],     wq.x, a1);
                a1 = fmaf(xn[4 * c2 + 1], wq.y, a1);
                a1 = fmaf(xn[4 * c2 + 2], wq.z, a1);
                a1 = fmaf(xn[4 * c2 + 3], wq.w, a1);
            }
            if (is_tok) Vb[s * VSTR + d] = a0 + a1;
        }
        // --- Q projection (scaled), packed to half2 for fdot2 ---
        float q0[32];
        #pragma unroll 4
        for (int d = 0; d < 32; ++d) {
            const float* wr = wiL + d * 32;
            float a0 = bib[d], a1 = 0.f;
            #pragma unroll
            for (int c2 = 0; c2 < 4; ++c2) {
                float4 wq = *(const float4*)&wr[4 * c2];
                a0 = fmaf(xn[4 * c2],     wq.x, a0);
                a0 = fmaf(xn[4 * c2 + 1], wq.y, a0);
                a0 = fmaf(xn[4 * c2 + 2], wq.z, a0);
                a0 = fmaf(xn[4 * c2 + 3], wq.w, a0);
            }
            #pragma unroll
            for (int c2 = 4; c2 < 8; ++c2) {
                float4 wq = *(const float4*)&wr[4 * c2];
                a1 = fmaf(xn[4 * c2],     wq.x, a1);
                a1 = fmaf(xn[4 * c2 + 1], wq.y, a1);
                a1 = fmaf(xn[4 * c2 + 2], wq.z, a1);
                a1 = fmaf(xn[4 * c2 + 3], wq.w, a1);
            }
            q0[d] = (a0 + a1) * 0.25f;
        }
        h2 qh[16];
        #pragma unroll
        for (int i = 0; i < 16; ++i) {
            h2 hh; hh[0] = (half_t)q0[2 * i]; hh[1] = (half_t)q0[2 * i + 1];
            qh[i] = hh;
        }

        // wave-local fence: own K/V ds_writes visible before broadcast reads
        __asm__ volatile("s_waitcnt lgkmcnt(0)" ::: "memory");

        // --- attention: 2 heads of 16 dims, softmax without running max ---
        float o[32];
        #pragma unroll
        for (int d = 0; d < 32; ++d) o[d] = 0.f;
        float l0 = 0.f, l1 = 0.f;
        union H4 { double qd; h2 p[2]; };
        for (int j = 0; j < 49; ++j) {
            const double* kr = (const double*)(Kb + j * KSTR);
            const float* vr = Vb + j * VSTR;
            H4 u0, u1, u2, u3, w0, w1h, w2h, w3;
            u0.qd = kr[0]; u1.qd = kr[1]; u2.qd = kr[2]; u3.qd = kr[3];
            w0.qd = kr[4]; w1h.qd = kr[5]; w2h.qd = kr[6]; w3.qd = kr[7];
            float s0a = 0.f, s0b = 0.f, s1a = 0.f, s1b = 0.f;
            s0a = FDOT2(u0.p[0], qh[0], s0a); s0a = FDOT2(u0.p[1], qh[1], s0a);
            s0b = FDOT2(u1.p[0], qh[2], s0b); s0b = FDOT2(u1.p[1], qh[3], s0b);
            s0a = FDOT2(u2.p[0], qh[4], s0a); s0a = FDOT2(u2.p[1], qh[5], s0a);
            s0b = FDOT2(u3.p[0], qh[6], s0b); s0b = FDOT2(u3.p[1], qh[7], s0b);
            s1a = FDOT2(w0.p[0], qh[8], s1a); s1a = FDOT2(w0.p[1], qh[9], s1a);
            s1b = FDOT2(w1h.p[0], qh[10], s1b); s1b = FDOT2(w1h.p[1], qh[11], s1b);
            s1a = FDOT2(w2h.p[0], qh[12], s1a); s1a = FDOT2(w2h.p[1], qh[13], s1a);
            s1b = FDOT2(w3.p[0], qh[14], s1b); s1b = FDOT2(w3.p[1], qh[15], s1b);
            float p0 = __expf(s0a + s0b), p1 = __expf(s1a + s1b);
            l0 += p0; l1 += p1;
            #pragma unroll
            for (int i = 0; i < 8; ++i) {
                float2 va = *(const float2*)&vr[2 * i];
                o[2 * i]     = fmaf(p0, va.x, o[2 * i]);
                o[2 * i + 1] = fmaf(p0, va.y, o[2 * i + 1]);
                float2 vc = *(const float2*)&vr[16 + 2 * i];
                o[16 + 2 * i]     = fmaf(p1, vc.x, o[16 + 2 * i]);
                o[16 + 2 * i + 1] = fmaf(p1, vc.y, o[16 + 2 * i + 1]);
            }
        }
        float il0 = 1.f / l0, il1 = 1.f / l1;
        #pragma unroll
        for (int d = 0; d < 16; ++d) { o[d] *= il0; o[16 + d] *= il1; }

        // --- out projection + residual (wave-uniform global weights, 4 KB) ---
        #pragma unroll
        for (int c = 0; c < 32; ++c) {
            const float* wr = wo + blk * 1024 + c * 32;
            float a = bo[blk * 32 + c];
            #pragma unroll
            for (int k2 = 0; k2 < 32; ++k2) a = fmaf(o[k2], wr[k2], a);
            t[c] += a;
        }

        // --- LN2 ---
        mu = 0.f;
        #pragma unroll
        for (int c = 0; c < 32; ++c) mu += t[c];
        mu *= 0.03125f;
        var = 0.f;
        #pragma unroll
        for (int c = 0; c < 32; ++c) { float d = t[c] - mu; var = fmaf(d, d, var); }
        rstd = rsqrtf(var * 0.03125f + 1e-5f);
        #pragma unroll
        for (int c = 0; c < 32; ++c)
            xn[c] = (t[c] - mu) * rstd * ln2g[blk * 32 + c] + ln2b[blk * 32 + c];

        __syncthreads();   // (C) all waves done reading K/V + wi

        // --- stage FF weights (overlay over KV) + next blk's wi ---
        {
            const float4* src1 = (const float4*)(w1 + blk * 4096);
            const float4* src2 = (const float4*)(w2t + blk * 4096);
            float4* dst = (float4*)Lraw;
            for (int e = tid; e < 1024; e += 256) dst[e] = src1[e];
            for (int e = tid; e < 1024; e += 256) dst[1024 + e] = src2[e];
            if (blk == 0) {
                const float4* srcw = (const float4*)(wi + 3072);
                float4* dstw = (float4*)(Lraw + WI_OFF);
                for (int e = tid; e < 768; e += 256) dstw[e] = srcw[e];
            }
        }
        __syncthreads();   // (D) FF weights (and wi for blk1) visible

        // --- FF from LDS: broadcast ds_read_b128 rows ---
        const float* w2L = Lf + 4096;
        #pragma unroll 2
        for (int j = 0; j < 128; ++j) {
            const float* wr = Lf + j * 32;
            float ha = fb1[blk * 128 + j], hb = 0.f;
            #pragma unroll
            for (int c2 = 0; c2 < 4; ++c2) {
                float4 wq = *(const float4*)&wr[4 * c2];
                ha = fmaf(xn[4 * c2],     wq.x, ha);
                ha = fmaf(xn[4 * c2 + 1], wq.y, ha);
                ha = fmaf(xn[4 * c2 + 2], wq.z, ha);
                ha = fmaf(xn[4 * c2 + 3], wq.w, ha);
            }
            #pragma unroll
            for (int c2 = 4; c2 < 8; ++c2) {
                float4 wq = *(const float4*)&wr[4 * c2];
                hb = fmaf(xn[4 * c2],     wq.x, hb);
                hb = fmaf(xn[4 * c2 + 1], wq.y, hb);
                hb = fmaf(xn[4 * c2 + 2], wq.z, hb);
                hb = fmaf(xn[4 * c2 + 3], wq.w, hb);
            }
            float h = ha + hb;
            h = 0.5f * h * (1.f + erff(h * 0.7071067811865476f));
            const float* w2r = w2L + j * 32;
            #pragma unroll
            for (int c2 = 0; c2 < 8; ++c2) {
                float4 wq = *(const float4*)&w2r[4 * c2];
                t[4 * c2]     = fmaf(h, wq.x, t[4 * c2]);
                t[4 * c2 + 1] = fmaf(h, wq.y, t[4 * c2 + 1]);
                t[4 * c2 + 2] = fmaf(h, wq.z, t[4 * c2 + 2]);
                t[4 * c2 + 3] = fmaf(h, wq.w, t[4 * c2 + 3]);
            }
        }
        #pragma unroll
        for (int c = 0; c < 32; ++c) t[c] += fb2[blk * 32 + c];
    }

    if (is_tok) {
        float* op = tokens + (size_t)b * 1568 + s * 32;
        #pragma unroll
        for (int c = 0; c < 32; c += 4) {
            float4 vv = make_float4(t[c], t[c + 1], t[c + 2], t[c + 3]);
            *(float4*)&op[c] = vv;
        }
    }
}

// ---------------------------------------------------------------------------
// C[M,N] = A[M,K] @ B[N,K]^T (+bias, optional ReLU). fp32, 128x64 tile.
// Used for the topk-upstream GEMMs (latent, dots) — must stay fp32.
// ---------------------------------------------------------------------------
__global__ __launch_bounds__(256) void k_gemm(
    const float* __restrict__ A, const float* __restrict__ Bm,
    const float* __restrict__ bias, float* __restrict__ C,
    int M, int N, int K, int relu)
{
    __shared__ float As[16 * 132];
    __shared__ float Bs[16 * 68];
    const int n0 = blockIdx.x * 64, m0 = blockIdx.y * 128;
    const int tid = threadIdx.x;
    const int tx = tid & 15, ty = tid >> 4;
    const int lr = tid >> 1, lk = (tid & 1) * 8;
    const int br = tid >> 2, bk = (tid & 3) * 4;
    float acc[8][4] = {{0.f}};
    for (int k0 = 0; k0 < K; k0 += 16) {
        float4 av0 = *(const float4*)&A[(size_t)(m0 + lr) * K + k0 + lk];
        float4 av1 = *(const float4*)&A[(size_t)(m0 + lr) * K + k0 + lk + 4];
        float4 bv0 = *(const float4*)&Bm[(size_t)(n0 + br) * K + k0 + bk];
        As[(lk + 0) * 132 + lr] = av0.x;
        As[(lk + 1) * 132 + lr] = av0.y;
        As[(lk + 2) * 132 + lr] = av0.z;
        As[(lk + 3) * 132 + lr] = av0.w;
        As[(lk + 4) * 132 + lr] = av1.x;
        As[(lk + 5) * 132 + lr] = av1.y;
        As[(lk + 6) * 132 + lr] = av1.z;
        As[(lk + 7) * 132 + lr] = av1.w;
        Bs[(bk + 0) * 68 + br] = bv0.x;
        Bs[(bk + 1) * 68 + br] = bv0.y;
        Bs[(bk + 2) * 68 + br] = bv0.z;
        Bs[(bk + 3) * 68 + br] = bv0.w;
        __syncthreads();
        #pragma unroll
        for (int k = 0; k < 16; ++k) {
            float4 a0 = *(const float4*)&As[k * 132 + ty * 8];
            float4 a1 = *(const float4*)&As[k * 132 + ty * 8 + 4];
            float4 bv = *(const float4*)&Bs[k * 68 + tx * 4];
            float a8[8] = {a0.x, a0.y, a0.z, a0.w, a1.x, a1.y, a1.z, a1.w};
            float b4[4] = {bv.x, bv.y, bv.z, bv.w};
            #pragma unroll
            for (int i = 0; i < 8; ++i)
                #pragma unroll
                for (int j = 0; j < 4; ++j)
                    acc[i][j] = fmaf(a8[i], b4[j], acc[i][j]);
        }
        __syncthreads();
    }
    #pragma unroll
    for (int i = 0; i < 8; ++i) {
        int m = m0 + ty * 8 + i;
        #pragma unroll
        for (int j = 0; j < 4; ++j) {
            int n = n0 + tx * 4 + j;
            float v = acc[i][j] + (bias ? bias[n] : 0.f);
            if (relu) v = fmaxf(v, 0.f);
            C[(size_t)m * N + n] = v;
        }
    }
}

// ---------------------------------------------------------------------------
// MFMA decoder GEMM: d1h[M,N] = (fp16)relu(A[M,K] @ B[N,K]^T + bias).
// fp16 MFMA 16x16x32, fp32 accum. Wf rows are permuted channel-minor
// (n = p*32+o) so d1h comes out as [sample][pixel][32ch] for MFMA conv1.
// ---------------------------------------------------------------------------
__global__ __launch_bounds__(256) void k_dgemm(
    const float* __restrict__ A, const float* __restrict__ Bm,
    const float* __restrict__ bias, half_t* __restrict__ C,
    int M, int N, int K)
{
    __shared__ __align__(16) half_t As[64 * 40];
    __shared__ __align__(16) half_t Bs[128 * 40];
    const int tid = threadIdx.x;
    const int n0 = blockIdx.x * 128, m0 = blockIdx.y * 64;
    const int w = tid >> 6, lane = tid & 63;
    const int wm = (w >> 1) * 32, wn = (w & 1) * 64;
    const int lr = lane & 15, lk = lane >> 4;

    const int ar = tid >> 2, aseg = (tid & 3) * 8;   // A stage: 64 rows x 32 k
    const int br = tid >> 1, bseg = (tid & 1) * 16;  // B stage: 128 rows x 32 k

    f4v acc[2][4];
    #pragma unroll
    for (int i = 0; i < 2; ++i)
        #pragma unroll
        for (int j = 0; j < 4; ++j) acc[i][j] = (f4v){0.f, 0.f, 0.f, 0.f};

    for (int k0 = 0; k0 < K; k0 += 32) {
        {
            const float* ap = A + (size_t)(m0 + ar) * K + k0 + aseg;
            float4 a0 = *(const float4*)ap;
            float4 a1 = *(const float4*)(ap + 4);
            h8v ha;
            ha[0] = (half_t)a0.x; ha[1] = (half_t)a0.y;
            ha[2] = (half_t)a0.z; ha[3] = (half_t)a0.w;
            ha[4] = (half_t)a1.x; ha[5] = (half_t)a1.y;
            ha[6] = (half_t)a1.z; ha[7] = (half_t)a1.w;
            *(h8v*)&As[ar * 40 + aseg] = ha;

            const float* bp = Bm + (size_t)(n0 + br) * K + k0 + bseg;
            float4 b0 = *(const float4*)bp;
            float4 b1 = *(const float4*)(bp + 4);
            float4 b2 = *(const float4*)(bp + 8);
            float4 b3 = *(const float4*)(bp + 12);
            h8v hb0, hb1;
            hb0[0] = (half_t)b0.x; hb0[1] = (half_t)b0.y;
            hb0[2] = (half_t)b0.z; hb0[3] = (half_t)b0.w;
            hb0[4] = (half_t)b1.x; hb0[5] = (half_t)b1.y;
            hb0[6] = (half_t)b1.z; hb0[7] = (half_t)b1.w;
            hb1[0] = (half_t)b2.x; hb1[1] = (half_t)b2.y;
            hb1[2] = (half_t)b2.z; hb1[3] = (half_t)b2.w;
            hb1[4] = (half_t)b3.x; hb1[5] = (half_t)b3.y;
            hb1[6] = (half_t)b3.z; hb1[7] = (half_t)b3.w;
            *(h8v*)&Bs[br * 40 + bseg] = hb0;
            *(h8v*)&Bs[br * 40 + bseg + 8] = hb1;
        }
        __syncthreads();
        h8v af[2], bfr[4];
        #pragma unroll
        for (int i = 0; i < 2; ++i)
            af[i] = *(const h8v*)&As[(wm + i * 16 + lr) * 40 + lk * 8];
        #pragma unroll
        for (int j = 0; j < 4; ++j)
            bfr[j] = *(const h8v*)&Bs[(wn + j * 16 + lr) * 40 + lk * 8];
        #pragma unroll
        for (int i = 0; i < 2; ++i)
            #pragma unroll
            for (int j = 0; j < 4; ++j)
                acc[i][j] = __builtin_amdgcn_mfma_f32_16x16x32_f16(af[i], bfr[j], acc[i][j], 0, 0, 0);
        __syncthreads();
    }

    // Epilogue: C/D col=lane&15, row=(lane>>4)*4+reg; fp16 store.
    #pragma unroll
    for (int j = 0; j < 4; ++j) {
        int n = n0 + wn + j * 16 + lr;
        float bv = bias[n];
        #pragma unroll
        for (int i = 0; i < 2; ++i) {
            #pragma unroll
            for (int r = 0; r < 4; ++r) {
                int m = m0 + wm + i * 16 + lk * 4 + r;
                C[(size_t)m * N + n] = (half_t)fmaxf(acc[i][j][r] + bv, 0.f);
            }
        }
    }
}

// ---------------------------------------------------------------------------
// Fuse dec (linear 256->3136) with convt1 (convT 64->32 k4 s2 p1).
// Output rows PERMUTED channel-minor: Wf[(p*32+o)][k], bf[p*32+o] so the
// decoder MFMA GEMM emits d1h in [sample][pixel][32ch] layout.
// ---------------------------------------------------------------------------
__global__ __launch_bounds__(256) void k_fuse(
    const float* __restrict__ wt1, const float* __restrict__ upt1_b,
    const float* __restrict__ dec_w, const float* __restrict__ dec_b,
    float* __restrict__ Wf, float* __restrict__ bf)
{
    const int n = blockIdx.x;
    const int k = threadIdx.x;
    const int o = n / 196, p = n % 196, y = p / 14, x = p % 14;
    float acc = 0.f, bacc = 0.f;
    for (int ky = 0; ky < 4; ++ky) {
        int iyn = y + 1 - ky;
        if (iyn < 0 || (iyn & 1)) continue;
        int iy = iyn >> 1;
        if (iy > 6) continue;
        for (int kx = 0; kx < 4; ++kx) {
            int ixn = x + 1 - kx;
            if (ixn < 0 || (ixn & 1)) continue;
            int ix = ixn >> 1;
            if (ix > 6) continue;
            for (int c = 0; c < 64; ++c) {
                float w = wt1[((c * 32 + o) * 4 + ky) * 4 + kx];
                int row = c * 49 + iy * 7 + ix;
                acc  = fmaf(w, dec_w[(size_t)row * 256 + k], acc);
                bacc = fmaf(w, dec_b[row], bacc);
            }
        }
    }
    Wf[(size_t)(p * 32 + o) * 256 + k] = acc;
    if (k == 0) bf[p * 32 + o] = bacc + upt1_b[o];
}

// ---------------------------------------------------------------------------
__global__ __launch_bounds__(256) void k_mnorm(const float* __restrict__ mem, float* __restrict__ inv_norm)
{
    __shared__ float red[256];
    const int row = blockIdx.x, tid = threadIdx.x;
    float v = mem[(size_t)row * 256 + tid];
    red[tid] = v * v;
    __syncthreads();
    for (int s = 128; s > 0; s >>= 1) {
        if (tid < s) red[tid] += red[tid + s];
        __syncthreads();
    }
    if (tid == 0) inv_norm[row] = 1.f / fmaxf(sqrtf(red[0]), 1e-12f);
}

// ---------------------------------------------------------------------------
__global__ __launch_bounds__(256) void k_memread(
    const float* __restrict__ latent, const float* __restrict__ dots,
    const float* __restrict__ inv_mn, const float* __restrict__ mem,
    float* __restrict__ out)
{
    __shared__ float red[256];
    __shared__ int   redi[256];
    __shared__ float inv_x_s;
    const int b = blockIdx.x, tid = threadIdx.x;
    float lx = latent[(size_t)b * 256 + tid];
    red[tid] = lx * lx;
    __syncthreads();
    for (int s = 128; s > 0; s >>= 1) {
        if (tid < s) red[tid] += red[tid + s];
        __syncthreads();
    }
    if (tid == 0) inv_x_s = 1.f / fmaxf(sqrtf(red[0]), 1e-12f);
    __syncthreads();
    const float inv_x = inv_x_s;

    float vals[16];
    for (int j = 0; j < 16; ++j) {
        int m = tid + j * 256;
        vals[j] = dots[(size_t)b * 4096 + m] * inv_mn[m] * inv_x;
    }
    float tv[10]; int ti[10];
    for (int t = 0; t < 10; ++t) {
        float bv = -1e30f; int bidx = 0x7fffffff;
        for (int j = 0; j < 16; ++j) {
            int m = tid + j * 256;
            float v = vals[j];
            if (v > bv || (v == bv && m < bidx)) { bv = v; bidx = m; }
        }
        red[tid] = bv; redi[tid] = bidx;
        __syncthreads();
        for (int s = 128; s > 0; s >>= 1) {
            if (tid < s) {
                float v2 = red[tid + s]; int i2 = redi[tid + s];
                if (v2 > red[tid] || (v2 == red[tid] && i2 < redi[tid])) { red[tid] = v2; redi[tid] = i2; }
            }
            __syncthreads();
        }
        int sel = redi[0];
        tv[t] = red[0]; ti[t] = sel;
        if ((sel & 255) == tid) vals[sel >> 8] = -1e30f;
        __syncthreads();
    }
    float w[10], wsum = 0.f;
    for (int t = 0; t < 10; ++t) { w[t] = expf(tv[t] - tv[0]); wsum += w[t]; }
    float inv_ws = 1.f / wsum;
    float acc = 0.f;
    for (int t = 0; t < 10; ++t) acc += (w[t] * inv_ws) * mem[(size_t)ti[t] * 256 + tid];
    out[(size_t)b * 256 + tid] = acc;
}

// ---------------------------------------------------------------------------
// Weight repack.
//   pk2h[((tap*2+nt)*16+oc)*32+ic] fp16  from c1_w [32][32][3][3]  (MFMA B-frag)
//   pk3[c32][q4][tap4][o16]              from upt2_w [32][16][4][4]
//   pk4[c16][tap9][o8]                   from c2_w   [8][16][3][3]
//   pk5[blk2][j128][c32]                 from blk_ff2_w [2][32][128] (transpose)
// ---------------------------------------------------------------------------
__global__ __launch_bounds__(256) void k_pack(
    const float* __restrict__ wc1, const float* __restrict__ wt2,
    const float* __restrict__ wc2, const float* __restrict__ w2src,
    half_t* __restrict__ pk2h, float* __restrict__ pk3,
    float* __restrict__ pk4, float* __restrict__ pk5)
{
    int i = blockIdx.x * 256 + threadIdx.x;
    if (i < 9216) {
        int ic = i & 31, oc = (i >> 5) & 15, nt = (i >> 9) & 1, t = i >> 10;
        pk2h[i] = (half_t)wc1[((nt * 16 + oc) * 32 + ic) * 9 + t];
    }
    if (i < 8192) {
        int o = i & 15, t = (i >> 4) & 3, q = (i >> 6) & 3, c = i >> 8;
        int wy = t >> 1, wx = t & 1, py = q >> 1, px = q & 1;
        int ky = 3 - py - 2 * wy, kx = 3 - px - 2 * wx;
        pk3[i] = wt2[((c * 16 + o) * 4 + ky) * 4 + kx];
    }
    if (i < 1152) {
        int o = i & 7, tap = (i >> 3) % 9, c = i / 72;
        pk4[i] = wc2[(o * 16 + c) * 9 + tap];
    }
    if (i < 8192) {
        int c = i & 31, j = (i >> 5) & 127, bq = i >> 12;
        pk5[i] = w2src[bq * 4096 + c * 128 + j];
    }
}

// ---------------------------------------------------------------------------
// Conv2d 32->32 k3 p1, 14x14, ReLU — MFMA version. 2 samples/block.
// Input d1h fp16 channel-minor [sample][196][32]; staged into zero-haloed
// LDS [16][16][40-half] per sample (40960 B total -> 4 blocks/CU; 40-half
// pixel stride rotates banks). Per 16-pixel tile: 9 taps x 1 per-lane b128
// A-frag x 2 MFMA (oc 0-15 / 16-31). B-frags (MFMA layout) preloaded to regs.
// Output d2 fp32 ch-major [sample][32][196] — convt23 unchanged.
// ---------------------------------------------------------------------------
__global__ __launch_bounds__(256) void k_conv1(
    const half_t* __restrict__ in, const half_t* __restrict__ wh,
    const float* __restrict__ bias, float* __restrict__ out)
{
    __shared__ __align__(16) half_t P[2 * 16 * 16 * 40];   // 40960 B
    const int tid = threadIdx.x;
    const int w = tid >> 6, lane = tid & 63;
    const size_t b0 = (size_t)blockIdx.x * 2;

    // zero halo (whole tile), then stage the two samples channel-minor
    for (int e = tid; e < 10240; e += 256) ((unsigned int*)P)[e] = 0u;
    __syncthreads();
    {
        const unsigned int* src = (const unsigned int*)in;
        for (int e = tid; e < 6272; e += 256) {
            int si = e >> 12;                 // e / 4096? no: 3136 per sample
            si = e / 3136;
            int rem = e - si * 3136;
            int p = rem >> 4, c2 = rem & 15;
            int y = p / 14, x = p % 14;
            ((unsigned int*)P)[si * 5120 + ((y + 1) * 16 + (x + 1)) * 20 + c2] =
                src[(b0 + si) * 3136 + rem];
        }
    }

    // preload B-frags: 9 taps x 2 oc-tiles, MFMA B layout (n=lane&15, k-seg)
    h8v bfr[9][2];
    #pragma unroll
    for (int t = 0; t < 9; ++t)
        #pragma unroll
        for (int nt = 0; nt < 2; ++nt)
            bfr[t][nt] = *(const h8v*)&wh[((size_t)((t * 2 + nt) * 16 + (lane & 15))) * 32 + (lane >> 4) * 8];

    __syncthreads();

    const int kseg = (lane >> 4) * 8;
    const int oc = lane & 15;
    const float bv0 = bias[oc], bv1 = bias[16 + oc];

    for (int job = w; job < 26; job += 4) {
        const int si = job >= 13 ? 1 : 0;
        const int tile = job - si * 13;
        int p = tile * 16 + (lane & 15);
        if (p > 195) p = 195;                 // clamp; stores guarded below
        const int y = p / 14, x = p % 14;
        const half_t* Pb = P + si * 10240;

        f4v acc0 = (f4v){0.f, 0.f, 0.f, 0.f};
        f4v acc1 = (f4v){0.f, 0.f, 0.f, 0.f};
        #pragma unroll
        for (int ky = 0; ky < 3; ++ky) {
            #pragma unroll
            for (int kx = 0; kx < 3; ++kx) {
                h8v af = *(const h8v*)&Pb[((y + ky) * 16 + (x + kx)) * 40 + kseg];
                acc0 = __builtin_amdgcn_mfma_f32_16x16x32_f16(af, bfr[ky * 3 + kx][0], acc0, 0, 0, 0);
                acc1 = __builtin_amdgcn_mfma_f32_16x16x32_f16(af, bfr[ky * 3 + kx][1], acc1, 0, 0, 0);
            }
        }

        // C/D: col=lane&15 -> oc, row=(lane>>4)*4+r -> pixel in tile
        const int pr0 = tile * 16 + (lane >> 4) * 4;
        float* ob = out + (b0 + si) * 32 * 196;
        #pragma unroll
        for (int r = 0; r < 4; ++r) {
            int pp = pr0 + r;
            if (pp < 196) {
                ob[(size_t)oc * 196 + pp]        = fmaxf(acc0[r] + bv0, 0.f);
                ob[(size_t)(16 + oc) * 196 + pp] = fmaxf(acc1[r] + bv1, 0.f);
            }
        }
    }
}

// ---------------------------------------------------------------------------
// FUSED: ConvTranspose2d 32->16 k4 s2 p1 (14x14->28x28, ReLU)
//        + Conv2d 16->8 k3 p1 (ReLU) + Conv2d 8->1 k1. One sample/block.
// Two 8-channel groups keep LDS at 40960 B -> 4 blocks/CU.
// ---------------------------------------------------------------------------
__global__ __launch_bounds__(256) void k_convt23(
    const float* __restrict__ in, const float* __restrict__ pk3,
    const float* __restrict__ bt2, const float* __restrict__ pk4,
    const float* __restrict__ b2, const float* __restrict__ w3,
    const float* __restrict__ b3, float* __restrict__ out)
{
    __shared__ __align__(16) float P[10240];   // 40960 B
    const int b = blockIdx.x, tid = threadIdx.x;

    // ---- Phase 1: convt2 from input tile [c32][16r][20c] ----
    for (int e = tid; e < 10240; e += 256) P[e] = 0.f;
    __syncthreads();
    for (int e = tid; e < 6272; e += 256) {
        int c = e / 196, p = e % 196;
        P[c * 320 + (p / 14 + 1) * 20 + (p % 14 + 1)] = in[(size_t)b * 6272 + e];
    }
    __syncthreads();

    const int q  = __builtin_amdgcn_readfirstlane(tid >> 6);
    const int py = q >> 1, px = q & 1;
    const int lane = tid & 63;
    const bool active = lane < 56;
    int ty = lane >> 2, tx0 = (lane & 3) * 4;
    if (!active) { ty = 0; tx0 = 0; }
    const int rbase = ty + py;

    float acc[4][16];
    #pragma unroll
    for (int i = 0; i < 4; ++i)
        #pragma unroll
        for (int o = 0; o < 16; ++o) acc[i][o] = 0.f;

    for (int c = 0; c < 32; ++c) {
        const float* Pb = &P[c * 320 + rbase * 20 + tx0];
        float raw[2][8];
        #pragma unroll
        for (int r2 = 0; r2 < 2; ++r2) {
            float4 a = *(const float4*)&Pb[r2 * 20];
            float4 bq = *(const float4*)&Pb[r2 * 20 + 4];
            raw[r2][0] = a.x; raw[r2][1] = a.y; raw[r2][2] = a.z; raw[r2][3] = a.w;
            raw[r2][4] = bq.x; raw[r2][5] = bq.y; raw[r2][6] = bq.z; raw[r2][7] = bq.w;
        }
        float rs[2][5];
        #pragma unroll
        for (int r2 = 0; r2 < 2; ++r2)
            #pragma unroll
            for (int j = 0; j < 5; ++j) rs[r2][j] = px ? raw[r2][j + 1] : raw[r2][j];
        const float* wq = pk3 + (size_t)((c * 4 + q) * 4) * 16;
        #pragma unroll
        for (int t = 0; t < 4; ++t) {
            int wy = t >> 1, wx = t & 1;
            const float* wt = wq + t * 16;
            #pragma unroll
            for (int o = 0; o < 16; ++o) {
                float w = wt[o];
                #pragma unroll
                for (int i = 0; i < 4; ++i)
                    acc[i][o] = fmaf(rs[wy][i + wx], w, acc[i][o]);
            }
        }
    }
    __syncthreads();   // all input-tile reads done; P reusable

    // ---- Phases 2+3 per 8-channel group ----
    const bool active2 = tid < 196;
    int row = active2 ? tid / 7 : 0;
    int tx0b = active2 ? (tid % 7) * 4 : 0;
    const int y = 2 * ty + py;

    float acc2[4][8];
    #pragma unroll
    for (int i = 0; i < 4; ++i)
        #pragma unroll
        for (int o = 0; o < 8; ++o) acc2[i][o] = 0.f;

    #pragma unroll
    for (int g = 0; g < 2; ++g) {
        for (int e = tid; e < 7680; e += 256) P[e] = 0.f;
        __syncthreads();
        if (active) {
            #pragma unroll
            for (int o8 = 0; o8 < 8; ++o8) {
                int o = g * 8 + o8;
                float bo = bt2[o];
                #pragma unroll
                for (int i = 0; i < 4; ++i) {
                    int xt = tx0 + i;
                    if (xt < 14)
                        P[(o8 * 30 + y + 1) * 32 + (2 * xt + px + 1)] = fmaxf(acc[i][o] + bo, 0.f);
                }
            }
        }
        __syncthreads();
        for (int cl = 0; cl < 8; ++cl) {
            const float* Pb = &P[(cl * 30 + row) * 32 + tx0b];
            const float* wb = pk4 + (size_t)(g * 8 + cl) * 72;
            #pragma unroll
            for (int ky = 0; ky < 3; ++ky) {
                float4 a = *(const float4*)&Pb[ky * 32];
                float4 bq = *(const float4*)&Pb[ky * 32 + 4];
                float rowb[8] = {a.x, a.y, a.z, a.w, bq.x, bq.y, bq.z, bq.w};
                #pragma unroll
                for (int kx = 0; kx < 3; ++kx) {
                    const float* wt = wb + (ky * 3 + kx) * 8;
                    #pragma unroll
                    for (int o = 0; o < 8; ++o) {
                        float w = wt[o];
                        #pragma unroll
                        for (int i = 0; i < 4; ++i)
                            acc2[i][o] = fmaf(rowb[i + kx], w, acc2[i][o]);
                    }
                }
            }
        }
        __syncthreads();   // group tile fully consumed before next zero-fill
    }

    // ---- conv3 (8->1, k1) + store ----
    if (active2) {
        const float bias3 = b3[0];
        #pragma unroll
        for (int i = 0; i < 4; ++i) {
            float r = bias3;
            #pragma unroll
            for (int o = 0; o < 8; ++o) r += fmaxf(acc2[i][o] + b2[o], 0.f) * w3[o];
            out[(size_t)b * 784 + row * 28 + tx0b + i] = r;
        }
    }
}

// ---------------------------------------------------------------------------
extern "C" void kernel_launch(void* const* d_in, const int* in_sizes, int n_in,
                              void* d_out, int out_size, void* d_ws, size_t ws_size,
                              hipStream_t stream)
{
    const float* x       = (const float*)d_in[0];
    const float* patch_w = (const float*)d_in[1];
    const float* patch_b = (const float*)d_in[2];
    const float* ln1g    = (const float*)d_in[3];
    const float* ln1b    = (const float*)d_in[4];
    const float* wi      = (const float*)d_in[5];
    const float* bi      = (const float*)d_in[6];
    const float* wo      = (const float*)d_in[7];
    const float* bo      = (const float*)d_in[8];
    const float* ln2g    = (const float*)d_in[9];
    const float* ln2b    = (const float*)d_in[10];
    const float* w1      = (const float*)d_in[11];
    const float* b1      = (const float*)d_in[12];
    const float* w2      = (const float*)d_in[13];
    const float* b2      = (const float*)d_in[14];
    const float* lat_w   = (const float*)d_in[15];
    const float* lat_b   = (const float*)d_in[16];
    const float* memory  = (const float*)d_in[17];
    const float* dec_w   = (const float*)d_in[18];
    const float* dec_b   = (const float*)d_in[19];
    const float* upt1_w  = (const float*)d_in[20];
    const float* upt1_b  = (const float*)d_in[21];
    const float* c1_w    = (const float*)d_in[22];
    const float* c1_b    = (const float*)d_in[23];
    const float* upt2_w  = (const float*)d_in[24];
    const float* upt2_b  = (const float*)d_in[25];
    const float* c2_w    = (const float*)d_in[26];
    const float* c2_b    = (const float*)d_in[27];
    const float* c3_w    = (const float*)d_in[28];
    const float* c3_b    = (const float*)d_in[29];
    float* outp = (float*)d_out;

    float* ws = (float*)d_ws;
    size_t off = 0;
    auto alloc = [&](size_t n) { float* p = ws + off; off += (n + 63) & ~(size_t)63; return p; };
    float* tokens     = alloc((size_t)B_TOT * 1568);
    float* latent     = alloc((size_t)B_TOT * 256);
    float* dots       = alloc((size_t)B_TOT * 4096);
    float* mem_latent = alloc((size_t)B_TOT * 256);
    float* inv_mn     = alloc(4096);
    half_t* pk2h      = (half_t*)alloc(4608);
    float* pk3        = alloc(8192);
    float* pk4        = alloc(1152);
    float* pk5        = alloc(8192);
    float* Wf         = alloc((size_t)6272 * 256);
    float* bf         = alloc(6272);
    half_t* d1h       = (half_t*)alloc((size_t)CHUNK * 6272 / 2);
    float* d2         = alloc((size_t)CHUNK * 6272);
    (void)in_sizes; (void)n_in; (void)out_size; (void)ws_size;

    // Weight repack + dec/convt1 algebraic fusion (Wf rows channel-minor)
    k_pack<<<36, 256, 0, stream>>>(c1_w, upt2_w, c2_w, w2, pk2h, pk3, pk4, pk5);
    k_fuse<<<6272, 256, 0, stream>>>(upt1_w, upt1_b, dec_w, dec_b, Wf, bf);

    // Encoder (wave-per-sample)
    k_tokens<<<B_TOT / 4, 256, 0, stream>>>(x, patch_w, patch_b, ln1g, ln1b, wi, bi,
                                            wo, bo, ln2g, ln2b, w1, b1, pk5, b2, tokens);
    k_gemm<<<dim3(256 / 64, B_TOT / 128), 256, 0, stream>>>(tokens, lat_w, lat_b, latent,
                                                            B_TOT, 256, 1568, 0);
    k_mnorm<<<4096, 256, 0, stream>>>(memory, inv_mn);
    k_gemm<<<dim3(4096 / 64, B_TOT / 128), 256, 0, stream>>>(latent, memory, nullptr, dots,
                                                             B_TOT, 4096, 256, 0);
    k_memread<<<B_TOT, 256, 0, stream>>>(latent, dots, inv_mn, memory, mem_latent);

    // Decoder, chunked. MFMA GEMM -> d1h (fp16 ch-minor); MFMA conv1 -> d2;
    // fused convt2+conv2+conv3 -> output.
    for (int c = 0; c < B_TOT / CHUNK; ++c) {
        const float* ml = mem_latent + (size_t)c * CHUNK * 256;
        k_dgemm<<<dim3(6272 / 128, CHUNK / 64), 256, 0, stream>>>(ml, Wf, bf, d1h,
                                                                  CHUNK, 6272, 256);
        k_conv1  <<<CHUNK / 2, 256, 0, stream>>>(d1h, pk2h, c1_b, d2);
        k_convt23<<<CHUNK, 256, 0, stream>>>(d2, pk3, upt2_b, pk4, c2_b, c3_w, c3_b,
                                             outp + (size_t)c * CHUNK * 784);
    }
}

// Round 12
// 1294.520 us; speedup vs baseline: 1.4475x; 1.1738x over previous
//
#include <hip/hip_runtime.h>
#include <math.h>

#define B_TOT 4096
#define CHUNK 1024

typedef _Float16 half_t;
typedef _Float16 h2 __attribute__((ext_vector_type(2)));
typedef _Float16 h8v __attribute__((ext_vector_type(8)));
typedef float f4v __attribute__((ext_vector_type(4)));

#if __has_builtin(__builtin_amdgcn_fdot2)
#define FDOT2(a, b, c) __builtin_amdgcn_fdot2((a), (b), (c), false)
#else
#define FDOT2(a, b, c) fmaf((float)(a)[1], (float)(b)[1], fmaf((float)(a)[0], (float)(b)[0], (c)))
#endif

// k_tokens LDS: K 49x36 halves fp16, V 49x34 floats fp32 per wave; wi slot.
// V stays fp32 (round-4: fp16 V broke topk selection).
// Decoder (downstream of topk) is fp16-MFMA end to end now: d1h (r8/r10),
// conv1 (r11), d2h + convt2 (this round). Fragment layout validated r10/r11.
#define KSTR 36
#define VSTR 34
#define KBYTES (49 * 72)
#define WAVE_LDS (49 * 72 + 49 * 136)  // 10192
#define WI_OFF  (4 * WAVE_LDS)         // 40768
#define BLOCK_LDS (WI_OFF + 12288)     // 53056

// ---------------------------------------------------------------------------
// Fused: patch conv (1->32, k4 s4) + 2 transformer blocks.
// ---------------------------------------------------------------------------
__global__ __launch_bounds__(256) void k_tokens(
    const float* __restrict__ x, const float* __restrict__ pw, const float* __restrict__ pb,
    const float* __restrict__ ln1g, const float* __restrict__ ln1b,
    const float* __restrict__ wi, const float* __restrict__ bi,
    const float* __restrict__ wo, const float* __restrict__ bo,
    const float* __restrict__ ln2g, const float* __restrict__ ln2b,
    const float* __restrict__ w1, const float* __restrict__ fb1,
    const float* __restrict__ w2t, const float* __restrict__ fb2,
    float* __restrict__ tokens)
{
    __shared__ __align__(16) unsigned char Lraw[BLOCK_LDS];
    const int tid = threadIdx.x;
    const int wv = tid >> 6, lane = tid & 63;
    const int b = blockIdx.x * 4 + wv;
    half_t* Kb = (half_t*)(Lraw + wv * WAVE_LDS);
    float*  Vb = (float*)(Lraw + wv * WAVE_LDS + KBYTES);
    const float* wiL = (const float*)(Lraw + WI_OFF);
    float* Lf = (float*)Lraw;            // FF-weight overlay (block-wide)
    const bool is_tok = lane < 49;
    const int s = is_tok ? lane : 48;
    const int py = s / 7, px = s % 7;

    // --- prologue: stage blk-0 qkv weights (visible after barrier (A)) ---
    {
        const float4* srcw = (const float4*)(wi);
        float4* dstw = (float4*)(Lraw + WI_OFF);
        for (int e = tid; e < 768; e += 256) dstw[e] = srcw[e];
    }

    // --- patch conv: direct float4 loads (rows are 16B-aligned) ---
    float xv[16];
    const float* xb = x + (size_t)b * 784 + py * 112 + px * 4;
    #pragma unroll
    for (int r = 0; r < 4; ++r) {
        float4 vq = *(const float4*)(xb + r * 28);
        xv[4 * r + 0] = vq.x; xv[4 * r + 1] = vq.y;
        xv[4 * r + 2] = vq.z; xv[4 * r + 3] = vq.w;
    }
    float t[32];
    #pragma unroll 4
    for (int c = 0; c < 32; ++c) {
        float a = pb[c];
        const float* wr = pw + c * 16;
        #pragma unroll
        for (int i = 0; i < 16; ++i) a = fmaf(xv[i], wr[i], a);
        t[c] = a;
    }

    for (int blk = 0; blk < 2; ++blk) {
        const float* bib = bi + blk * 96;

        // --- LN1 ---
        float mu = 0.f;
        #pragma unroll
        for (int c = 0; c < 32; ++c) mu += t[c];
        mu *= 0.03125f;
        float var = 0.f;
        #pragma unroll
        for (int c = 0; c < 32; ++c) { float d = t[c] - mu; var = fmaf(d, d, var); }
        float rstd = rsqrtf(var * 0.03125f + 1e-5f);
        float xn[32];
        #pragma unroll
        for (int c = 0; c < 32; ++c)
            xn[c] = (t[c] - mu) * rstd * ln1g[blk * 32 + c] + ln1b[blk * 32 + c];

        __syncthreads();   // (A) prior-phase LDS reads done; wi stage visible

        // --- K projection -> LDS fp16 (broadcast b128 weight reads) ---
        #pragma unroll 4
        for (int d = 0; d < 32; ++d) {
            const float* wr = wiL + (32 + d) * 32;
            float a0 = bib[32 + d], a1 = 0.f;
            #pragma unroll
            for (int c2 = 0; c2 < 4; ++c2) {
                float4 wq = *(const float4*)&wr[4 * c2];
                a0 = fmaf(xn[4 * c2],     wq.x, a0);
                a0 = fmaf(xn[4 * c2 + 1], wq.y, a0);
                a0 = fmaf(xn[4 * c2 + 2], wq.z, a0);
                a0 = fmaf(xn[4 * c2 + 3], wq.w, a0);
            }
            #pragma unroll
            for (int c2 = 4; c2 < 8; ++c2) {
                float4 wq = *(const float4*)&wr[4 * c2];
                a1 = fmaf(xn[4 * c2],     wq.x, a1);
                a1 = fmaf(xn[4 * c2 + 1], wq.y, a1);
                a1 = fmaf(xn[4 * c2 + 2], wq.z, a1);
                a1 = fmaf(xn[4 * c2 + 3], wq.w, a1);
            }
            if (is_tok) Kb[s * KSTR + d] = (half_t)(a0 + a1);
        }
        // --- V projection -> LDS fp32 ---
        #pragma unroll 4
        for (int d = 0; d < 32; ++d) {
            const float* wr = wiL + (64 + d) * 32;
            float a0 = bib[64 + d], a1 = 0.f;
            #pragma unroll
            for (int c2 = 0; c2 < 4; ++c2) {
                float4 wq = *(const float4*)&wr[4 * c2];
                a0 = fmaf(xn[4 * c2],     wq.x, a0);
                a0 = fmaf(xn[4 * c2 + 1], wq.y, a0);
                a0 = fmaf(xn[4 * c2 + 2], wq.z, a0);
                a0 = fmaf(xn[4 * c2 + 3], wq.w, a0);
            }
            #pragma unroll
            for (int c2 = 4; c2 < 8; ++c2) {
                float4 wq = *(const float4*)&wr[4 * c2];
                a1 = fmaf(xn[4 * c2],     wq.x, a1);
                a1 = fmaf(xn[4 * c2 + 1], wq.y, a1);
                a1 = fmaf(xn[4 * c2 + 2], wq.z, a1);
                a1 = fmaf(xn[4 * c2 + 3], wq.w, a1);
            }
            if (is_tok) Vb[s * VSTR + d] = a0 + a1;
        }
        // --- Q projection (scaled), packed to half2 for fdot2 ---
        float q0[32];
        #pragma unroll 4
        for (int d = 0; d < 32; ++d) {
            const float* wr = wiL + d * 32;
            float a0 = bib[d], a1 = 0.f;
            #pragma unroll
            for (int c2 = 0; c2 < 4; ++c2) {
                float4 wq = *(const float4*)&wr[4 * c2];
                a0 = fmaf(xn[4 * c2],     wq.x, a0);
                a0 = fmaf(xn[4 * c2 + 1], wq.y, a0);
                a0 = fmaf(xn[4 * c2 + 2], wq.z, a0);
                a0 = fmaf(xn[4 * c2 + 3], wq.w, a0);
            }
            #pragma unroll
            for (int c2 = 4; c2 < 8; ++c2) {
                float4 wq = *(const float4*)&wr[4 * c2];
                a1 = fmaf(xn[4 * c2],     wq.x, a1);
                a1 = fmaf(xn[4 * c2 + 1], wq.y, a1);
                a1 = fmaf(xn[4 * c2 + 2], wq.z, a1);
                a1 = fmaf(xn[4 * c2 + 3], wq.w, a1);
            }
            q0[d] = (a0 + a1) * 0.25f;
        }
        h2 qh[16];
        #pragma unroll
        for (int i = 0; i < 16; ++i) {
            h2 hh; hh[0] = (half_t)q0[2 * i]; hh[1] = (half_t)q0[2 * i + 1];
            qh[i] = hh;
        }

        // wave-local fence: own K/V ds_writes visible before broadcast reads
        __asm__ volatile("s_waitcnt lgkmcnt(0)" ::: "memory");

        // --- attention: 2 heads of 16 dims, softmax without running max ---
        float o[32];
        #pragma unroll
        for (int d = 0; d < 32; ++d) o[d] = 0.f;
        float l0 = 0.f, l1 = 0.f;
        union H4 { double qd; h2 p[2]; };
        for (int j = 0; j < 49; ++j) {
            const double* kr = (const double*)(Kb + j * KSTR);
            const float* vr = Vb + j * VSTR;
            H4 u0, u1, u2, u3, w0, w1h, w2h, w3;
            u0.qd = kr[0]; u1.qd = kr[1]; u2.qd = kr[2]; u3.qd = kr[3];
            w0.qd = kr[4]; w1h.qd = kr[5]; w2h.qd = kr[6]; w3.qd = kr[7];
            float s0a = 0.f, s0b = 0.f, s1a = 0.f, s1b = 0.f;
            s0a = FDOT2(u0.p[0], qh[0], s0a); s0a = FDOT2(u0.p[1], qh[1], s0a);
            s0b = FDOT2(u1.p[0], qh[2], s0b); s0b = FDOT2(u1.p[1], qh[3], s0b);
            s0a = FDOT2(u2.p[0], qh[4], s0a); s0a = FDOT2(u2.p[1], qh[5], s0a);
            s0b = FDOT2(u3.p[0], qh[6], s0b); s0b = FDOT2(u3.p[1], qh[7], s0b);
            s1a = FDOT2(w0.p[0], qh[8], s1a); s1a = FDOT2(w0.p[1], qh[9], s1a);
            s1b = FDOT2(w1h.p[0], qh[10], s1b); s1b = FDOT2(w1h.p[1], qh[11], s1b);
            s1a = FDOT2(w2h.p[0], qh[12], s1a); s1a = FDOT2(w2h.p[1], qh[13], s1a);
            s1b = FDOT2(w3.p[0], qh[14], s1b); s1b = FDOT2(w3.p[1], qh[15], s1b);
            float p0 = __expf(s0a + s0b), p1 = __expf(s1a + s1b);
            l0 += p0; l1 += p1;
            #pragma unroll
            for (int i = 0; i < 8; ++i) {
                float2 va = *(const float2*)&vr[2 * i];
                o[2 * i]     = fmaf(p0, va.x, o[2 * i]);
                o[2 * i + 1] = fmaf(p0, va.y, o[2 * i + 1]);
                float2 vc = *(const float2*)&vr[16 + 2 * i];
                o[16 + 2 * i]     = fmaf(p1, vc.x, o[16 + 2 * i]);
                o[16 + 2 * i + 1] = fmaf(p1, vc.y, o[16 + 2 * i + 1]);
            }
        }
        float il0 = 1.f / l0, il1 = 1.f / l1;
        #pragma unroll
        for (int d = 0; d < 16; ++d) { o[d] *= il0; o[16 + d] *= il1; }

        // --- out projection + residual (wave-uniform global weights, 4 KB) ---
        #pragma unroll
        for (int c = 0; c < 32; ++c) {
            const float* wr = wo + blk * 1024 + c * 32;
            float a = bo[blk * 32 + c];
            #pragma unroll
            for (int k2 = 0; k2 < 32; ++k2) a = fmaf(o[k2], wr[k2], a);
            t[c] += a;
        }

        // --- LN2 ---
        mu = 0.f;
        #pragma unroll
        for (int c = 0; c < 32; ++c) mu += t[c];
        mu *= 0.03125f;
        var = 0.f;
        #pragma unroll
        for (int c = 0; c < 32; ++c) { float d = t[c] - mu; var = fmaf(d, d, var); }
        rstd = rsqrtf(var * 0.03125f + 1e-5f);
        #pragma unroll
        for (int c = 0; c < 32; ++c)
            xn[c] = (t[c] - mu) * rstd * ln2g[blk * 32 + c] + ln2b[blk * 32 + c];

        __syncthreads();   // (C) all waves done reading K/V + wi

        // --- stage FF weights (overlay over KV) + next blk's wi ---
        {
            const float4* src1 = (const float4*)(w1 + blk * 4096);
            const float4* src2 = (const float4*)(w2t + blk * 4096);
            float4* dst = (float4*)Lraw;
            for (int e = tid; e < 1024; e += 256) dst[e] = src1[e];
            for (int e = tid; e < 1024; e += 256) dst[1024 + e] = src2[e];
            if (blk == 0) {
                const float4* srcw = (const float4*)(wi + 3072);
                float4* dstw = (float4*)(Lraw + WI_OFF);
                for (int e = tid; e < 768; e += 256) dstw[e] = srcw[e];
            }
        }
        __syncthreads();   // (D) FF weights (and wi for blk1) visible

        // --- FF from LDS: broadcast ds_read_b128 rows ---
        const float* w2L = Lf + 4096;
        #pragma unroll 2
        for (int j = 0; j < 128; ++j) {
            const float* wr = Lf + j * 32;
            float ha = fb1[blk * 128 + j], hb = 0.f;
            #pragma unroll
            for (int c2 = 0; c2 < 4; ++c2) {
                float4 wq = *(const float4*)&wr[4 * c2];
                ha = fmaf(xn[4 * c2],     wq.x, ha);
                ha = fmaf(xn[4 * c2 + 1], wq.y, ha);
                ha = fmaf(xn[4 * c2 + 2], wq.z, ha);
                ha = fmaf(xn[4 * c2 + 3], wq.w, ha);
            }
            #pragma unroll
            for (int c2 = 4; c2 < 8; ++c2) {
                float4 wq = *(const float4*)&wr[4 * c2];
                hb = fmaf(xn[4 * c2],     wq.x, hb);
                hb = fmaf(xn[4 * c2 + 1], wq.y, hb);
                hb = fmaf(xn[4 * c2 + 2], wq.z, hb);
                hb = fmaf(xn[4 * c2 + 3], wq.w, hb);
            }
            float h = ha + hb;
            h = 0.5f * h * (1.f + erff(h * 0.7071067811865476f));
            const float* w2r = w2L + j * 32;
            #pragma unroll
            for (int c2 = 0; c2 < 8; ++c2) {
                float4 wq = *(const float4*)&w2r[4 * c2];
                t[4 * c2]     = fmaf(h, wq.x, t[4 * c2]);
                t[4 * c2 + 1] = fmaf(h, wq.y, t[4 * c2 + 1]);
                t[4 * c2 + 2] = fmaf(h, wq.z, t[4 * c2 + 2]);
                t[4 * c2 + 3] = fmaf(h, wq.w, t[4 * c2 + 3]);
            }
        }
        #pragma unroll
        for (int c = 0; c < 32; ++c) t[c] += fb2[blk * 32 + c];
    }

    if (is_tok) {
        float* op = tokens + (size_t)b * 1568 + s * 32;
        #pragma unroll
        for (int c = 0; c < 32; c += 4) {
            float4 vv = make_float4(t[c], t[c + 1], t[c + 2], t[c + 3]);
            *(float4*)&op[c] = vv;
        }
    }
}

// ---------------------------------------------------------------------------
// C[M,N] = A[M,K] @ B[N,K]^T (+bias, optional ReLU). fp32, 128x64 tile.
// Used for the topk-upstream GEMMs (latent, dots) — must stay fp32.
// ---------------------------------------------------------------------------
__global__ __launch_bounds__(256) void k_gemm(
    const float* __restrict__ A, const float* __restrict__ Bm,
    const float* __restrict__ bias, float* __restrict__ C,
    int M, int N, int K, int relu)
{
    __shared__ float As[16 * 132];
    __shared__ float Bs[16 * 68];
    const int n0 = blockIdx.x * 64, m0 = blockIdx.y * 128;
    const int tid = threadIdx.x;
    const int tx = tid & 15, ty = tid >> 4;
    const int lr = tid >> 1, lk = (tid & 1) * 8;
    const int br = tid >> 2, bk = (tid & 3) * 4;
    float acc[8][4] = {{0.f}};
    for (int k0 = 0; k0 < K; k0 += 16) {
        float4 av0 = *(const float4*)&A[(size_t)(m0 + lr) * K + k0 + lk];
        float4 av1 = *(const float4*)&A[(size_t)(m0 + lr) * K + k0 + lk + 4];
        float4 bv0 = *(const float4*)&Bm[(size_t)(n0 + br) * K + k0 + bk];
        As[(lk + 0) * 132 + lr] = av0.x;
        As[(lk + 1) * 132 + lr] = av0.y;
        As[(lk + 2) * 132 + lr] = av0.z;
        As[(lk + 3) * 132 + lr] = av0.w;
        As[(lk + 4) * 132 + lr] = av1.x;
        As[(lk + 5) * 132 + lr] = av1.y;
        As[(lk + 6) * 132 + lr] = av1.z;
        As[(lk + 7) * 132 + lr] = av1.w;
        Bs[(bk + 0) * 68 + br] = bv0.x;
        Bs[(bk + 1) * 68 + br] = bv0.y;
        Bs[(bk + 2) * 68 + br] = bv0.z;
        Bs[(bk + 3) * 68 + br] = bv0.w;
        __syncthreads();
        #pragma unroll
        for (int k = 0; k < 16; ++k) {
            float4 a0 = *(const float4*)&As[k * 132 + ty * 8];
            float4 a1 = *(const float4*)&As[k * 132 + ty * 8 + 4];
            float4 bv = *(const float4*)&Bs[k * 68 + tx * 4];
            float a8[8] = {a0.x, a0.y, a0.z, a0.w, a1.x, a1.y, a1.z, a1.w};
            float b4[4] = {bv.x, bv.y, bv.z, bv.w};
            #pragma unroll
            for (int i = 0; i < 8; ++i)
                #pragma unroll
                for (int j = 0; j < 4; ++j)
                    acc[i][j] = fmaf(a8[i], b4[j], acc[i][j]);
        }
        __syncthreads();
    }
    #pragma unroll
    for (int i = 0; i < 8; ++i) {
        int m = m0 + ty * 8 + i;
        #pragma unroll
        for (int j = 0; j < 4; ++j) {
            int n = n0 + tx * 4 + j;
            float v = acc[i][j] + (bias ? bias[n] : 0.f);
            if (relu) v = fmaxf(v, 0.f);
            C[(size_t)m * N + n] = v;
        }
    }
}

// ---------------------------------------------------------------------------
// MFMA decoder GEMM: d1h[M,N] = (fp16)relu(A[M,K] @ B[N,K]^T + bias).
// fp16 MFMA 16x16x32, fp32 accum. Wf rows are permuted channel-minor
// (n = p*32+o) so d1h comes out as [sample][pixel][32ch] for MFMA conv1.
// ---------------------------------------------------------------------------
__global__ __launch_bounds__(256) void k_dgemm(
    const float* __restrict__ A, const float* __restrict__ Bm,
    const float* __restrict__ bias, half_t* __restrict__ C,
    int M, int N, int K)
{
    __shared__ __align__(16) half_t As[64 * 40];
    __shared__ __align__(16) half_t Bs[128 * 40];
    const int tid = threadIdx.x;
    const int n0 = blockIdx.x * 128, m0 = blockIdx.y * 64;
    const int w = tid >> 6, lane = tid & 63;
    const int wm = (w >> 1) * 32, wn = (w & 1) * 64;
    const int lr = lane & 15, lk = lane >> 4;

    const int ar = tid >> 2, aseg = (tid & 3) * 8;   // A stage: 64 rows x 32 k
    const int br = tid >> 1, bseg = (tid & 1) * 16;  // B stage: 128 rows x 32 k

    f4v acc[2][4];
    #pragma unroll
    for (int i = 0; i < 2; ++i)
        #pragma unroll
        for (int j = 0; j < 4; ++j) acc[i][j] = (f4v){0.f, 0.f, 0.f, 0.f};

    for (int k0 = 0; k0 < K; k0 += 32) {
        {
            const float* ap = A + (size_t)(m0 + ar) * K + k0 + aseg;
            float4 a0 = *(const float4*)ap;
            float4 a1 = *(const float4*)(ap + 4);
            h8v ha;
            ha[0] = (half_t)a0.x; ha[1] = (half_t)a0.y;
            ha[2] = (half_t)a0.z; ha[3] = (half_t)a0.w;
            ha[4] = (half_t)a1.x; ha[5] = (half_t)a1.y;
            ha[6] = (half_t)a1.z; ha[7] = (half_t)a1.w;
            *(h8v*)&As[ar * 40 + aseg] = ha;

            const float* bp = Bm + (size_t)(n0 + br) * K + k0 + bseg;
            float4 b0 = *(const float4*)bp;
            float4 b1 = *(const float4*)(bp + 4);
            float4 b2 = *(const float4*)(bp + 8);
            float4 b3 = *(const float4*)(bp + 12);
            h8v hb0, hb1;
            hb0[0] = (half_t)b0.x; hb0[1] = (half_t)b0.y;
            hb0[2] = (half_t)b0.z; hb0[3] = (half_t)b0.w;
            hb0[4] = (half_t)b1.x; hb0[5] = (half_t)b1.y;
            hb0[6] = (half_t)b1.z; hb0[7] = (half_t)b1.w;
            hb1[0] = (half_t)b2.x; hb1[1] = (half_t)b2.y;
            hb1[2] = (half_t)b2.z; hb1[3] = (half_t)b2.w;
            hb1[4] = (half_t)b3.x; hb1[5] = (half_t)b3.y;
            hb1[6] = (half_t)b3.z; hb1[7] = (half_t)b3.w;
            *(h8v*)&Bs[br * 40 + bseg] = hb0;
            *(h8v*)&Bs[br * 40 + bseg + 8] = hb1;
        }
        __syncthreads();
        h8v af[2], bfr[4];
        #pragma unroll
        for (int i = 0; i < 2; ++i)
            af[i] = *(const h8v*)&As[(wm + i * 16 + lr) * 40 + lk * 8];
        #pragma unroll
        for (int j = 0; j < 4; ++j)
            bfr[j] = *(const h8v*)&Bs[(wn + j * 16 + lr) * 40 + lk * 8];
        #pragma unroll
        for (int i = 0; i < 2; ++i)
            #pragma unroll
            for (int j = 0; j < 4; ++j)
                acc[i][j] = __builtin_amdgcn_mfma_f32_16x16x32_f16(af[i], bfr[j], acc[i][j], 0, 0, 0);
        __syncthreads();
    }

    // Epilogue: C/D col=lane&15, row=(lane>>4)*4+reg; fp16 store.
    #pragma unroll
    for (int j = 0; j < 4; ++j) {
        int n = n0 + wn + j * 16 + lr;
        float bv = bias[n];
        #pragma unroll
        for (int i = 0; i < 2; ++i) {
            #pragma unroll
            for (int r = 0; r < 4; ++r) {
                int m = m0 + wm + i * 16 + lk * 4 + r;
                C[(size_t)m * N + n] = (half_t)fmaxf(acc[i][j][r] + bv, 0.f);
            }
        }
    }
}

// ---------------------------------------------------------------------------
// Fuse dec (linear 256->3136) with convt1 (convT 64->32 k4 s2 p1).
// Output rows PERMUTED channel-minor: Wf[(p*32+o)][k], bf[p*32+o].
// ---------------------------------------------------------------------------
__global__ __launch_bounds__(256) void k_fuse(
    const float* __restrict__ wt1, const float* __restrict__ upt1_b,
    const float* __restrict__ dec_w, const float* __restrict__ dec_b,
    float* __restrict__ Wf, float* __restrict__ bf)
{
    const int n = blockIdx.x;
    const int k = threadIdx.x;
    const int o = n / 196, p = n % 196, y = p / 14, x = p % 14;
    float acc = 0.f, bacc = 0.f;
    for (int ky = 0; ky < 4; ++ky) {
        int iyn = y + 1 - ky;
        if (iyn < 0 || (iyn & 1)) continue;
        int iy = iyn >> 1;
        if (iy > 6) continue;
        for (int kx = 0; kx < 4; ++kx) {
            int ixn = x + 1 - kx;
            if (ixn < 0 || (ixn & 1)) continue;
            int ix = ixn >> 1;
            if (ix > 6) continue;
            for (int c = 0; c < 64; ++c) {
                float w = wt1[((c * 32 + o) * 4 + ky) * 4 + kx];
                int row = c * 49 + iy * 7 + ix;
                acc  = fmaf(w, dec_w[(size_t)row * 256 + k], acc);
                bacc = fmaf(w, dec_b[row], bacc);
            }
        }
    }
    Wf[(size_t)(p * 32 + o) * 256 + k] = acc;
    if (k == 0) bf[p * 32 + o] = bacc + upt1_b[o];
}

// ---------------------------------------------------------------------------
__global__ __launch_bounds__(256) void k_mnorm(const float* __restrict__ mem, float* __restrict__ inv_norm)
{
    __shared__ float red[256];
    const int row = blockIdx.x, tid = threadIdx.x;
    float v = mem[(size_t)row * 256 + tid];
    red[tid] = v * v;
    __syncthreads();
    for (int s = 128; s > 0; s >>= 1) {
        if (tid < s) red[tid] += red[tid + s];
        __syncthreads();
    }
    if (tid == 0) inv_norm[row] = 1.f / fmaxf(sqrtf(red[0]), 1e-12f);
}

// ---------------------------------------------------------------------------
__global__ __launch_bounds__(256) void k_memread(
    const float* __restrict__ latent, const float* __restrict__ dots,
    const float* __restrict__ inv_mn, const float* __restrict__ mem,
    float* __restrict__ out)
{
    __shared__ float red[256];
    __shared__ int   redi[256];
    __shared__ float inv_x_s;
    const int b = blockIdx.x, tid = threadIdx.x;
    float lx = latent[(size_t)b * 256 + tid];
    red[tid] = lx * lx;
    __syncthreads();
    for (int s = 128; s > 0; s >>= 1) {
        if (tid < s) red[tid] += red[tid + s];
        __syncthreads();
    }
    if (tid == 0) inv_x_s = 1.f / fmaxf(sqrtf(red[0]), 1e-12f);
    __syncthreads();
    const float inv_x = inv_x_s;

    float vals[16];
    for (int j = 0; j < 16; ++j) {
        int m = tid + j * 256;
        vals[j] = dots[(size_t)b * 4096 + m] * inv_mn[m] * inv_x;
    }
    float tv[10]; int ti[10];
    for (int t = 0; t < 10; ++t) {
        float bv = -1e30f; int bidx = 0x7fffffff;
        for (int j = 0; j < 16; ++j) {
            int m = tid + j * 256;
            float v = vals[j];
            if (v > bv || (v == bv && m < bidx)) { bv = v; bidx = m; }
        }
        red[tid] = bv; redi[tid] = bidx;
        __syncthreads();
        for (int s = 128; s > 0; s >>= 1) {
            if (tid < s) {
                float v2 = red[tid + s]; int i2 = redi[tid + s];
                if (v2 > red[tid] || (v2 == red[tid] && i2 < redi[tid])) { red[tid] = v2; redi[tid] = i2; }
            }
            __syncthreads();
        }
        int sel = redi[0];
        tv[t] = red[0]; ti[t] = sel;
        if ((sel & 255) == tid) vals[sel >> 8] = -1e30f;
        __syncthreads();
    }
    float w[10], wsum = 0.f;
    for (int t = 0; t < 10; ++t) { w[t] = expf(tv[t] - tv[0]); wsum += w[t]; }
    float inv_ws = 1.f / wsum;
    float acc = 0.f;
    for (int t = 0; t < 10; ++t) acc += (w[t] * inv_ws) * mem[(size_t)ti[t] * 256 + tid];
    out[(size_t)b * 256 + tid] = acc;
}

// ---------------------------------------------------------------------------
// Weight repack.
//   pk2h[((tap*2+nt)*16+oc)*32+ic] fp16  from c1_w [32][32][3][3] (MFMA B)
//   pk3h[((q*4+t)*16+oc)*32+ic]   fp16  from upt2_w [32][16][4][4] (MFMA B;
//       t=(wy,wx), q=(py,px), ky=3-py-2wy, kx=3-px-2wx — same verified map)
//   pk4[c16][tap9][o8]                   from c2_w   [8][16][3][3]
//   pk5[blk2][j128][c32]                 from blk_ff2_w [2][32][128]
// ---------------------------------------------------------------------------
__global__ __launch_bounds__(256) void k_pack(
    const float* __restrict__ wc1, const float* __restrict__ wt2,
    const float* __restrict__ wc2, const float* __restrict__ w2src,
    half_t* __restrict__ pk2h, half_t* __restrict__ pk3h,
    float* __restrict__ pk4, float* __restrict__ pk5)
{
    int i = blockIdx.x * 256 + threadIdx.x;
    if (i < 9216) {
        int ic = i & 31, oc = (i >> 5) & 15, nt = (i >> 9) & 1, t = i >> 10;
        pk2h[i] = (half_t)wc1[((nt * 16 + oc) * 32 + ic) * 9 + t];
    }
    if (i < 8192) {
        int ic = i & 31, oc = (i >> 5) & 15, t = (i >> 9) & 3, q = i >> 11;
        int wy = t >> 1, wx = t & 1, py = q >> 1, px = q & 1;
        int ky = 3 - py - 2 * wy, kx = 3 - px - 2 * wx;
        pk3h[i] = (half_t)wt2[((ic * 16 + oc) * 4 + ky) * 4 + kx];
    }
    if (i < 1152) {
        int o = i & 7, tap = (i >> 3) % 9, c = i / 72;
        pk4[i] = wc2[(o * 16 + c) * 9 + tap];
    }
    if (i < 8192) {
        int c = i & 31, j = (i >> 5) & 127, bq = i >> 12;
        pk5[i] = w2src[bq * 4096 + c * 128 + j];
    }
}

// ---------------------------------------------------------------------------
// Conv2d 32->32 k3 p1, 14x14, ReLU — MFMA. 2 samples/block.
// Output d2h fp16 channel-minor [sample][196][32] (feeds MFMA convt2).
// ---------------------------------------------------------------------------
__global__ __launch_bounds__(256) void k_conv1(
    const half_t* __restrict__ in, const half_t* __restrict__ wh,
    const float* __restrict__ bias, half_t* __restrict__ out)
{
    __shared__ __align__(16) half_t P[2 * 16 * 16 * 40];   // 40960 B
    const int tid = threadIdx.x;
    const int w = tid >> 6, lane = tid & 63;
    const size_t b0 = (size_t)blockIdx.x * 2;

    for (int e = tid; e < 10240; e += 256) ((unsigned int*)P)[e] = 0u;
    __syncthreads();
    {
        const unsigned int* src = (const unsigned int*)in;
        for (int e = tid; e < 6272; e += 256) {
            int si = e / 3136;
            int rem = e - si * 3136;
            int p = rem >> 4, c2 = rem & 15;
            int y = p / 14, x = p % 14;
            ((unsigned int*)P)[si * 5120 + ((y + 1) * 16 + (x + 1)) * 20 + c2] =
                src[(b0 + si) * 3136 + rem];
        }
    }

    h8v bfr[9][2];
    #pragma unroll
    for (int t = 0; t < 9; ++t)
        #pragma unroll
        for (int nt = 0; nt < 2; ++nt)
            bfr[t][nt] = *(const h8v*)&wh[((size_t)((t * 2 + nt) * 16 + (lane & 15))) * 32 + (lane >> 4) * 8];

    __syncthreads();

    const int kseg = (lane >> 4) * 8;
    const int oc = lane & 15;
    const float bv0 = bias[oc], bv1 = bias[16 + oc];

    for (int job = w; job < 26; job += 4) {
        const int si = job >= 13 ? 1 : 0;
        const int tile = job - si * 13;
        int p = tile * 16 + (lane & 15);
        if (p > 195) p = 195;
        const int y = p / 14, x = p % 14;
        const half_t* Pb = P + si * 10240;

        f4v acc0 = (f4v){0.f, 0.f, 0.f, 0.f};
        f4v acc1 = (f4v){0.f, 0.f, 0.f, 0.f};
        #pragma unroll
        for (int ky = 0; ky < 3; ++ky) {
            #pragma unroll
            for (int kx = 0; kx < 3; ++kx) {
                h8v af = *(const h8v*)&Pb[((y + ky) * 16 + (x + kx)) * 40 + kseg];
                acc0 = __builtin_amdgcn_mfma_f32_16x16x32_f16(af, bfr[ky * 3 + kx][0], acc0, 0, 0, 0);
                acc1 = __builtin_amdgcn_mfma_f32_16x16x32_f16(af, bfr[ky * 3 + kx][1], acc1, 0, 0, 0);
            }
        }

        const int pr0 = tile * 16 + (lane >> 4) * 4;
        half_t* ob = out + (b0 + si) * 6272;
        #pragma unroll
        for (int r = 0; r < 4; ++r) {
            int pp = pr0 + r;
            if (pp < 196) {
                ob[(size_t)pp * 32 + oc]      = (half_t)fmaxf(acc0[r] + bv0, 0.f);
                ob[(size_t)pp * 32 + 16 + oc] = (half_t)fmaxf(acc1[r] + bv1, 0.f);
            }
        }
    }
}

// ---------------------------------------------------------------------------
// FUSED: ConvTranspose2d 32->16 k4 s2 p1 (MFMA) + Conv2d 16->8 k3 p1 (ReLU)
//        + Conv2d 8->1 k1. One sample/block.
// convt2 per parity-quadrant q: out[q-pixel][16oc] = sum of 4 taps, each a
// K=32 MFMA on the haloed [16][16][40-half] d2h tile (same recipe as conv1;
// input pixel = (ty+py+wy, tx+px+wx), verified fp32 mapping re-indexed).
// All 52 (q,tile) jobs' results kept in registers (13 f4v/lane), so the fp32
// [8][30][32] group tile OVERLAYS the dead input tile: LDS = 30720 B.
// Phases conv2+conv3 unchanged fp32.
// ---------------------------------------------------------------------------
__global__ __launch_bounds__(256) void k_convt23(
    const half_t* __restrict__ in, const half_t* __restrict__ pk3h,
    const float* __restrict__ bt2, const float* __restrict__ pk4,
    const float* __restrict__ b2, const float* __restrict__ w3,
    const float* __restrict__ b3, float* __restrict__ out)
{
    __shared__ __align__(16) unsigned char Lraw[30720];
    half_t* Pin = (half_t*)Lraw;     // [16][16][40] halves = 20480 B
    float*  P2  = (float*)Lraw;      // [8][30][32] floats = 30720 B (overlay)
    const int tid = threadIdx.x;
    const int w = tid >> 6, lane = tid & 63;
    const int b = blockIdx.x;

    // stage d2h into zero-haloed tile
    for (int e = tid; e < 5120; e += 256) ((unsigned int*)Pin)[e] = 0u;
    __syncthreads();
    {
        const unsigned int* src = (const unsigned int*)in;
        for (int e = tid; e < 3136; e += 256) {
            int p = e >> 4, c2 = e & 15;
            int y = p / 14, x = p % 14;
            ((unsigned int*)Pin)[((y + 1) * 16 + (x + 1)) * 20 + c2] =
                src[(size_t)b * 3136 + e];
        }
    }
    __syncthreads();

    const int oc = lane & 15;
    const int kseg = (lane >> 4) * 8;

    // MFMA convt2: 52 jobs (q=py*2+px, tile), 13/wave, results in registers
    f4v res[13];
    #pragma unroll
    for (int j = 0; j < 13; ++j) {
        const int job = w + 4 * j;
        const int q = job / 13, tile = job - q * 13;
        const int py = q >> 1, px = q & 1;
        int p = tile * 16 + (lane & 15);
        if (p > 195) p = 195;
        const int ty = p / 14, tx = p % 14;
        f4v a = (f4v){0.f, 0.f, 0.f, 0.f};
        #pragma unroll
        for (int t = 0; t < 4; ++t) {
            const int wy = t >> 1, wx = t & 1;
            h8v bf = *(const h8v*)&pk3h[((size_t)((q * 4 + t) * 16 + oc)) * 32 + kseg];
            h8v af = *(const h8v*)&Pin[((ty + py + wy) * 16 + (tx + px + wx)) * 40 + kseg];
            a = __builtin_amdgcn_mfma_f32_16x16x32_f16(af, bf, a, 0, 0, 0);
        }
        res[j] = a;
    }
    __syncthreads();   // all input-tile reads done; overlay safe

    // ---- conv2 (16->8, k3, ReLU) over two 8-oc groups + conv3 ----
    const bool active2 = tid < 196;
    int row = active2 ? tid / 7 : 0;
    int tx0b = active2 ? (tid % 7) * 4 : 0;
    const float bco = bt2[oc];

    float acc2[4][8];
    #pragma unroll
    for (int i = 0; i < 4; ++i)
        #pragma unroll
        for (int o = 0; o < 8; ++o) acc2[i][o] = 0.f;

    #pragma unroll
    for (int g = 0; g < 2; ++g) {
        for (int e = tid; e < 7680; e += 256) P2[e] = 0.f;
        __syncthreads();
        if ((oc >> 3) == g) {
            #pragma unroll
            for (int j = 0; j < 13; ++j) {
                const int job = w + 4 * j;
                const int q = job / 13, tile = job - q * 13;
                const int py = q >> 1, px = q & 1;
                const int pr0 = tile * 16 + (lane >> 4) * 4;
                #pragma unroll
                for (int r = 0; r < 4; ++r) {
                    int p = pr0 + r;
                    if (p < 196) {
                        int Y = 2 * (p / 14) + py, X = 2 * (p % 14) + px;
                        P2[((oc & 7) * 30 + Y + 1) * 32 + (X + 1)] = fmaxf(res[j][r] + bco, 0.f);
                    }
                }
            }
        }
        __syncthreads();
        for (int cl = 0; cl < 8; ++cl) {
            const float* Pb = &P2[(cl * 30 + row) * 32 + tx0b];
            const float* wb = pk4 + (size_t)(g * 8 + cl) * 72;
            #pragma unroll
            for (int ky = 0; ky < 3; ++ky) {
                float4 a = *(const float4*)&Pb[ky * 32];
                float4 bq = *(const float4*)&Pb[ky * 32 + 4];
                float rowb[8] = {a.x, a.y, a.z, a.w, bq.x, bq.y, bq.z, bq.w};
                #pragma unroll
                for (int kx = 0; kx < 3; ++kx) {
                    const float* wt = wb + (ky * 3 + kx) * 8;
                    #pragma unroll
                    for (int o = 0; o < 8; ++o) {
                        float wv = wt[o];
                        #pragma unroll
                        for (int i = 0; i < 4; ++i)
                            acc2[i][o] = fmaf(rowb[i + kx], wv, acc2[i][o]);
                    }
                }
            }
        }
        __syncthreads();   // group tile fully consumed before next zero-fill
    }

    if (active2) {
        const float bias3 = b3[0];
        #pragma unroll
        for (int i = 0; i < 4; ++i) {
            float r = bias3;
            #pragma unroll
            for (int o = 0; o < 8; ++o) r += fmaxf(acc2[i][o] + b2[o], 0.f) * w3[o];
            out[(size_t)b * 784 + row * 28 + tx0b + i] = r;
        }
    }
}

// ---------------------------------------------------------------------------
extern "C" void kernel_launch(void* const* d_in, const int* in_sizes, int n_in,
                              void* d_out, int out_size, void* d_ws, size_t ws_size,
                              hipStream_t stream)
{
    const float* x       = (const float*)d_in[0];
    const float* patch_w = (const float*)d_in[1];
    const float* patch_b = (const float*)d_in[2];
    const float* ln1g    = (const float*)d_in[3];
    const float* ln1b    = (const float*)d_in[4];
    const float* wi      = (const float*)d_in[5];
    const float* bi      = (const float*)d_in[6];
    const float* wo      = (const float*)d_in[7];
    const float* bo      = (const float*)d_in[8];
    const float* ln2g    = (const float*)d_in[9];
    const float* ln2b    = (const float*)d_in[10];
    const float* w1      = (const float*)d_in[11];
    const float* b1      = (const float*)d_in[12];
    const float* w2      = (const float*)d_in[13];
    const float* b2      = (const float*)d_in[14];
    const float* lat_w   = (const float*)d_in[15];
    const float* lat_b   = (const float*)d_in[16];
    const float* memory  = (const float*)d_in[17];
    const float* dec_w   = (const float*)d_in[18];
    const float* dec_b   = (const float*)d_in[19];
    const float* upt1_w  = (const float*)d_in[20];
    const float* upt1_b  = (const float*)d_in[21];
    const float* c1_w    = (const float*)d_in[22];
    const float* c1_b    = (const float*)d_in[23];
    const float* upt2_w  = (const float*)d_in[24];
    const float* upt2_b  = (const float*)d_in[25];
    const float* c2_w    = (const float*)d_in[26];
    const float* c2_b    = (const float*)d_in[27];
    const float* c3_w    = (const float*)d_in[28];
    const float* c3_b    = (const float*)d_in[29];
    float* outp = (float*)d_out;

    float* ws = (float*)d_ws;
    size_t off = 0;
    auto alloc = [&](size_t n) { float* p = ws + off; off += (n + 63) & ~(size_t)63; return p; };
    float* tokens     = alloc((size_t)B_TOT * 1568);
    float* latent     = alloc((size_t)B_TOT * 256);
    float* dots       = alloc((size_t)B_TOT * 4096);
    float* mem_latent = alloc((size_t)B_TOT * 256);
    float* inv_mn     = alloc(4096);
    half_t* pk2h      = (half_t*)alloc(4608);
    half_t* pk3h      = (half_t*)alloc(4096);
    float* pk4        = alloc(1152);
    float* pk5        = alloc(8192);
    float* Wf         = alloc((size_t)6272 * 256);
    float* bf         = alloc(6272);
    half_t* d1h       = (half_t*)alloc((size_t)CHUNK * 6272 / 2);
    half_t* d2h       = (half_t*)alloc((size_t)CHUNK * 6272 / 2);
    (void)in_sizes; (void)n_in; (void)out_size; (void)ws_size;

    // Weight repack + dec/convt1 algebraic fusion (Wf rows channel-minor)
    k_pack<<<36, 256, 0, stream>>>(c1_w, upt2_w, c2_w, w2, pk2h, pk3h, pk4, pk5);
    k_fuse<<<6272, 256, 0, stream>>>(upt1_w, upt1_b, dec_w, dec_b, Wf, bf);

    // Encoder (wave-per-sample)
    k_tokens<<<B_TOT / 4, 256, 0, stream>>>(x, patch_w, patch_b, ln1g, ln1b, wi, bi,
                                            wo, bo, ln2g, ln2b, w1, b1, pk5, b2, tokens);
    k_gemm<<<dim3(256 / 64, B_TOT / 128), 256, 0, stream>>>(tokens, lat_w, lat_b, latent,
                                                            B_TOT, 256, 1568, 0);
    k_mnorm<<<4096, 256, 0, stream>>>(memory, inv_mn);
    k_gemm<<<dim3(4096 / 64, B_TOT / 128), 256, 0, stream>>>(latent, memory, nullptr, dots,
                                                             B_TOT, 4096, 256, 0);
    k_memread<<<B_TOT, 256, 0, stream>>>(latent, dots, inv_mn, memory, mem_latent);

    // Decoder, chunked. MFMA GEMM -> d1h; MFMA conv1 -> d2h (fp16 ch-minor);
    // MFMA convt2 + fp32 conv2/conv3 -> output.
    for (int c = 0; c < B_TOT / CHUNK; ++c) {
        const float* ml = mem_latent + (size_t)c * CHUNK * 256;
        k_dgemm<<<dim3(6272 / 128, CHUNK / 64), 256, 0, stream>>>(ml, Wf, bf, d1h,
                                                                  CHUNK, 6272, 256);
        k_conv1  <<<CHUNK / 2, 256, 0, stream>>>(d1h, pk2h, c1_b, d2h);
        k_convt23<<<CHUNK, 256, 0, stream>>>(d2h, pk3h, upt2_b, pk4, c2_b, c3_w, c3_b,
                                             outp + (size_t)c * CHUNK * 784);
    }
}

// Round 13
// 1201.749 us; speedup vs baseline: 1.5592x; 1.0772x over previous
//
#include <hip/hip_runtime.h>
#include <math.h>

#define B_TOT 4096
#define CHUNK 4096

typedef _Float16 half_t;
typedef _Float16 h2 __attribute__((ext_vector_type(2)));
typedef _Float16 h8v __attribute__((ext_vector_type(8)));
typedef float f4v __attribute__((ext_vector_type(4)));

#if __has_builtin(__builtin_amdgcn_fdot2)
#define FDOT2(a, b, c) __builtin_amdgcn_fdot2((a), (b), (c), false)
#else
#define FDOT2(a, b, c) fmaf((float)(a)[1], (float)(b)[1], fmaf((float)(a)[0], (float)(b)[0], (c)))
#endif

// k_tokens LDS: K 49x36 halves fp16, V 49x34 floats fp32 per wave; wi slot.
// V stays fp32 (round-4: fp16 V broke accuracy). Decoder (downstream of topk)
// is fp16-MFMA end to end (validated r10-r12). latent/dots GEMMs stay fp32
// (upstream of topk — even 1e-5-scale sim perturbations risk selection flips).
#define KSTR 36
#define VSTR 34
#define KBYTES (49 * 72)
#define WAVE_LDS (49 * 72 + 49 * 136)  // 10192
#define WI_OFF  (4 * WAVE_LDS)         // 40768
#define BLOCK_LDS (WI_OFF + 12288)     // 53056

// ---------------------------------------------------------------------------
// Fused: patch conv (1->32, k4 s4) + 2 transformer blocks.
// ---------------------------------------------------------------------------
__global__ __launch_bounds__(256) void k_tokens(
    const float* __restrict__ x, const float* __restrict__ pw, const float* __restrict__ pb,
    const float* __restrict__ ln1g, const float* __restrict__ ln1b,
    const float* __restrict__ wi, const float* __restrict__ bi,
    const float* __restrict__ wo, const float* __restrict__ bo,
    const float* __restrict__ ln2g, const float* __restrict__ ln2b,
    const float* __restrict__ w1, const float* __restrict__ fb1,
    const float* __restrict__ w2t, const float* __restrict__ fb2,
    float* __restrict__ tokens)
{
    __shared__ __align__(16) unsigned char Lraw[BLOCK_LDS];
    const int tid = threadIdx.x;
    const int wv = tid >> 6, lane = tid & 63;
    const int b = blockIdx.x * 4 + wv;
    half_t* Kb = (half_t*)(Lraw + wv * WAVE_LDS);
    float*  Vb = (float*)(Lraw + wv * WAVE_LDS + KBYTES);
    const float* wiL = (const float*)(Lraw + WI_OFF);
    float* Lf = (float*)Lraw;            // FF-weight overlay (block-wide)
    const bool is_tok = lane < 49;
    const int s = is_tok ? lane : 48;
    const int py = s / 7, px = s % 7;

    // --- prologue: stage blk-0 qkv weights (visible after barrier (A)) ---
    {
        const float4* srcw = (const float4*)(wi);
        float4* dstw = (float4*)(Lraw + WI_OFF);
        for (int e = tid; e < 768; e += 256) dstw[e] = srcw[e];
    }

    // --- patch conv: direct float4 loads (rows are 16B-aligned) ---
    float xv[16];
    const float* xb = x + (size_t)b * 784 + py * 112 + px * 4;
    #pragma unroll
    for (int r = 0; r < 4; ++r) {
        float4 vq = *(const float4*)(xb + r * 28);
        xv[4 * r + 0] = vq.x; xv[4 * r + 1] = vq.y;
        xv[4 * r + 2] = vq.z; xv[4 * r + 3] = vq.w;
    }
    float t[32];
    #pragma unroll 4
    for (int c = 0; c < 32; ++c) {
        float a = pb[c];
        const float* wr = pw + c * 16;
        #pragma unroll
        for (int i = 0; i < 16; ++i) a = fmaf(xv[i], wr[i], a);
        t[c] = a;
    }

    for (int blk = 0; blk < 2; ++blk) {
        const float* bib = bi + blk * 96;

        // --- LN1 ---
        float mu = 0.f;
        #pragma unroll
        for (int c = 0; c < 32; ++c) mu += t[c];
        mu *= 0.03125f;
        float var = 0.f;
        #pragma unroll
        for (int c = 0; c < 32; ++c) { float d = t[c] - mu; var = fmaf(d, d, var); }
        float rstd = rsqrtf(var * 0.03125f + 1e-5f);
        float xn[32];
        #pragma unroll
        for (int c = 0; c < 32; ++c)
            xn[c] = (t[c] - mu) * rstd * ln1g[blk * 32 + c] + ln1b[blk * 32 + c];

        __syncthreads();   // (A) prior-phase LDS reads done; wi stage visible

        // --- K projection -> LDS fp16 (broadcast b128 weight reads) ---
        #pragma unroll 4
        for (int d = 0; d < 32; ++d) {
            const float* wr = wiL + (32 + d) * 32;
            float a0 = bib[32 + d], a1 = 0.f;
            #pragma unroll
            for (int c2 = 0; c2 < 4; ++c2) {
                float4 wq = *(const float4*)&wr[4 * c2];
                a0 = fmaf(xn[4 * c2],     wq.x, a0);
                a0 = fmaf(xn[4 * c2 + 1], wq.y, a0);
                a0 = fmaf(xn[4 * c2 + 2], wq.z, a0);
                a0 = fmaf(xn[4 * c2 + 3], wq.w, a0);
            }
            #pragma unroll
            for (int c2 = 4; c2 < 8; ++c2) {
                float4 wq = *(const float4*)&wr[4 * c2];
                a1 = fmaf(xn[4 * c2],     wq.x, a1);
                a1 = fmaf(xn[4 * c2 + 1], wq.y, a1);
                a1 = fmaf(xn[4 * c2 + 2], wq.z, a1);
                a1 = fmaf(xn[4 * c2 + 3], wq.w, a1);
            }
            if (is_tok) Kb[s * KSTR + d] = (half_t)(a0 + a1);
        }
        // --- V projection -> LDS fp32 ---
        #pragma unroll 4
        for (int d = 0; d < 32; ++d) {
            const float* wr = wiL + (64 + d) * 32;
            float a0 = bib[64 + d], a1 = 0.f;
            #pragma unroll
            for (int c2 = 0; c2 < 4; ++c2) {
                float4 wq = *(const float4*)&wr[4 * c2];
                a0 = fmaf(xn[4 * c2],     wq.x, a0);
                a0 = fmaf(xn[4 * c2 + 1], wq.y, a0);
                a0 = fmaf(xn[4 * c2 + 2], wq.z, a0);
                a0 = fmaf(xn[4 * c2 + 3], wq.w, a0);
            }
            #pragma unroll
            for (int c2 = 4; c2 < 8; ++c2) {
                float4 wq = *(const float4*)&wr[4 * c2];
                a1 = fmaf(xn[4 * c2],     wq.x, a1);
                a1 = fmaf(xn[4 * c2 + 1], wq.y, a1);
                a1 = fmaf(xn[4 * c2 + 2], wq.z, a1);
                a1 = fmaf(xn[4 * c2 + 3], wq.w, a1);
            }
            if (is_tok) Vb[s * VSTR + d] = a0 + a1;
        }
        // --- Q projection (scaled), packed to half2 for fdot2 ---
        float q0[32];
        #pragma unroll 4
        for (int d = 0; d < 32; ++d) {
            const float* wr = wiL + d * 32;
            float a0 = bib[d], a1 = 0.f;
            #pragma unroll
            for (int c2 = 0; c2 < 4; ++c2) {
                float4 wq = *(const float4*)&wr[4 * c2];
                a0 = fmaf(xn[4 * c2],     wq.x, a0);
                a0 = fmaf(xn[4 * c2 + 1], wq.y, a0);
                a0 = fmaf(xn[4 * c2 + 2], wq.z, a0);
                a0 = fmaf(xn[4 * c2 + 3], wq.w, a0);
            }
            #pragma unroll
            for (int c2 = 4; c2 < 8; ++c2) {
                float4 wq = *(const float4*)&wr[4 * c2];
                a1 = fmaf(xn[4 * c2],     wq.x, a1);
                a1 = fmaf(xn[4 * c2 + 1], wq.y, a1);
                a1 = fmaf(xn[4 * c2 + 2], wq.z, a1);
                a1 = fmaf(xn[4 * c2 + 3], wq.w, a1);
            }
            q0[d] = (a0 + a1) * 0.25f;
        }
        h2 qh[16];
        #pragma unroll
        for (int i = 0; i < 16; ++i) {
            h2 hh; hh[0] = (half_t)q0[2 * i]; hh[1] = (half_t)q0[2 * i + 1];
            qh[i] = hh;
        }

        // wave-local fence: own K/V ds_writes visible before broadcast reads
        __asm__ volatile("s_waitcnt lgkmcnt(0)" ::: "memory");

        // --- attention: 2 heads of 16 dims, softmax without running max ---
        float o[32];
        #pragma unroll
        for (int d = 0; d < 32; ++d) o[d] = 0.f;
        float l0 = 0.f, l1 = 0.f;
        union H4 { double qd; h2 p[2]; };
        for (int j = 0; j < 49; ++j) {
            const double* kr = (const double*)(Kb + j * KSTR);
            const float* vr = Vb + j * VSTR;
            H4 u0, u1, u2, u3, w0, w1h, w2h, w3;
            u0.qd = kr[0]; u1.qd = kr[1]; u2.qd = kr[2]; u3.qd = kr[3];
            w0.qd = kr[4]; w1h.qd = kr[5]; w2h.qd = kr[6]; w3.qd = kr[7];
            float s0a = 0.f, s0b = 0.f, s1a = 0.f, s1b = 0.f;
            s0a = FDOT2(u0.p[0], qh[0], s0a); s0a = FDOT2(u0.p[1], qh[1], s0a);
            s0b = FDOT2(u1.p[0], qh[2], s0b); s0b = FDOT2(u1.p[1], qh[3], s0b);
            s0a = FDOT2(u2.p[0], qh[4], s0a); s0a = FDOT2(u2.p[1], qh[5], s0a);
            s0b = FDOT2(u3.p[0], qh[6], s0b); s0b = FDOT2(u3.p[1], qh[7], s0b);
            s1a = FDOT2(w0.p[0], qh[8], s1a); s1a = FDOT2(w0.p[1], qh[9], s1a);
            s1b = FDOT2(w1h.p[0], qh[10], s1b); s1b = FDOT2(w1h.p[1], qh[11], s1b);
            s1a = FDOT2(w2h.p[0], qh[12], s1a); s1a = FDOT2(w2h.p[1], qh[13], s1a);
            s1b = FDOT2(w3.p[0], qh[14], s1b); s1b = FDOT2(w3.p[1], qh[15], s1b);
            float p0 = __expf(s0a + s0b), p1 = __expf(s1a + s1b);
            l0 += p0; l1 += p1;
            #pragma unroll
            for (int i = 0; i < 8; ++i) {
                float2 va = *(const float2*)&vr[2 * i];
                o[2 * i]     = fmaf(p0, va.x, o[2 * i]);
                o[2 * i + 1] = fmaf(p0, va.y, o[2 * i + 1]);
                float2 vc = *(const float2*)&vr[16 + 2 * i];
                o[16 + 2 * i]     = fmaf(p1, vc.x, o[16 + 2 * i]);
                o[16 + 2 * i + 1] = fmaf(p1, vc.y, o[16 + 2 * i + 1]);
            }
        }
        float il0 = 1.f / l0, il1 = 1.f / l1;
        #pragma unroll
        for (int d = 0; d < 16; ++d) { o[d] *= il0; o[16 + d] *= il1; }

        // --- out projection + residual (wave-uniform global weights, 4 KB) ---
        #pragma unroll
        for (int c = 0; c < 32; ++c) {
            const float* wr = wo + blk * 1024 + c * 32;
            float a = bo[blk * 32 + c];
            #pragma unroll
            for (int k2 = 0; k2 < 32; ++k2) a = fmaf(o[k2], wr[k2], a);
            t[c] += a;
        }

        // --- LN2 ---
        mu = 0.f;
        #pragma unroll
        for (int c = 0; c < 32; ++c) mu += t[c];
        mu *= 0.03125f;
        var = 0.f;
        #pragma unroll
        for (int c = 0; c < 32; ++c) { float d = t[c] - mu; var = fmaf(d, d, var); }
        rstd = rsqrtf(var * 0.03125f + 1e-5f);
        #pragma unroll
        for (int c = 0; c < 32; ++c)
            xn[c] = (t[c] - mu) * rstd * ln2g[blk * 32 + c] + ln2b[blk * 32 + c];

        __syncthreads();   // (C) all waves done reading K/V + wi

        // --- stage FF weights (overlay over KV) + next blk's wi ---
        {
            const float4* src1 = (const float4*)(w1 + blk * 4096);
            const float4* src2 = (const float4*)(w2t + blk * 4096);
            float4* dst = (float4*)Lraw;
            for (int e = tid; e < 1024; e += 256) dst[e] = src1[e];
            for (int e = tid; e < 1024; e += 256) dst[1024 + e] = src2[e];
            if (blk == 0) {
                const float4* srcw = (const float4*)(wi + 3072);
                float4* dstw = (float4*)(Lraw + WI_OFF);
                for (int e = tid; e < 768; e += 256) dstw[e] = srcw[e];
            }
        }
        __syncthreads();   // (D) FF weights (and wi for blk1) visible

        // --- FF from LDS: broadcast ds_read_b128 rows ---
        const float* w2L = Lf + 4096;
        #pragma unroll 2
        for (int j = 0; j < 128; ++j) {
            const float* wr = Lf + j * 32;
            float ha = fb1[blk * 128 + j], hb = 0.f;
            #pragma unroll
            for (int c2 = 0; c2 < 4; ++c2) {
                float4 wq = *(const float4*)&wr[4 * c2];
                ha = fmaf(xn[4 * c2],     wq.x, ha);
                ha = fmaf(xn[4 * c2 + 1], wq.y, ha);
                ha = fmaf(xn[4 * c2 + 2], wq.z, ha);
                ha = fmaf(xn[4 * c2 + 3], wq.w, ha);
            }
            #pragma unroll
            for (int c2 = 4; c2 < 8; ++c2) {
                float4 wq = *(const float4*)&wr[4 * c2];
                hb = fmaf(xn[4 * c2],     wq.x, hb);
                hb = fmaf(xn[4 * c2 + 1], wq.y, hb);
                hb = fmaf(xn[4 * c2 + 2], wq.z, hb);
                hb = fmaf(xn[4 * c2 + 3], wq.w, hb);
            }
            float h = ha + hb;
            h = 0.5f * h * (1.f + erff(h * 0.7071067811865476f));
            const float* w2r = w2L + j * 32;
            #pragma unroll
            for (int c2 = 0; c2 < 8; ++c2) {
                float4 wq = *(const float4*)&w2r[4 * c2];
                t[4 * c2]     = fmaf(h, wq.x, t[4 * c2]);
                t[4 * c2 + 1] = fmaf(h, wq.y, t[4 * c2 + 1]);
                t[4 * c2 + 2] = fmaf(h, wq.z, t[4 * c2 + 2]);
                t[4 * c2 + 3] = fmaf(h, wq.w, t[4 * c2 + 3]);
            }
        }
        #pragma unroll
        for (int c = 0; c < 32; ++c) t[c] += fb2[blk * 32 + c];
    }

    if (is_tok) {
        float* op = tokens + (size_t)b * 1568 + s * 32;
        #pragma unroll
        for (int c = 0; c < 32; c += 4) {
            float4 vv = make_float4(t[c], t[c + 1], t[c + 2], t[c + 3]);
            *(float4*)&op[c] = vv;
        }
    }
}

// ---------------------------------------------------------------------------
// C[M,N] = A[M,K] @ B[N,K]^T (+bias, optional ReLU). fp32, 128x64 tile.
// Used for the topk-upstream GEMMs (latent, dots) — must stay fp32.
// ---------------------------------------------------------------------------
__global__ __launch_bounds__(256) void k_gemm(
    const float* __restrict__ A, const float* __restrict__ Bm,
    const float* __restrict__ bias, float* __restrict__ C,
    int M, int N, int K, int relu)
{
    __shared__ float As[16 * 132];
    __shared__ float Bs[16 * 68];
    const int n0 = blockIdx.x * 64, m0 = blockIdx.y * 128;
    const int tid = threadIdx.x;
    const int tx = tid & 15, ty = tid >> 4;
    const int lr = tid >> 1, lk = (tid & 1) * 8;
    const int br = tid >> 2, bk = (tid & 3) * 4;
    float acc[8][4] = {{0.f}};
    for (int k0 = 0; k0 < K; k0 += 16) {
        float4 av0 = *(const float4*)&A[(size_t)(m0 + lr) * K + k0 + lk];
        float4 av1 = *(const float4*)&A[(size_t)(m0 + lr) * K + k0 + lk + 4];
        float4 bv0 = *(const float4*)&Bm[(size_t)(n0 + br) * K + k0 + bk];
        As[(lk + 0) * 132 + lr] = av0.x;
        As[(lk + 1) * 132 + lr] = av0.y;
        As[(lk + 2) * 132 + lr] = av0.z;
        As[(lk + 3) * 132 + lr] = av0.w;
        As[(lk + 4) * 132 + lr] = av1.x;
        As[(lk + 5) * 132 + lr] = av1.y;
        As[(lk + 6) * 132 + lr] = av1.z;
        As[(lk + 7) * 132 + lr] = av1.w;
        Bs[(bk + 0) * 68 + br] = bv0.x;
        Bs[(bk + 1) * 68 + br] = bv0.y;
        Bs[(bk + 2) * 68 + br] = bv0.z;
        Bs[(bk + 3) * 68 + br] = bv0.w;
        __syncthreads();
        #pragma unroll
        for (int k = 0; k < 16; ++k) {
            float4 a0 = *(const float4*)&As[k * 132 + ty * 8];
            float4 a1 = *(const float4*)&As[k * 132 + ty * 8 + 4];
            float4 bv = *(const float4*)&Bs[k * 68 + tx * 4];
            float a8[8] = {a0.x, a0.y, a0.z, a0.w, a1.x, a1.y, a1.z, a1.w};
            float b4[4] = {bv.x, bv.y, bv.z, bv.w};
            #pragma unroll
            for (int i = 0; i < 8; ++i)
                #pragma unroll
                for (int j = 0; j < 4; ++j)
                    acc[i][j] = fmaf(a8[i], b4[j], acc[i][j]);
        }
        __syncthreads();
    }
    #pragma unroll
    for (int i = 0; i < 8; ++i) {
        int m = m0 + ty * 8 + i;
        #pragma unroll
        for (int j = 0; j < 4; ++j) {
            int n = n0 + tx * 4 + j;
            float v = acc[i][j] + (bias ? bias[n] : 0.f);
            if (relu) v = fmaxf(v, 0.f);
            C[(size_t)m * N + n] = v;
        }
    }
}

// ---------------------------------------------------------------------------
// MFMA decoder GEMM: d1h[M,N] = (fp16)relu(A[M,K] @ B[N,K]^T + bias).
// ---------------------------------------------------------------------------
__global__ __launch_bounds__(256) void k_dgemm(
    const float* __restrict__ A, const float* __restrict__ Bm,
    const float* __restrict__ bias, half_t* __restrict__ C,
    int M, int N, int K)
{
    __shared__ __align__(16) half_t As[64 * 40];
    __shared__ __align__(16) half_t Bs[128 * 40];
    const int tid = threadIdx.x;
    const int n0 = blockIdx.x * 128, m0 = blockIdx.y * 64;
    const int w = tid >> 6, lane = tid & 63;
    const int wm = (w >> 1) * 32, wn = (w & 1) * 64;
    const int lr = lane & 15, lk = lane >> 4;

    const int ar = tid >> 2, aseg = (tid & 3) * 8;   // A stage: 64 rows x 32 k
    const int br = tid >> 1, bseg = (tid & 1) * 16;  // B stage: 128 rows x 32 k

    f4v acc[2][4];
    #pragma unroll
    for (int i = 0; i < 2; ++i)
        #pragma unroll
        for (int j = 0; j < 4; ++j) acc[i][j] = (f4v){0.f, 0.f, 0.f, 0.f};

    for (int k0 = 0; k0 < K; k0 += 32) {
        {
            const float* ap = A + (size_t)(m0 + ar) * K + k0 + aseg;
            float4 a0 = *(const float4*)ap;
            float4 a1 = *(const float4*)(ap + 4);
            h8v ha;
            ha[0] = (half_t)a0.x; ha[1] = (half_t)a0.y;
            ha[2] = (half_t)a0.z; ha[3] = (half_t)a0.w;
            ha[4] = (half_t)a1.x; ha[5] = (half_t)a1.y;
            ha[6] = (half_t)a1.z; ha[7] = (half_t)a1.w;
            *(h8v*)&As[ar * 40 + aseg] = ha;

            const float* bp = Bm + (size_t)(n0 + br) * K + k0 + bseg;
            float4 b0 = *(const float4*)bp;
            float4 b1 = *(const float4*)(bp + 4);
            float4 b2 = *(const float4*)(bp + 8);
            float4 b3 = *(const float4*)(bp + 12);
            h8v hb0, hb1;
            hb0[0] = (half_t)b0.x; hb0[1] = (half_t)b0.y;
            hb0[2] = (half_t)b0.z; hb0[3] = (half_t)b0.w;
            hb0[4] = (half_t)b1.x; hb0[5] = (half_t)b1.y;
            hb0[6] = (half_t)b1.z; hb0[7] = (half_t)b1.w;
            hb1[0] = (half_t)b2.x; hb1[1] = (half_t)b2.y;
            hb1[2] = (half_t)b2.z; hb1[3] = (half_t)b2.w;
            hb1[4] = (half_t)b3.x; hb1[5] = (half_t)b3.y;
            hb1[6] = (half_t)b3.z; hb1[7] = (half_t)b3.w;
            *(h8v*)&Bs[br * 40 + bseg] = hb0;
            *(h8v*)&Bs[br * 40 + bseg + 8] = hb1;
        }
        __syncthreads();
        h8v af[2], bfr[4];
        #pragma unroll
        for (int i = 0; i < 2; ++i)
            af[i] = *(const h8v*)&As[(wm + i * 16 + lr) * 40 + lk * 8];
        #pragma unroll
        for (int j = 0; j < 4; ++j)
            bfr[j] = *(const h8v*)&Bs[(wn + j * 16 + lr) * 40 + lk * 8];
        #pragma unroll
        for (int i = 0; i < 2; ++i)
            #pragma unroll
            for (int j = 0; j < 4; ++j)
                acc[i][j] = __builtin_amdgcn_mfma_f32_16x16x32_f16(af[i], bfr[j], acc[i][j], 0, 0, 0);
        __syncthreads();
    }

    // Epilogue: C/D col=lane&15, row=(lane>>4)*4+reg; fp16 store.
    #pragma unroll
    for (int j = 0; j < 4; ++j) {
        int n = n0 + wn + j * 16 + lr;
        float bv = bias[n];
        #pragma unroll
        for (int i = 0; i < 2; ++i) {
            #pragma unroll
            for (int r = 0; r < 4; ++r) {
                int m = m0 + wm + i * 16 + lk * 4 + r;
                C[(size_t)m * N + n] = (half_t)fmaxf(acc[i][j][r] + bv, 0.f);
            }
        }
    }
}

// ---------------------------------------------------------------------------
// Fuse dec (linear 256->3136) with convt1 (convT 64->32 k4 s2 p1).
// RESTRUCTURED: one block per pixel p (196 blocks); all 32 output channels
// share the same <=4x64 dec_w rows, read ONCE (was 32x re-read with one
// block per n). wt1 tap-slice staged in LDS. Tap order (ky->kx->c) matches
// the old kernel exactly -> bit-identical Wf/bf.
// Output rows channel-minor: Wf[(p*32+o)][k], bf[p*32+o].
// ---------------------------------------------------------------------------
__global__ __launch_bounds__(256) void k_fuse(
    const float* __restrict__ wt1, const float* __restrict__ upt1_b,
    const float* __restrict__ dec_w, const float* __restrict__ dec_b,
    float* __restrict__ Wf, float* __restrict__ bf)
{
    __shared__ float WL[4][64][32];   // 32 KB (<=ntap slices used)
    const int p = blockIdx.x;
    const int k = threadIdx.x;
    const int y = p / 14, x = p % 14;

    // valid tap lists (uniform across block); <=2 each
    int ky0 = 0, iy0 = 0, ky1 = 0, iy1 = 0, nky = 0;
    for (int ky = 0; ky < 4; ++ky) {
        int iyn = y + 1 - ky;
        if (iyn < 0 || (iyn & 1)) continue;
        int iy = iyn >> 1;
        if (iy > 6) continue;
        if (nky == 0) { ky0 = ky; iy0 = iy; } else { ky1 = ky; iy1 = iy; }
        ++nky;
    }
    int kx0 = 0, ix0 = 0, kx1 = 0, ix1 = 0, nkx = 0;
    for (int kx = 0; kx < 4; ++kx) {
        int ixn = x + 1 - kx;
        if (ixn < 0 || (ixn & 1)) continue;
        int ix = ixn >> 1;
        if (ix > 6) continue;
        if (nkx == 0) { kx0 = kx; ix0 = ix; } else { kx1 = kx; ix1 = ix; }
        ++nkx;
    }
    const int ntap = nky * nkx;

    // stage wt1 slices: t = ti*nkx+tj (ky outer, kx inner — original order)
    for (int e = k; e < ntap * 2048; e += 256) {
        int t = e >> 11, c = (e >> 5) & 63, o = e & 31;
        int ti = (nkx == 2) ? (t >> 1) : t;
        int tj = (nkx == 2) ? (t & 1) : 0;
        int ky = ti ? ky1 : ky0;
        int kx = tj ? kx1 : kx0;
        WL[t][c][o] = wt1[((c * 32 + o) * 4 + ky) * 4 + kx];
    }
    __syncthreads();

    float acc[32];
    #pragma unroll
    for (int o = 0; o < 32; ++o) acc[o] = 0.f;
    float bacc = 0.f;   // valid for k < 32 (o = k)

    for (int t = 0; t < ntap; ++t) {
        int ti = (nkx == 2) ? (t >> 1) : t;
        int tj = (nkx == 2) ? (t & 1) : 0;
        int iy = ti ? iy1 : iy0;
        int ix = tj ? ix1 : ix0;
        int rbase = iy * 7 + ix;
        for (int c = 0; c < 64; ++c) {
            int row = c * 49 + rbase;
            float v = dec_w[(size_t)row * 256 + k];
            const float* wr = &WL[t][c][0];
            #pragma unroll
            for (int o8 = 0; o8 < 8; ++o8) {
                float4 wq = *(const float4*)&wr[4 * o8];
                acc[4 * o8 + 0] = fmaf(wq.x, v, acc[4 * o8 + 0]);
                acc[4 * o8 + 1] = fmaf(wq.y, v, acc[4 * o8 + 1]);
                acc[4 * o8 + 2] = fmaf(wq.z, v, acc[4 * o8 + 2]);
                acc[4 * o8 + 3] = fmaf(wq.w, v, acc[4 * o8 + 3]);
            }
            if (k < 32) bacc = fmaf(WL[t][c][k], dec_b[row], bacc);
        }
    }

    #pragma unroll 4
    for (int o = 0; o < 32; ++o)
        Wf[((size_t)(p * 32 + o)) * 256 + k] = acc[o];
    if (k < 32) bf[p * 32 + k] = bacc + upt1_b[k];
}

// ---------------------------------------------------------------------------
__global__ __launch_bounds__(256) void k_mnorm(const float* __restrict__ mem, float* __restrict__ inv_norm)
{
    __shared__ float red[256];
    const int row = blockIdx.x, tid = threadIdx.x;
    float v = mem[(size_t)row * 256 + tid];
    red[tid] = v * v;
    __syncthreads();
    for (int s = 128; s > 0; s >>= 1) {
        if (tid < s) red[tid] += red[tid + s];
        __syncthreads();
    }
    if (tid == 0) inv_norm[row] = 1.f / fmaxf(sqrtf(red[0]), 1e-12f);
}

// ---------------------------------------------------------------------------
// Top-k loop uses wave __shfl_xor lexicographic (v,idx) reduce — exactly
// associative (no FP rounding), so identical result to the old LDS tree at
// a fraction of the barriers. Norm reduce keeps ORIGINAL order (fp32 sum is
// order-sensitive and upstream of topk).
// ---------------------------------------------------------------------------
__global__ __launch_bounds__(256) void k_memread(
    const float* __restrict__ latent, const float* __restrict__ dots,
    const float* __restrict__ inv_mn, const float* __restrict__ mem,
    float* __restrict__ out)
{
    __shared__ float red[256];
    __shared__ int   redi[4];
    __shared__ float inv_x_s;
    const int b = blockIdx.x, tid = threadIdx.x;
    const int w = tid >> 6, lane = tid & 63;
    float lx = latent[(size_t)b * 256 + tid];
    red[tid] = lx * lx;
    __syncthreads();
    for (int s = 128; s > 0; s >>= 1) {
        if (tid < s) red[tid] += red[tid + s];
        __syncthreads();
    }
    if (tid == 0) inv_x_s = 1.f / fmaxf(sqrtf(red[0]), 1e-12f);
    __syncthreads();
    const float inv_x = inv_x_s;

    float vals[16];
    for (int j = 0; j < 16; ++j) {
        int m = tid + j * 256;
        vals[j] = dots[(size_t)b * 4096 + m] * inv_mn[m] * inv_x;
    }
    float tv[10]; int ti[10];
    for (int t = 0; t < 10; ++t) {
        float bv = -1e30f; int bidx = 0x7fffffff;
        #pragma unroll
        for (int j = 0; j < 16; ++j) {
            int m = tid + j * 256;
            float v = vals[j];
            if (v > bv || (v == bv && m < bidx)) { bv = v; bidx = m; }
        }
        #pragma unroll
        for (int off = 32; off > 0; off >>= 1) {
            float ov = __shfl_xor(bv, off);
            int   oi = __shfl_xor(bidx, off);
            if (ov > bv || (ov == bv && oi < bidx)) { bv = ov; bidx = oi; }
        }
        if (lane == 0) { red[w] = bv; redi[w] = bidx; }
        __syncthreads();
        float fv = red[0]; int fi = redi[0];
        #pragma unroll
        for (int q = 1; q < 4; ++q) {
            float v2 = red[q]; int i2 = redi[q];
            if (v2 > fv || (v2 == fv && i2 < fi)) { fv = v2; fi = i2; }
        }
        tv[t] = fv; ti[t] = fi;
        if ((fi & 255) == tid) vals[fi >> 8] = -1e30f;
        __syncthreads();
    }
    float wgt[10], wsum = 0.f;
    for (int t = 0; t < 10; ++t) { wgt[t] = expf(tv[t] - tv[0]); wsum += wgt[t]; }
    float inv_ws = 1.f / wsum;
    float acc = 0.f;
    for (int t = 0; t < 10; ++t) acc += (wgt[t] * inv_ws) * mem[(size_t)ti[t] * 256 + tid];
    out[(size_t)b * 256 + tid] = acc;
}

// ---------------------------------------------------------------------------
// Weight repack.
//   pk2h[((tap*2+nt)*16+oc)*32+ic] fp16  from c1_w [32][32][3][3] (MFMA B)
//   pk3h[((q*4+t)*16+oc)*32+ic]   fp16  from upt2_w [32][16][4][4] (MFMA B)
//   pk4[c16][tap9][o8]                   from c2_w   [8][16][3][3]
//   pk5[blk2][j128][c32]                 from blk_ff2_w [2][32][128]
// ---------------------------------------------------------------------------
__global__ __launch_bounds__(256) void k_pack(
    const float* __restrict__ wc1, const float* __restrict__ wt2,
    const float* __restrict__ wc2, const float* __restrict__ w2src,
    half_t* __restrict__ pk2h, half_t* __restrict__ pk3h,
    float* __restrict__ pk4, float* __restrict__ pk5)
{
    int i = blockIdx.x * 256 + threadIdx.x;
    if (i < 9216) {
        int ic = i & 31, oc = (i >> 5) & 15, nt = (i >> 9) & 1, t = i >> 10;
        pk2h[i] = (half_t)wc1[((nt * 16 + oc) * 32 + ic) * 9 + t];
    }
    if (i < 8192) {
        int ic = i & 31, oc = (i >> 5) & 15, t = (i >> 9) & 3, q = i >> 11;
        int wy = t >> 1, wx = t & 1, py = q >> 1, px = q & 1;
        int ky = 3 - py - 2 * wy, kx = 3 - px - 2 * wx;
        pk3h[i] = (half_t)wt2[((ic * 16 + oc) * 4 + ky) * 4 + kx];
    }
    if (i < 1152) {
        int o = i & 7, tap = (i >> 3) % 9, c = i / 72;
        pk4[i] = wc2[(o * 16 + c) * 9 + tap];
    }
    if (i < 8192) {
        int c = i & 31, j = (i >> 5) & 127, bq = i >> 12;
        pk5[i] = w2src[bq * 4096 + c * 128 + j];
    }
}

// ---------------------------------------------------------------------------
// Conv2d 32->32 k3 p1, 14x14, ReLU — MFMA. 2 samples/block.
// Output d2h fp16 channel-minor [sample][196][32] (feeds MFMA convt2).
// ---------------------------------------------------------------------------
__global__ __launch_bounds__(256) void k_conv1(
    const half_t* __restrict__ in, const half_t* __restrict__ wh,
    const float* __restrict__ bias, half_t* __restrict__ out)
{
    __shared__ __align__(16) half_t P[2 * 16 * 16 * 40];   // 40960 B
    const int tid = threadIdx.x;
    const int w = tid >> 6, lane = tid & 63;
    const size_t b0 = (size_t)blockIdx.x * 2;

    for (int e = tid; e < 10240; e += 256) ((unsigned int*)P)[e] = 0u;
    __syncthreads();
    {
        const unsigned int* src = (const unsigned int*)in;
        for (int e = tid; e < 6272; e += 256) {
            int si = e / 3136;
            int rem = e - si * 3136;
            int p = rem >> 4, c2 = rem & 15;
            int y = p / 14, x = p % 14;
            ((unsigned int*)P)[si * 5120 + ((y + 1) * 16 + (x + 1)) * 20 + c2] =
                src[(b0 + si) * 3136 + rem];
        }
    }

    h8v bfr[9][2];
    #pragma unroll
    for (int t = 0; t < 9; ++t)
        #pragma unroll
        for (int nt = 0; nt < 2; ++nt)
            bfr[t][nt] = *(const h8v*)&wh[((size_t)((t * 2 + nt) * 16 + (lane & 15))) * 32 + (lane >> 4) * 8];

    __syncthreads();

    const int kseg = (lane >> 4) * 8;
    const int oc = lane & 15;
    const float bv0 = bias[oc], bv1 = bias[16 + oc];

    for (int job = w; job < 26; job += 4) {
        const int si = job >= 13 ? 1 : 0;
        const int tile = job - si * 13;
        int p = tile * 16 + (lane & 15);
        if (p > 195) p = 195;
        const int y = p / 14, x = p % 14;
        const half_t* Pb = P + si * 10240;

        f4v acc0 = (f4v){0.f, 0.f, 0.f, 0.f};
        f4v acc1 = (f4v){0.f, 0.f, 0.f, 0.f};
        #pragma unroll
        for (int ky = 0; ky < 3; ++ky) {
            #pragma unroll
            for (int kx = 0; kx < 3; ++kx) {
                h8v af = *(const h8v*)&Pb[((y + ky) * 16 + (x + kx)) * 40 + kseg];
                acc0 = __builtin_amdgcn_mfma_f32_16x16x32_f16(af, bfr[ky * 3 + kx][0], acc0, 0, 0, 0);
                acc1 = __builtin_amdgcn_mfma_f32_16x16x32_f16(af, bfr[ky * 3 + kx][1], acc1, 0, 0, 0);
            }
        }

        const int pr0 = tile * 16 + (lane >> 4) * 4;
        half_t* ob = out + (b0 + si) * 6272;
        #pragma unroll
        for (int r = 0; r < 4; ++r) {
            int pp = pr0 + r;
            if (pp < 196) {
                ob[(size_t)pp * 32 + oc]      = (half_t)fmaxf(acc0[r] + bv0, 0.f);
                ob[(size_t)pp * 32 + 16 + oc] = (half_t)fmaxf(acc1[r] + bv1, 0.f);
            }
        }
    }
}

// ---------------------------------------------------------------------------
// FUSED: ConvTranspose2d 32->16 k4 s2 p1 (MFMA) + Conv2d 16->8 k3 p1 (ReLU)
//        + Conv2d 8->1 k1. One sample/block. Results in registers; fp32
//        [8][30][32] group tile overlays the dead input tile (30720 B LDS).
// ---------------------------------------------------------------------------
__global__ __launch_bounds__(256) void k_convt23(
    const half_t* __restrict__ in, const half_t* __restrict__ pk3h,
    const float* __restrict__ bt2, const float* __restrict__ pk4,
    const float* __restrict__ b2, const float* __restrict__ w3,
    const float* __restrict__ b3, float* __restrict__ out)
{
    __shared__ __align__(16) unsigned char Lraw[30720];
    half_t* Pin = (half_t*)Lraw;     // [16][16][40] halves = 20480 B
    float*  P2  = (float*)Lraw;      // [8][30][32] floats = 30720 B (overlay)
    const int tid = threadIdx.x;
    const int w = tid >> 6, lane = tid & 63;
    const int b = blockIdx.x;

    for (int e = tid; e < 5120; e += 256) ((unsigned int*)Pin)[e] = 0u;
    __syncthreads();
    {
        const unsigned int* src = (const unsigned int*)in;
        for (int e = tid; e < 3136; e += 256) {
            int p = e >> 4, c2 = e & 15;
            int y = p / 14, x = p % 14;
            ((unsigned int*)Pin)[((y + 1) * 16 + (x + 1)) * 20 + c2] =
                src[(size_t)b * 3136 + e];
        }
    }
    __syncthreads();

    const int oc = lane & 15;
    const int kseg = (lane >> 4) * 8;

    f4v res[13];
    #pragma unroll
    for (int j = 0; j < 13; ++j) {
        const int job = w + 4 * j;
        const int q = job / 13, tile = job - q * 13;
        const int py = q >> 1, px = q & 1;
        int p = tile * 16 + (lane & 15);
        if (p > 195) p = 195;
        const int ty = p / 14, tx = p % 14;
        f4v a = (f4v){0.f, 0.f, 0.f, 0.f};
        #pragma unroll
        for (int t = 0; t < 4; ++t) {
            const int wy = t >> 1, wx = t & 1;
            h8v bf = *(const h8v*)&pk3h[((size_t)((q * 4 + t) * 16 + oc)) * 32 + kseg];
            h8v af = *(const h8v*)&Pin[((ty + py + wy) * 16 + (tx + px + wx)) * 40 + kseg];
            a = __builtin_amdgcn_mfma_f32_16x16x32_f16(af, bf, a, 0, 0, 0);
        }
        res[j] = a;
    }
    __syncthreads();   // all input-tile reads done; overlay safe

    const bool active2 = tid < 196;
    int row = active2 ? tid / 7 : 0;
    int tx0b = active2 ? (tid % 7) * 4 : 0;
    const float bco = bt2[oc];

    float acc2[4][8];
    #pragma unroll
    for (int i = 0; i < 4; ++i)
        #pragma unroll
        for (int o = 0; o < 8; ++o) acc2[i][o] = 0.f;

    #pragma unroll
    for (int g = 0; g < 2; ++g) {
        for (int e = tid; e < 7680; e += 256) P2[e] = 0.f;
        __syncthreads();
        if ((oc >> 3) == g) {
            #pragma unroll
            for (int j = 0; j < 13; ++j) {
                const int job = w + 4 * j;
                const int q = job / 13, tile = job - q * 13;
                const int py = q >> 1, px = q & 1;
                const int pr0 = tile * 16 + (lane >> 4) * 4;
                #pragma unroll
                for (int r = 0; r < 4; ++r) {
                    int p = pr0 + r;
                    if (p < 196) {
                        int Y = 2 * (p / 14) + py, X = 2 * (p % 14) + px;
                        P2[((oc & 7) * 30 + Y + 1) * 32 + (X + 1)] = fmaxf(res[j][r] + bco, 0.f);
                    }
                }
            }
        }
        __syncthreads();
        for (int cl = 0; cl < 8; ++cl) {
            const float* Pb = &P2[(cl * 30 + row) * 32 + tx0b];
            const float* wb = pk4 + (size_t)(g * 8 + cl) * 72;
            #pragma unroll
            for (int ky = 0; ky < 3; ++ky) {
                float4 a = *(const float4*)&Pb[ky * 32];
                float4 bq = *(const float4*)&Pb[ky * 32 + 4];
                float rowb[8] = {a.x, a.y, a.z, a.w, bq.x, bq.y, bq.z, bq.w};
                #pragma unroll
                for (int kx = 0; kx < 3; ++kx) {
                    const float* wt = wb + (ky * 3 + kx) * 8;
                    #pragma unroll
                    for (int o = 0; o < 8; ++o) {
                        float wv2 = wt[o];
                        #pragma unroll
                        for (int i = 0; i < 4; ++i)
                            acc2[i][o] = fmaf(rowb[i + kx], wv2, acc2[i][o]);
                    }
                }
            }
        }
        __syncthreads();
    }

    if (active2) {
        const float bias3 = b3[0];
        #pragma unroll
        for (int i = 0; i < 4; ++i) {
            float r = bias3;
            #pragma unroll
            for (int o = 0; o < 8; ++o) r += fmaxf(acc2[i][o] + b2[o], 0.f) * w3[o];
            out[(size_t)b * 784 + row * 28 + tx0b + i] = r;
        }
    }
}

// ---------------------------------------------------------------------------
extern "C" void kernel_launch(void* const* d_in, const int* in_sizes, int n_in,
                              void* d_out, int out_size, void* d_ws, size_t ws_size,
                              hipStream_t stream)
{
    const float* x       = (const float*)d_in[0];
    const float* patch_w = (const float*)d_in[1];
    const float* patch_b = (const float*)d_in[2];
    const float* ln1g    = (const float*)d_in[3];
    const float* ln1b    = (const float*)d_in[4];
    const float* wi      = (const float*)d_in[5];
    const float* bi      = (const float*)d_in[6];
    const float* wo      = (const float*)d_in[7];
    const float* bo      = (const float*)d_in[8];
    const float* ln2g    = (const float*)d_in[9];
    const float* ln2b    = (const float*)d_in[10];
    const float* w1      = (const float*)d_in[11];
    const float* b1      = (const float*)d_in[12];
    const float* w2      = (const float*)d_in[13];
    const float* b2      = (const float*)d_in[14];
    const float* lat_w   = (const float*)d_in[15];
    const float* lat_b   = (const float*)d_in[16];
    const float* memory  = (const float*)d_in[17];
    const float* dec_w   = (const float*)d_in[18];
    const float* dec_b   = (const float*)d_in[19];
    const float* upt1_w  = (const float*)d_in[20];
    const float* upt1_b  = (const float*)d_in[21];
    const float* c1_w    = (const float*)d_in[22];
    const float* c1_b    = (const float*)d_in[23];
    const float* upt2_w  = (const float*)d_in[24];
    const float* upt2_b  = (const float*)d_in[25];
    const float* c2_w    = (const float*)d_in[26];
    const float* c2_b    = (const float*)d_in[27];
    const float* c3_w    = (const float*)d_in[28];
    const float* c3_b    = (const float*)d_in[29];
    float* outp = (float*)d_out;

    float* ws = (float*)d_ws;
    size_t off = 0;
    auto alloc = [&](size_t n) { float* p = ws + off; off += (n + 63) & ~(size_t)63; return p; };
    float* tokens     = alloc((size_t)B_TOT * 1568);
    float* latent     = alloc((size_t)B_TOT * 256);
    float* dots       = alloc((size_t)B_TOT * 4096);
    float* mem_latent = alloc((size_t)B_TOT * 256);
    float* inv_mn     = alloc(4096);
    half_t* pk2h      = (half_t*)alloc(4608);
    half_t* pk3h      = (half_t*)alloc(4096);
    float* pk4        = alloc(1152);
    float* pk5        = alloc(8192);
    float* Wf         = alloc((size_t)6272 * 256);
    float* bf         = alloc(6272);
    half_t* d1h       = (half_t*)alloc((size_t)CHUNK * 6272 / 2);
    half_t* d2h       = (half_t*)alloc((size_t)CHUNK * 6272 / 2);
    (void)in_sizes; (void)n_in; (void)out_size; (void)ws_size;

    // Weight repack + dec/convt1 algebraic fusion (Wf rows channel-minor)
    k_pack<<<36, 256, 0, stream>>>(c1_w, upt2_w, c2_w, w2, pk2h, pk3h, pk4, pk5);
    k_fuse<<<196, 256, 0, stream>>>(upt1_w, upt1_b, dec_w, dec_b, Wf, bf);

    // Encoder (wave-per-sample)
    k_tokens<<<B_TOT / 4, 256, 0, stream>>>(x, patch_w, patch_b, ln1g, ln1b, wi, bi,
                                            wo, bo, ln2g, ln2b, w1, b1, pk5, b2, tokens);
    k_gemm<<<dim3(256 / 64, B_TOT / 128), 256, 0, stream>>>(tokens, lat_w, lat_b, latent,
                                                            B_TOT, 256, 1568, 0);
    k_mnorm<<<4096, 256, 0, stream>>>(memory, inv_mn);
    k_gemm<<<dim3(4096 / 64, B_TOT / 128), 256, 0, stream>>>(latent, memory, nullptr, dots,
                                                             B_TOT, 4096, 256, 0);
    k_memread<<<B_TOT, 256, 0, stream>>>(latent, dots, inv_mn, memory, mem_latent);

    // Decoder, full batch in one pass (ws fits with fp16 d1h/d2h).
    for (int c = 0; c < B_TOT / CHUNK; ++c) {
        const float* ml = mem_latent + (size_t)c * CHUNK * 256;
        k_dgemm<<<dim3(6272 / 128, CHUNK / 64), 256, 0, stream>>>(ml, Wf, bf, d1h,
                                                                  CHUNK, 6272, 256);
        k_conv1  <<<CHUNK / 2, 256, 0, stream>>>(d1h, pk2h, c1_b, d2h);
        k_convt23<<<CHUNK, 256, 0, stream>>>(d2h, pk3h, upt2_b, pk4, c2_b, c3_w, c3_b,
                                             outp + (size_t)c * CHUNK * 784);
    }
}

// Round 14
// 1143.609 us; speedup vs baseline: 1.6385x; 1.0508x over previous
//
#include <hip/hip_runtime.h>
#include <math.h>

#define B_TOT 4096
#define CHUNK 4096

typedef _Float16 half_t;
typedef _Float16 h2 __attribute__((ext_vector_type(2)));
typedef _Float16 h8v __attribute__((ext_vector_type(8)));
typedef float f4v __attribute__((ext_vector_type(4)));

#if __has_builtin(__builtin_amdgcn_fdot2)
#define FDOT2(a, b, c) __builtin_amdgcn_fdot2((a), (b), (c), false)
#else
#define FDOT2(a, b, c) fmaf((float)(a)[1], (float)(b)[1], fmaf((float)(a)[0], (float)(b)[0], (c)))
#endif

// k_tokens LDS: K 49x36 halves fp16, V 49x34 floats fp32 per wave; wi slot.
// V stays fp32 (round-4: fp16 V broke accuracy). Decoder (downstream of topk)
// is fp16-MFMA end to end (validated r10-r12).
// dots GEMM (upstream of topk) uses SPLIT-fp16 MFMA this round: error ~5e-7
// on sims (~5x fp32 noise, 1000x tighter than round-4's failed 5e-4 class).
// Pre-commit: if absmax moves off the 2.441e-4 bf16 floor -> revert to fp32.
#define KSTR 36
#define VSTR 34
#define KBYTES (49 * 72)
#define WAVE_LDS (49 * 72 + 49 * 136)  // 10192
#define WI_OFF  (4 * WAVE_LDS)         // 40768
#define BLOCK_LDS (WI_OFF + 12288)     // 53056

// ---------------------------------------------------------------------------
// Fused: patch conv (1->32, k4 s4) + 2 transformer blocks.
// ---------------------------------------------------------------------------
__global__ __launch_bounds__(256) void k_tokens(
    const float* __restrict__ x, const float* __restrict__ pw, const float* __restrict__ pb,
    const float* __restrict__ ln1g, const float* __restrict__ ln1b,
    const float* __restrict__ wi, const float* __restrict__ bi,
    const float* __restrict__ wo, const float* __restrict__ bo,
    const float* __restrict__ ln2g, const float* __restrict__ ln2b,
    const float* __restrict__ w1, const float* __restrict__ fb1,
    const float* __restrict__ w2t, const float* __restrict__ fb2,
    float* __restrict__ tokens)
{
    __shared__ __align__(16) unsigned char Lraw[BLOCK_LDS];
    const int tid = threadIdx.x;
    const int wv = tid >> 6, lane = tid & 63;
    const int b = blockIdx.x * 4 + wv;
    half_t* Kb = (half_t*)(Lraw + wv * WAVE_LDS);
    float*  Vb = (float*)(Lraw + wv * WAVE_LDS + KBYTES);
    const float* wiL = (const float*)(Lraw + WI_OFF);
    float* Lf = (float*)Lraw;            // FF-weight overlay (block-wide)
    const bool is_tok = lane < 49;
    const int s = is_tok ? lane : 48;
    const int py = s / 7, px = s % 7;

    // --- prologue: stage blk-0 qkv weights (visible after barrier (A)) ---
    {
        const float4* srcw = (const float4*)(wi);
        float4* dstw = (float4*)(Lraw + WI_OFF);
        for (int e = tid; e < 768; e += 256) dstw[e] = srcw[e];
    }

    // --- patch conv: direct float4 loads (rows are 16B-aligned) ---
    float xv[16];
    const float* xb = x + (size_t)b * 784 + py * 112 + px * 4;
    #pragma unroll
    for (int r = 0; r < 4; ++r) {
        float4 vq = *(const float4*)(xb + r * 28);
        xv[4 * r + 0] = vq.x; xv[4 * r + 1] = vq.y;
        xv[4 * r + 2] = vq.z; xv[4 * r + 3] = vq.w;
    }
    float t[32];
    #pragma unroll 4
    for (int c = 0; c < 32; ++c) {
        float a = pb[c];
        const float* wr = pw + c * 16;
        #pragma unroll
        for (int i = 0; i < 16; ++i) a = fmaf(xv[i], wr[i], a);
        t[c] = a;
    }

    for (int blk = 0; blk < 2; ++blk) {
        const float* bib = bi + blk * 96;

        // --- LN1 ---
        float mu = 0.f;
        #pragma unroll
        for (int c = 0; c < 32; ++c) mu += t[c];
        mu *= 0.03125f;
        float var = 0.f;
        #pragma unroll
        for (int c = 0; c < 32; ++c) { float d = t[c] - mu; var = fmaf(d, d, var); }
        float rstd = rsqrtf(var * 0.03125f + 1e-5f);
        float xn[32];
        #pragma unroll
        for (int c = 0; c < 32; ++c)
            xn[c] = (t[c] - mu) * rstd * ln1g[blk * 32 + c] + ln1b[blk * 32 + c];

        __syncthreads();   // (A) prior-phase LDS reads done; wi stage visible

        // --- K projection -> LDS fp16 (broadcast b128 weight reads) ---
        #pragma unroll 4
        for (int d = 0; d < 32; ++d) {
            const float* wr = wiL + (32 + d) * 32;
            float a0 = bib[32 + d], a1 = 0.f;
            #pragma unroll
            for (int c2 = 0; c2 < 4; ++c2) {
                float4 wq = *(const float4*)&wr[4 * c2];
                a0 = fmaf(xn[4 * c2],     wq.x, a0);
                a0 = fmaf(xn[4 * c2 + 1], wq.y, a0);
                a0 = fmaf(xn[4 * c2 + 2], wq.z, a0);
                a0 = fmaf(xn[4 * c2 + 3], wq.w, a0);
            }
            #pragma unroll
            for (int c2 = 4; c2 < 8; ++c2) {
                float4 wq = *(const float4*)&wr[4 * c2];
                a1 = fmaf(xn[4 * c2],     wq.x, a1);
                a1 = fmaf(xn[4 * c2 + 1], wq.y, a1);
                a1 = fmaf(xn[4 * c2 + 2], wq.z, a1);
                a1 = fmaf(xn[4 * c2 + 3], wq.w, a1);
            }
            if (is_tok) Kb[s * KSTR + d] = (half_t)(a0 + a1);
        }
        // --- V projection -> LDS fp32 ---
        #pragma unroll 4
        for (int d = 0; d < 32; ++d) {
            const float* wr = wiL + (64 + d) * 32;
            float a0 = bib[64 + d], a1 = 0.f;
            #pragma unroll
            for (int c2 = 0; c2 < 4; ++c2) {
                float4 wq = *(const float4*)&wr[4 * c2];
                a0 = fmaf(xn[4 * c2],     wq.x, a0);
                a0 = fmaf(xn[4 * c2 + 1], wq.y, a0);
                a0 = fmaf(xn[4 * c2 + 2], wq.z, a0);
                a0 = fmaf(xn[4 * c2 + 3], wq.w, a0);
            }
            #pragma unroll
            for (int c2 = 4; c2 < 8; ++c2) {
                float4 wq = *(const float4*)&wr[4 * c2];
                a1 = fmaf(xn[4 * c2],     wq.x, a1);
                a1 = fmaf(xn[4 * c2 + 1], wq.y, a1);
                a1 = fmaf(xn[4 * c2 + 2], wq.z, a1);
                a1 = fmaf(xn[4 * c2 + 3], wq.w, a1);
            }
            if (is_tok) Vb[s * VSTR + d] = a0 + a1;
        }
        // --- Q projection (scaled), packed to half2 for fdot2 ---
        float q0[32];
        #pragma unroll 4
        for (int d = 0; d < 32; ++d) {
            const float* wr = wiL + d * 32;
            float a0 = bib[d], a1 = 0.f;
            #pragma unroll
            for (int c2 = 0; c2 < 4; ++c2) {
                float4 wq = *(const float4*)&wr[4 * c2];
                a0 = fmaf(xn[4 * c2],     wq.x, a0);
                a0 = fmaf(xn[4 * c2 + 1], wq.y, a0);
                a0 = fmaf(xn[4 * c2 + 2], wq.z, a0);
                a0 = fmaf(xn[4 * c2 + 3], wq.w, a0);
            }
            #pragma unroll
            for (int c2 = 4; c2 < 8; ++c2) {
                float4 wq = *(const float4*)&wr[4 * c2];
                a1 = fmaf(xn[4 * c2],     wq.x, a1);
                a1 = fmaf(xn[4 * c2 + 1], wq.y, a1);
                a1 = fmaf(xn[4 * c2 + 2], wq.z, a1);
                a1 = fmaf(xn[4 * c2 + 3], wq.w, a1);
            }
            q0[d] = (a0 + a1) * 0.25f;
        }
        h2 qh[16];
        #pragma unroll
        for (int i = 0; i < 16; ++i) {
            h2 hh; hh[0] = (half_t)q0[2 * i]; hh[1] = (half_t)q0[2 * i + 1];
            qh[i] = hh;
        }

        // wave-local fence: own K/V ds_writes visible before broadcast reads
        __asm__ volatile("s_waitcnt lgkmcnt(0)" ::: "memory");

        // --- attention: 2 heads of 16 dims, softmax without running max ---
        float o[32];
        #pragma unroll
        for (int d = 0; d < 32; ++d) o[d] = 0.f;
        float l0 = 0.f, l1 = 0.f;
        union H4 { double qd; h2 p[2]; };
        for (int j = 0; j < 49; ++j) {
            const double* kr = (const double*)(Kb + j * KSTR);
            const float* vr = Vb + j * VSTR;
            H4 u0, u1, u2, u3, w0, w1h, w2h, w3;
            u0.qd = kr[0]; u1.qd = kr[1]; u2.qd = kr[2]; u3.qd = kr[3];
            w0.qd = kr[4]; w1h.qd = kr[5]; w2h.qd = kr[6]; w3.qd = kr[7];
            float s0a = 0.f, s0b = 0.f, s1a = 0.f, s1b = 0.f;
            s0a = FDOT2(u0.p[0], qh[0], s0a); s0a = FDOT2(u0.p[1], qh[1], s0a);
            s0b = FDOT2(u1.p[0], qh[2], s0b); s0b = FDOT2(u1.p[1], qh[3], s0b);
            s0a = FDOT2(u2.p[0], qh[4], s0a); s0a = FDOT2(u2.p[1], qh[5], s0a);
            s0b = FDOT2(u3.p[0], qh[6], s0b); s0b = FDOT2(u3.p[1], qh[7], s0b);
            s1a = FDOT2(w0.p[0], qh[8], s1a); s1a = FDOT2(w0.p[1], qh[9], s1a);
            s1b = FDOT2(w1h.p[0], qh[10], s1b); s1b = FDOT2(w1h.p[1], qh[11], s1b);
            s1a = FDOT2(w2h.p[0], qh[12], s1a); s1a = FDOT2(w2h.p[1], qh[13], s1a);
            s1b = FDOT2(w3.p[0], qh[14], s1b); s1b = FDOT2(w3.p[1], qh[15], s1b);
            float p0 = __expf(s0a + s0b), p1 = __expf(s1a + s1b);
            l0 += p0; l1 += p1;
            #pragma unroll
            for (int i = 0; i < 8; ++i) {
                float2 va = *(const float2*)&vr[2 * i];
                o[2 * i]     = fmaf(p0, va.x, o[2 * i]);
                o[2 * i + 1] = fmaf(p0, va.y, o[2 * i + 1]);
                float2 vc = *(const float2*)&vr[16 + 2 * i];
                o[16 + 2 * i]     = fmaf(p1, vc.x, o[16 + 2 * i]);
                o[16 + 2 * i + 1] = fmaf(p1, vc.y, o[16 + 2 * i + 1]);
            }
        }
        float il0 = 1.f / l0, il1 = 1.f / l1;
        #pragma unroll
        for (int d = 0; d < 16; ++d) { o[d] *= il0; o[16 + d] *= il1; }

        // --- out projection + residual (wave-uniform global weights, 4 KB) ---
        #pragma unroll
        for (int c = 0; c < 32; ++c) {
            const float* wr = wo + blk * 1024 + c * 32;
            float a = bo[blk * 32 + c];
            #pragma unroll
            for (int k2 = 0; k2 < 32; ++k2) a = fmaf(o[k2], wr[k2], a);
            t[c] += a;
        }

        // --- LN2 ---
        mu = 0.f;
        #pragma unroll
        for (int c = 0; c < 32; ++c) mu += t[c];
        mu *= 0.03125f;
        var = 0.f;
        #pragma unroll
        for (int c = 0; c < 32; ++c) { float d = t[c] - mu; var = fmaf(d, d, var); }
        rstd = rsqrtf(var * 0.03125f + 1e-5f);
        #pragma unroll
        for (int c = 0; c < 32; ++c)
            xn[c] = (t[c] - mu) * rstd * ln2g[blk * 32 + c] + ln2b[blk * 32 + c];

        __syncthreads();   // (C) all waves done reading K/V + wi

        // --- stage FF weights (overlay over KV) + next blk's wi ---
        {
            const float4* src1 = (const float4*)(w1 + blk * 4096);
            const float4* src2 = (const float4*)(w2t + blk * 4096);
            float4* dst = (float4*)Lraw;
            for (int e = tid; e < 1024; e += 256) dst[e] = src1[e];
            for (int e = tid; e < 1024; e += 256) dst[1024 + e] = src2[e];
            if (blk == 0) {
                const float4* srcw = (const float4*)(wi + 3072);
                float4* dstw = (float4*)(Lraw + WI_OFF);
                for (int e = tid; e < 768; e += 256) dstw[e] = srcw[e];
            }
        }
        __syncthreads();   // (D) FF weights (and wi for blk1) visible

        // --- FF from LDS: broadcast ds_read_b128 rows ---
        const float* w2L = Lf + 4096;
        #pragma unroll 2
        for (int j = 0; j < 128; ++j) {
            const float* wr = Lf + j * 32;
            float ha = fb1[blk * 128 + j], hb = 0.f;
            #pragma unroll
            for (int c2 = 0; c2 < 4; ++c2) {
                float4 wq = *(const float4*)&wr[4 * c2];
                ha = fmaf(xn[4 * c2],     wq.x, ha);
                ha = fmaf(xn[4 * c2 + 1], wq.y, ha);
                ha = fmaf(xn[4 * c2 + 2], wq.z, ha);
                ha = fmaf(xn[4 * c2 + 3], wq.w, ha);
            }
            #pragma unroll
            for (int c2 = 4; c2 < 8; ++c2) {
                float4 wq = *(const float4*)&wr[4 * c2];
                hb = fmaf(xn[4 * c2],     wq.x, hb);
                hb = fmaf(xn[4 * c2 + 1], wq.y, hb);
                hb = fmaf(xn[4 * c2 + 2], wq.z, hb);
                hb = fmaf(xn[4 * c2 + 3], wq.w, hb);
            }
            float h = ha + hb;
            h = 0.5f * h * (1.f + erff(h * 0.7071067811865476f));
            const float* w2r = w2L + j * 32;
            #pragma unroll
            for (int c2 = 0; c2 < 8; ++c2) {
                float4 wq = *(const float4*)&w2r[4 * c2];
                t[4 * c2]     = fmaf(h, wq.x, t[4 * c2]);
                t[4 * c2 + 1] = fmaf(h, wq.y, t[4 * c2 + 1]);
                t[4 * c2 + 2] = fmaf(h, wq.z, t[4 * c2 + 2]);
                t[4 * c2 + 3] = fmaf(h, wq.w, t[4 * c2 + 3]);
            }
        }
        #pragma unroll
        for (int c = 0; c < 32; ++c) t[c] += fb2[blk * 32 + c];
    }

    if (is_tok) {
        float* op = tokens + (size_t)b * 1568 + s * 32;
        #pragma unroll
        for (int c = 0; c < 32; c += 4) {
            float4 vv = make_float4(t[c], t[c + 1], t[c + 2], t[c + 3]);
            *(float4*)&op[c] = vv;
        }
    }
}

// ---------------------------------------------------------------------------
// C[M,N] = A[M,K] @ B[N,K]^T (+bias, optional ReLU). fp32, 128x64 tile.
// Used for the latent GEMM (topk-upstream, kept fp32).
// ---------------------------------------------------------------------------
__global__ __launch_bounds__(256) void k_gemm(
    const float* __restrict__ A, const float* __restrict__ Bm,
    const float* __restrict__ bias, float* __restrict__ C,
    int M, int N, int K, int relu)
{
    __shared__ float As[16 * 132];
    __shared__ float Bs[16 * 68];
    const int n0 = blockIdx.x * 64, m0 = blockIdx.y * 128;
    const int tid = threadIdx.x;
    const int tx = tid & 15, ty = tid >> 4;
    const int lr = tid >> 1, lk = (tid & 1) * 8;
    const int br = tid >> 2, bk = (tid & 3) * 4;
    float acc[8][4] = {{0.f}};
    for (int k0 = 0; k0 < K; k0 += 16) {
        float4 av0 = *(const float4*)&A[(size_t)(m0 + lr) * K + k0 + lk];
        float4 av1 = *(const float4*)&A[(size_t)(m0 + lr) * K + k0 + lk + 4];
        float4 bv0 = *(const float4*)&Bm[(size_t)(n0 + br) * K + k0 + bk];
        As[(lk + 0) * 132 + lr] = av0.x;
        As[(lk + 1) * 132 + lr] = av0.y;
        As[(lk + 2) * 132 + lr] = av0.z;
        As[(lk + 3) * 132 + lr] = av0.w;
        As[(lk + 4) * 132 + lr] = av1.x;
        As[(lk + 5) * 132 + lr] = av1.y;
        As[(lk + 6) * 132 + lr] = av1.z;
        As[(lk + 7) * 132 + lr] = av1.w;
        Bs[(bk + 0) * 68 + br] = bv0.x;
        Bs[(bk + 1) * 68 + br] = bv0.y;
        Bs[(bk + 2) * 68 + br] = bv0.z;
        Bs[(bk + 3) * 68 + br] = bv0.w;
        __syncthreads();
        #pragma unroll
        for (int k = 0; k < 16; ++k) {
            float4 a0 = *(const float4*)&As[k * 132 + ty * 8];
            float4 a1 = *(const float4*)&As[k * 132 + ty * 8 + 4];
            float4 bv = *(const float4*)&Bs[k * 68 + tx * 4];
            float a8[8] = {a0.x, a0.y, a0.z, a0.w, a1.x, a1.y, a1.z, a1.w};
            float b4[4] = {bv.x, bv.y, bv.z, bv.w};
            #pragma unroll
            for (int i = 0; i < 8; ++i)
                #pragma unroll
                for (int j = 0; j < 4; ++j)
                    acc[i][j] = fmaf(a8[i], b4[j], acc[i][j]);
        }
        __syncthreads();
    }
    #pragma unroll
    for (int i = 0; i < 8; ++i) {
        int m = m0 + ty * 8 + i;
        #pragma unroll
        for (int j = 0; j < 4; ++j) {
            int n = n0 + tx * 4 + j;
            float v = acc[i][j] + (bias ? bias[n] : 0.f);
            if (relu) v = fmaxf(v, 0.f);
            C[(size_t)m * N + n] = v;
        }
    }
}

// ---------------------------------------------------------------------------
// SPLIT-fp16 MFMA GEMM for dots: C[M,N] = A[M,K] @ B[N,K]^T, fp32 out.
// x = hi + lo/2048 with hi=fp16(x), lo=fp16((x-hi)*2048) (scaled to avoid
// fp16 denormal flush). dot = Σhi·hi + (Σhi·lo + Σlo·hi)/2048 via 3 MFMA
// passes, fp32 accum. Error ~5e-7 on sims (fp32-class). Same 64x128 tile /
// fragment skeleton as k_dgemm (validated r10).
// ---------------------------------------------------------------------------
__global__ __launch_bounds__(256) void k_sgemm(
    const float* __restrict__ A, const float* __restrict__ Bm,
    float* __restrict__ C, int M, int N, int K)
{
    __shared__ __align__(16) half_t Ah[64 * 40];
    __shared__ __align__(16) half_t Al[64 * 40];
    __shared__ __align__(16) half_t Bh[128 * 40];
    __shared__ __align__(16) half_t Bl[128 * 40];
    const int tid = threadIdx.x;
    const int n0 = blockIdx.x * 128, m0 = blockIdx.y * 64;
    const int w = tid >> 6, lane = tid & 63;
    const int wm = (w >> 1) * 32, wn = (w & 1) * 64;
    const int lr = lane & 15, lk = lane >> 4;

    const int ar = tid >> 2, aseg = (tid & 3) * 8;   // A stage: 64 rows x 32 k
    const int br = tid >> 1, bseg = (tid & 1) * 16;  // B stage: 128 rows x 32 k

    f4v acch[2][4], accm[2][4];
    #pragma unroll
    for (int i = 0; i < 2; ++i)
        #pragma unroll
        for (int j = 0; j < 4; ++j) {
            acch[i][j] = (f4v){0.f, 0.f, 0.f, 0.f};
            accm[i][j] = (f4v){0.f, 0.f, 0.f, 0.f};
        }

    for (int k0 = 0; k0 < K; k0 += 32) {
        {
            const float* ap = A + (size_t)(m0 + ar) * K + k0 + aseg;
            float4 a0 = *(const float4*)ap;
            float4 a1 = *(const float4*)(ap + 4);
            float av[8] = {a0.x, a0.y, a0.z, a0.w, a1.x, a1.y, a1.z, a1.w};
            h8v ah, al;
            #pragma unroll
            for (int i = 0; i < 8; ++i) {
                half_t h = (half_t)av[i];
                ah[i] = h;
                al[i] = (half_t)((av[i] - (float)h) * 2048.0f);
            }
            *(h8v*)&Ah[ar * 40 + aseg] = ah;
            *(h8v*)&Al[ar * 40 + aseg] = al;

            const float* bp = Bm + (size_t)(n0 + br) * K + k0 + bseg;
            float4 b0 = *(const float4*)bp;
            float4 b1 = *(const float4*)(bp + 4);
            float4 b2 = *(const float4*)(bp + 8);
            float4 b3 = *(const float4*)(bp + 12);
            float bv[16] = {b0.x, b0.y, b0.z, b0.w, b1.x, b1.y, b1.z, b1.w,
                            b2.x, b2.y, b2.z, b2.w, b3.x, b3.y, b3.z, b3.w};
            h8v bh0, bh1, bl0, bl1;
            #pragma unroll
            for (int i = 0; i < 8; ++i) {
                half_t h = (half_t)bv[i];
                bh0[i] = h;
                bl0[i] = (half_t)((bv[i] - (float)h) * 2048.0f);
                half_t h2v = (half_t)bv[8 + i];
                bh1[i] = h2v;
                bl1[i] = (half_t)((bv[8 + i] - (float)h2v) * 2048.0f);
            }
            *(h8v*)&Bh[br * 40 + bseg]     = bh0;
            *(h8v*)&Bh[br * 40 + bseg + 8] = bh1;
            *(h8v*)&Bl[br * 40 + bseg]     = bl0;
            *(h8v*)&Bl[br * 40 + bseg + 8] = bl1;
        }
        __syncthreads();
        h8v afh[2], afl[2], bfh[4], bfl[4];
        #pragma unroll
        for (int i = 0; i < 2; ++i) {
            afh[i] = *(const h8v*)&Ah[(wm + i * 16 + lr) * 40 + lk * 8];
            afl[i] = *(const h8v*)&Al[(wm + i * 16 + lr) * 40 + lk * 8];
        }
        #pragma unroll
        for (int j = 0; j < 4; ++j) {
            bfh[j] = *(const h8v*)&Bh[(wn + j * 16 + lr) * 40 + lk * 8];
            bfl[j] = *(const h8v*)&Bl[(wn + j * 16 + lr) * 40 + lk * 8];
        }
        #pragma unroll
        for (int i = 0; i < 2; ++i)
            #pragma unroll
            for (int j = 0; j < 4; ++j) {
                acch[i][j] = __builtin_amdgcn_mfma_f32_16x16x32_f16(afh[i], bfh[j], acch[i][j], 0, 0, 0);
                accm[i][j] = __builtin_amdgcn_mfma_f32_16x16x32_f16(afh[i], bfl[j], accm[i][j], 0, 0, 0);
                accm[i][j] = __builtin_amdgcn_mfma_f32_16x16x32_f16(afl[i], bfh[j], accm[i][j], 0, 0, 0);
            }
        __syncthreads();
    }

    // Epilogue: C/D col=lane&15, row=(lane>>4)*4+reg.
    #pragma unroll
    for (int j = 0; j < 4; ++j) {
        int n = n0 + wn + j * 16 + lr;
        #pragma unroll
        for (int i = 0; i < 2; ++i) {
            #pragma unroll
            for (int r = 0; r < 4; ++r) {
                int m = m0 + wm + i * 16 + lk * 4 + r;
                C[(size_t)m * N + n] = acch[i][j][r] + accm[i][j][r] * (1.0f / 2048.0f);
            }
        }
    }
}

// ---------------------------------------------------------------------------
// MFMA decoder GEMM: d1h[M,N] = (fp16)relu(A[M,K] @ B[N,K]^T + bias).
// ---------------------------------------------------------------------------
__global__ __launch_bounds__(256) void k_dgemm(
    const float* __restrict__ A, const float* __restrict__ Bm,
    const float* __restrict__ bias, half_t* __restrict__ C,
    int M, int N, int K)
{
    __shared__ __align__(16) half_t As[64 * 40];
    __shared__ __align__(16) half_t Bs[128 * 40];
    const int tid = threadIdx.x;
    const int n0 = blockIdx.x * 128, m0 = blockIdx.y * 64;
    const int w = tid >> 6, lane = tid & 63;
    const int wm = (w >> 1) * 32, wn = (w & 1) * 64;
    const int lr = lane & 15, lk = lane >> 4;

    const int ar = tid >> 2, aseg = (tid & 3) * 8;   // A stage: 64 rows x 32 k
    const int br = tid >> 1, bseg = (tid & 1) * 16;  // B stage: 128 rows x 32 k

    f4v acc[2][4];
    #pragma unroll
    for (int i = 0; i < 2; ++i)
        #pragma unroll
        for (int j = 0; j < 4; ++j) acc[i][j] = (f4v){0.f, 0.f, 0.f, 0.f};

    for (int k0 = 0; k0 < K; k0 += 32) {
        {
            const float* ap = A + (size_t)(m0 + ar) * K + k0 + aseg;
            float4 a0 = *(const float4*)ap;
            float4 a1 = *(const float4*)(ap + 4);
            h8v ha;
            ha[0] = (half_t)a0.x; ha[1] = (half_t)a0.y;
            ha[2] = (half_t)a0.z; ha[3] = (half_t)a0.w;
            ha[4] = (half_t)a1.x; ha[5] = (half_t)a1.y;
            ha[6] = (half_t)a1.z; ha[7] = (half_t)a1.w;
            *(h8v*)&As[ar * 40 + aseg] = ha;

            const float* bp = Bm + (size_t)(n0 + br) * K + k0 + bseg;
            float4 b0 = *(const float4*)bp;
            float4 b1 = *(const float4*)(bp + 4);
            float4 b2 = *(const float4*)(bp + 8);
            float4 b3 = *(const float4*)(bp + 12);
            h8v hb0, hb1;
            hb0[0] = (half_t)b0.x; hb0[1] = (half_t)b0.y;
            hb0[2] = (half_t)b0.z; hb0[3] = (half_t)b0.w;
            hb0[4] = (half_t)b1.x; hb0[5] = (half_t)b1.y;
            hb0[6] = (half_t)b1.z; hb0[7] = (half_t)b1.w;
            hb1[0] = (half_t)b2.x; hb1[1] = (half_t)b2.y;
            hb1[2] = (half_t)b2.z; hb1[3] = (half_t)b2.w;
            hb1[4] = (half_t)b3.x; hb1[5] = (half_t)b3.y;
            hb1[6] = (half_t)b3.z; hb1[7] = (half_t)b3.w;
            *(h8v*)&Bs[br * 40 + bseg] = hb0;
            *(h8v*)&Bs[br * 40 + bseg + 8] = hb1;
        }
        __syncthreads();
        h8v af[2], bfr[4];
        #pragma unroll
        for (int i = 0; i < 2; ++i)
            af[i] = *(const h8v*)&As[(wm + i * 16 + lr) * 40 + lk * 8];
        #pragma unroll
        for (int j = 0; j < 4; ++j)
            bfr[j] = *(const h8v*)&Bs[(wn + j * 16 + lr) * 40 + lk * 8];
        #pragma unroll
        for (int i = 0; i < 2; ++i)
            #pragma unroll
            for (int j = 0; j < 4; ++j)
                acc[i][j] = __builtin_amdgcn_mfma_f32_16x16x32_f16(af[i], bfr[j], acc[i][j], 0, 0, 0);
        __syncthreads();
    }

    // Epilogue: C/D col=lane&15, row=(lane>>4)*4+reg; fp16 store.
    #pragma unroll
    for (int j = 0; j < 4; ++j) {
        int n = n0 + wn + j * 16 + lr;
        float bv = bias[n];
        #pragma unroll
        for (int i = 0; i < 2; ++i) {
            #pragma unroll
            for (int r = 0; r < 4; ++r) {
                int m = m0 + wm + i * 16 + lk * 4 + r;
                C[(size_t)m * N + n] = (half_t)fmaxf(acc[i][j][r] + bv, 0.f);
            }
        }
    }
}

// ---------------------------------------------------------------------------
// Fuse dec (linear 256->3136) with convt1 (convT 64->32 k4 s2 p1).
// One block per pixel p; dec_w rows read once; bit-identical Wf/bf.
// ---------------------------------------------------------------------------
__global__ __launch_bounds__(256) void k_fuse(
    const float* __restrict__ wt1, const float* __restrict__ upt1_b,
    const float* __restrict__ dec_w, const float* __restrict__ dec_b,
    float* __restrict__ Wf, float* __restrict__ bf)
{
    __shared__ float WL[4][64][32];   // 32 KB (<=ntap slices used)
    const int p = blockIdx.x;
    const int k = threadIdx.x;
    const int y = p / 14, x = p % 14;

    int ky0 = 0, iy0 = 0, ky1 = 0, iy1 = 0, nky = 0;
    for (int ky = 0; ky < 4; ++ky) {
        int iyn = y + 1 - ky;
        if (iyn < 0 || (iyn & 1)) continue;
        int iy = iyn >> 1;
        if (iy > 6) continue;
        if (nky == 0) { ky0 = ky; iy0 = iy; } else { ky1 = ky; iy1 = iy; }
        ++nky;
    }
    int kx0 = 0, ix0 = 0, kx1 = 0, ix1 = 0, nkx = 0;
    for (int kx = 0; kx < 4; ++kx) {
        int ixn = x + 1 - kx;
        if (ixn < 0 || (ixn & 1)) continue;
        int ix = ixn >> 1;
        if (ix > 6) continue;
        if (nkx == 0) { kx0 = kx; ix0 = ix; } else { kx1 = kx; ix1 = ix; }
        ++nkx;
    }
    const int ntap = nky * nkx;

    for (int e = k; e < ntap * 2048; e += 256) {
        int t = e >> 11, c = (e >> 5) & 63, o = e & 31;
        int ti = (nkx == 2) ? (t >> 1) : t;
        int tj = (nkx == 2) ? (t & 1) : 0;
        int ky = ti ? ky1 : ky0;
        int kx = tj ? kx1 : kx0;
        WL[t][c][o] = wt1[((c * 32 + o) * 4 + ky) * 4 + kx];
    }
    __syncthreads();

    float acc[32];
    #pragma unroll
    for (int o = 0; o < 32; ++o) acc[o] = 0.f;
    float bacc = 0.f;

    for (int t = 0; t < ntap; ++t) {
        int ti = (nkx == 2) ? (t >> 1) : t;
        int tj = (nkx == 2) ? (t & 1) : 0;
        int iy = ti ? iy1 : iy0;
        int ix = tj ? ix1 : ix0;
        int rbase = iy * 7 + ix;
        for (int c = 0; c < 64; ++c) {
            int row = c * 49 + rbase;
            float v = dec_w[(size_t)row * 256 + k];
            const float* wr = &WL[t][c][0];
            #pragma unroll
            for (int o8 = 0; o8 < 8; ++o8) {
                float4 wq = *(const float4*)&wr[4 * o8];
                acc[4 * o8 + 0] = fmaf(wq.x, v, acc[4 * o8 + 0]);
                acc[4 * o8 + 1] = fmaf(wq.y, v, acc[4 * o8 + 1]);
                acc[4 * o8 + 2] = fmaf(wq.z, v, acc[4 * o8 + 2]);
                acc[4 * o8 + 3] = fmaf(wq.w, v, acc[4 * o8 + 3]);
            }
            if (k < 32) bacc = fmaf(WL[t][c][k], dec_b[row], bacc);
        }
    }

    #pragma unroll 4
    for (int o = 0; o < 32; ++o)
        Wf[((size_t)(p * 32 + o)) * 256 + k] = acc[o];
    if (k < 32) bf[p * 32 + k] = bacc + upt1_b[k];
}

// ---------------------------------------------------------------------------
__global__ __launch_bounds__(256) void k_mnorm(const float* __restrict__ mem, float* __restrict__ inv_norm)
{
    __shared__ float red[256];
    const int row = blockIdx.x, tid = threadIdx.x;
    float v = mem[(size_t)row * 256 + tid];
    red[tid] = v * v;
    __syncthreads();
    for (int s = 128; s > 0; s >>= 1) {
        if (tid < s) red[tid] += red[tid + s];
        __syncthreads();
    }
    if (tid == 0) inv_norm[row] = 1.f / fmaxf(sqrtf(red[0]), 1e-12f);
}

// ---------------------------------------------------------------------------
// Top-k via wave __shfl_xor lexicographic (v,idx) reduce (exactly associative;
// identical result). Norm reduce keeps ORIGINAL order.
// ---------------------------------------------------------------------------
__global__ __launch_bounds__(256) void k_memread(
    const float* __restrict__ latent, const float* __restrict__ dots,
    const float* __restrict__ inv_mn, const float* __restrict__ mem,
    float* __restrict__ out)
{
    __shared__ float red[256];
    __shared__ int   redi[4];
    __shared__ float inv_x_s;
    const int b = blockIdx.x, tid = threadIdx.x;
    const int w = tid >> 6, lane = tid & 63;
    float lx = latent[(size_t)b * 256 + tid];
    red[tid] = lx * lx;
    __syncthreads();
    for (int s = 128; s > 0; s >>= 1) {
        if (tid < s) red[tid] += red[tid + s];
        __syncthreads();
    }
    if (tid == 0) inv_x_s = 1.f / fmaxf(sqrtf(red[0]), 1e-12f);
    __syncthreads();
    const float inv_x = inv_x_s;

    float vals[16];
    for (int j = 0; j < 16; ++j) {
        int m = tid + j * 256;
        vals[j] = dots[(size_t)b * 4096 + m] * inv_mn[m] * inv_x;
    }
    float tv[10]; int ti[10];
    for (int t = 0; t < 10; ++t) {
        float bv = -1e30f; int bidx = 0x7fffffff;
        #pragma unroll
        for (int j = 0; j < 16; ++j) {
            int m = tid + j * 256;
            float v = vals[j];
            if (v > bv || (v == bv && m < bidx)) { bv = v; bidx = m; }
        }
        #pragma unroll
        for (int off = 32; off > 0; off >>= 1) {
            float ov = __shfl_xor(bv, off);
            int   oi = __shfl_xor(bidx, off);
            if (ov > bv || (ov == bv && oi < bidx)) { bv = ov; bidx = oi; }
        }
        if (lane == 0) { red[w] = bv; redi[w] = bidx; }
        __syncthreads();
        float fv = red[0]; int fi = redi[0];
        #pragma unroll
        for (int q = 1; q < 4; ++q) {
            float v2 = red[q]; int i2 = redi[q];
            if (v2 > fv || (v2 == fv && i2 < fi)) { fv = v2; fi = i2; }
        }
        tv[t] = fv; ti[t] = fi;
        if ((fi & 255) == tid) vals[fi >> 8] = -1e30f;
        __syncthreads();
    }
    float wgt[10], wsum = 0.f;
    for (int t = 0; t < 10; ++t) { wgt[t] = expf(tv[t] - tv[0]); wsum += wgt[t]; }
    float inv_ws = 1.f / wsum;
    float acc = 0.f;
    for (int t = 0; t < 10; ++t) acc += (wgt[t] * inv_ws) * mem[(size_t)ti[t] * 256 + tid];
    out[(size_t)b * 256 + tid] = acc;
}

// ---------------------------------------------------------------------------
// Weight repack.
//   pk2h[((tap*2+nt)*16+oc)*32+ic] fp16  from c1_w [32][32][3][3] (MFMA B)
//   pk3h[((q*4+t)*16+oc)*32+ic]   fp16  from upt2_w [32][16][4][4] (MFMA B)
//   pk4[c16][tap9][o8]                   from c2_w   [8][16][3][3]
//   pk5[blk2][j128][c32]                 from blk_ff2_w [2][32][128]
// ---------------------------------------------------------------------------
__global__ __launch_bounds__(256) void k_pack(
    const float* __restrict__ wc1, const float* __restrict__ wt2,
    const float* __restrict__ wc2, const float* __restrict__ w2src,
    half_t* __restrict__ pk2h, half_t* __restrict__ pk3h,
    float* __restrict__ pk4, float* __restrict__ pk5)
{
    int i = blockIdx.x * 256 + threadIdx.x;
    if (i < 9216) {
        int ic = i & 31, oc = (i >> 5) & 15, nt = (i >> 9) & 1, t = i >> 10;
        pk2h[i] = (half_t)wc1[((nt * 16 + oc) * 32 + ic) * 9 + t];
    }
    if (i < 8192) {
        int ic = i & 31, oc = (i >> 5) & 15, t = (i >> 9) & 3, q = i >> 11;
        int wy = t >> 1, wx = t & 1, py = q >> 1, px = q & 1;
        int ky = 3 - py - 2 * wy, kx = 3 - px - 2 * wx;
        pk3h[i] = (half_t)wt2[((ic * 16 + oc) * 4 + ky) * 4 + kx];
    }
    if (i < 1152) {
        int o = i & 7, tap = (i >> 3) % 9, c = i / 72;
        pk4[i] = wc2[(o * 16 + c) * 9 + tap];
    }
    if (i < 8192) {
        int c = i & 31, j = (i >> 5) & 127, bq = i >> 12;
        pk5[i] = w2src[bq * 4096 + c * 128 + j];
    }
}

// ---------------------------------------------------------------------------
// Conv2d 32->32 k3 p1, 14x14, ReLU — MFMA. 2 samples/block.
// Output d2h fp16 channel-minor [sample][196][32] (feeds MFMA convt2).
// ---------------------------------------------------------------------------
__global__ __launch_bounds__(256) void k_conv1(
    const half_t* __restrict__ in, const half_t* __restrict__ wh,
    const float* __restrict__ bias, half_t* __restrict__ out)
{
    __shared__ __align__(16) half_t P[2 * 16 * 16 * 40];   // 40960 B
    const int tid = threadIdx.x;
    const int w = tid >> 6, lane = tid & 63;
    const size_t b0 = (size_t)blockIdx.x * 2;

    for (int e = tid; e < 10240; e += 256) ((unsigned int*)P)[e] = 0u;
    __syncthreads();
    {
        const unsigned int* src = (const unsigned int*)in;
        for (int e = tid; e < 6272; e += 256) {
            int si = e / 3136;
            int rem = e - si * 3136;
            int p = rem >> 4, c2 = rem & 15;
            int y = p / 14, x = p % 14;
            ((unsigned int*)P)[si * 5120 + ((y + 1) * 16 + (x + 1)) * 20 + c2] =
                src[(b0 + si) * 3136 + rem];
        }
    }

    h8v bfr[9][2];
    #pragma unroll
    for (int t = 0; t < 9; ++t)
        #pragma unroll
        for (int nt = 0; nt < 2; ++nt)
            bfr[t][nt] = *(const h8v*)&wh[((size_t)((t * 2 + nt) * 16 + (lane & 15))) * 32 + (lane >> 4) * 8];

    __syncthreads();

    const int kseg = (lane >> 4) * 8;
    const int oc = lane & 15;
    const float bv0 = bias[oc], bv1 = bias[16 + oc];

    for (int job = w; job < 26; job += 4) {
        const int si = job >= 13 ? 1 : 0;
        const int tile = job - si * 13;
        int p = tile * 16 + (lane & 15);
        if (p > 195) p = 195;
        const int y = p / 14, x = p % 14;
        const half_t* Pb = P + si * 10240;

        f4v acc0 = (f4v){0.f, 0.f, 0.f, 0.f};
        f4v acc1 = (f4v){0.f, 0.f, 0.f, 0.f};
        #pragma unroll
        for (int ky = 0; ky < 3; ++ky) {
            #pragma unroll
            for (int kx = 0; kx < 3; ++kx) {
                h8v af = *(const h8v*)&Pb[((y + ky) * 16 + (x + kx)) * 40 + kseg];
                acc0 = __builtin_amdgcn_mfma_f32_16x16x32_f16(af, bfr[ky * 3 + kx][0], acc0, 0, 0, 0);
                acc1 = __builtin_amdgcn_mfma_f32_16x16x32_f16(af, bfr[ky * 3 + kx][1], acc1, 0, 0, 0);
            }
        }

        const int pr0 = tile * 16 + (lane >> 4) * 4;
        half_t* ob = out + (b0 + si) * 6272;
        #pragma unroll
        for (int r = 0; r < 4; ++r) {
            int pp = pr0 + r;
            if (pp < 196) {
                ob[(size_t)pp * 32 + oc]      = (half_t)fmaxf(acc0[r] + bv0, 0.f);
                ob[(size_t)pp * 32 + 16 + oc] = (half_t)fmaxf(acc1[r] + bv1, 0.f);
            }
        }
    }
}

// ---------------------------------------------------------------------------
// FUSED: ConvTranspose2d 32->16 k4 s2 p1 (MFMA) + Conv2d 16->8 k3 p1 (ReLU)
//        + Conv2d 8->1 k1. One sample/block. Results in registers; fp32
//        [8][30][32] group tile overlays the dead input tile (30720 B LDS).
// ---------------------------------------------------------------------------
__global__ __launch_bounds__(256) void k_convt23(
    const half_t* __restrict__ in, const half_t* __restrict__ pk3h,
    const float* __restrict__ bt2, const float* __restrict__ pk4,
    const float* __restrict__ b2, const float* __restrict__ w3,
    const float* __restrict__ b3, float* __restrict__ out)
{
    __shared__ __align__(16) unsigned char Lraw[30720];
    half_t* Pin = (half_t*)Lraw;     // [16][16][40] halves = 20480 B
    float*  P2  = (float*)Lraw;      // [8][30][32] floats = 30720 B (overlay)
    const int tid = threadIdx.x;
    const int w = tid >> 6, lane = tid & 63;
    const int b = blockIdx.x;

    for (int e = tid; e < 5120; e += 256) ((unsigned int*)Pin)[e] = 0u;
    __syncthreads();
    {
        const unsigned int* src = (const unsigned int*)in;
        for (int e = tid; e < 3136; e += 256) {
            int p = e >> 4, c2 = e & 15;
            int y = p / 14, x = p % 14;
            ((unsigned int*)Pin)[((y + 1) * 16 + (x + 1)) * 20 + c2] =
                src[(size_t)b * 3136 + e];
        }
    }
    __syncthreads();

    const int oc = lane & 15;
    const int kseg = (lane >> 4) * 8;

    f4v res[13];
    #pragma unroll
    for (int j = 0; j < 13; ++j) {
        const int job = w + 4 * j;
        const int q = job / 13, tile = job - q * 13;
        const int py = q >> 1, px = q & 1;
        int p = tile * 16 + (lane & 15);
        if (p > 195) p = 195;
        const int ty = p / 14, tx = p % 14;
        f4v a = (f4v){0.f, 0.f, 0.f, 0.f};
        #pragma unroll
        for (int t = 0; t < 4; ++t) {
            const int wy = t >> 1, wx = t & 1;
            h8v bf = *(const h8v*)&pk3h[((size_t)((q * 4 + t) * 16 + oc)) * 32 + kseg];
            h8v af = *(const h8v*)&Pin[((ty + py + wy) * 16 + (tx + px + wx)) * 40 + kseg];
            a = __builtin_amdgcn_mfma_f32_16x16x32_f16(af, bf, a, 0, 0, 0);
        }
        res[j] = a;
    }
    __syncthreads();   // all input-tile reads done; overlay safe

    const bool active2 = tid < 196;
    int row = active2 ? tid / 7 : 0;
    int tx0b = active2 ? (tid % 7) * 4 : 0;
    const float bco = bt2[oc];

    float acc2[4][8];
    #pragma unroll
    for (int i = 0; i < 4; ++i)
        #pragma unroll
        for (int o = 0; o < 8; ++o) acc2[i][o] = 0.f;

    #pragma unroll
    for (int g = 0; g < 2; ++g) {
        for (int e = tid; e < 7680; e += 256) P2[e] = 0.f;
        __syncthreads();
        if ((oc >> 3) == g) {
            #pragma unroll
            for (int j = 0; j < 13; ++j) {
                const int job = w + 4 * j;
                const int q = job / 13, tile = job - q * 13;
                const int py = q >> 1, px = q & 1;
                const int pr0 = tile * 16 + (lane >> 4) * 4;
                #pragma unroll
                for (int r = 0; r < 4; ++r) {
                    int p = pr0 + r;
                    if (p < 196) {
                        int Y = 2 * (p / 14) + py, X = 2 * (p % 14) + px;
                        P2[((oc & 7) * 30 + Y + 1) * 32 + (X + 1)] = fmaxf(res[j][r] + bco, 0.f);
                    }
                }
            }
        }
        __syncthreads();
        for (int cl = 0; cl < 8; ++cl) {
            const float* Pb = &P2[(cl * 30 + row) * 32 + tx0b];
            const float* wb = pk4 + (size_t)(g * 8 + cl) * 72;
            #pragma unroll
            for (int ky = 0; ky < 3; ++ky) {
                float4 a = *(const float4*)&Pb[ky * 32];
                float4 bq = *(const float4*)&Pb[ky * 32 + 4];
                float rowb[8] = {a.x, a.y, a.z, a.w, bq.x, bq.y, bq.z, bq.w};
                #pragma unroll
                for (int kx = 0; kx < 3; ++kx) {
                    const float* wt = wb + (ky * 3 + kx) * 8;
                    #pragma unroll
                    for (int o = 0; o < 8; ++o) {
                        float wv2 = wt[o];
                        #pragma unroll
                        for (int i = 0; i < 4; ++i)
                            acc2[i][o] = fmaf(rowb[i + kx], wv2, acc2[i][o]);
                    }
                }
            }
        }
        __syncthreads();
    }

    if (active2) {
        const float bias3 = b3[0];
        #pragma unroll
        for (int i = 0; i < 4; ++i) {
            float r = bias3;
            #pragma unroll
            for (int o = 0; o < 8; ++o) r += fmaxf(acc2[i][o] + b2[o], 0.f) * w3[o];
            out[(size_t)b * 784 + row * 28 + tx0b + i] = r;
        }
    }
}

// ---------------------------------------------------------------------------
extern "C" void kernel_launch(void* const* d_in, const int* in_sizes, int n_in,
                              void* d_out, int out_size, void* d_ws, size_t ws_size,
                              hipStream_t stream)
{
    const float* x       = (const float*)d_in[0];
    const float* patch_w = (const float*)d_in[1];
    const float* patch_b = (const float*)d_in[2];
    const float* ln1g    = (const float*)d_in[3];
    const float* ln1b    = (const float*)d_in[4];
    const float* wi      = (const float*)d_in[5];
    const float* bi      = (const float*)d_in[6];
    const float* wo      = (const float*)d_in[7];
    const float* bo      = (const float*)d_in[8];
    const float* ln2g    = (const float*)d_in[9];
    const float* ln2b    = (const float*)d_in[10];
    const float* w1      = (const float*)d_in[11];
    const float* b1      = (const float*)d_in[12];
    const float* w2      = (const float*)d_in[13];
    const float* b2      = (const float*)d_in[14];
    const float* lat_w   = (const float*)d_in[15];
    const float* lat_b   = (const float*)d_in[16];
    const float* memory  = (const float*)d_in[17];
    const float* dec_w   = (const float*)d_in[18];
    const float* dec_b   = (const float*)d_in[19];
    const float* upt1_w  = (const float*)d_in[20];
    const float* upt1_b  = (const float*)d_in[21];
    const float* c1_w    = (const float*)d_in[22];
    const float* c1_b    = (const float*)d_in[23];
    const float* upt2_w  = (const float*)d_in[24];
    const float* upt2_b  = (const float*)d_in[25];
    const float* c2_w    = (const float*)d_in[26];
    const float* c2_b    = (const float*)d_in[27];
    const float* c3_w    = (const float*)d_in[28];
    const float* c3_b    = (const float*)d_in[29];
    float* outp = (float*)d_out;

    float* ws = (float*)d_ws;
    size_t off = 0;
    auto alloc = [&](size_t n) { float* p = ws + off; off += (n + 63) & ~(size_t)63; return p; };
    float* tokens     = alloc((size_t)B_TOT * 1568);
    float* latent     = alloc((size_t)B_TOT * 256);
    float* dots       = alloc((size_t)B_TOT * 4096);
    float* mem_latent = alloc((size_t)B_TOT * 256);
    float* inv_mn     = alloc(4096);
    half_t* pk2h      = (half_t*)alloc(4608);
    half_t* pk3h      = (half_t*)alloc(4096);
    float* pk4        = alloc(1152);
    float* pk5        = alloc(8192);
    float* Wf         = alloc((size_t)6272 * 256);
    float* bf         = alloc(6272);
    half_t* d1h       = (half_t*)alloc((size_t)CHUNK * 6272 / 2);
    half_t* d2h       = (half_t*)alloc((size_t)CHUNK * 6272 / 2);
    (void)in_sizes; (void)n_in; (void)out_size; (void)ws_size;

    // Weight repack + dec/convt1 algebraic fusion (Wf rows channel-minor)
    k_pack<<<36, 256, 0, stream>>>(c1_w, upt2_w, c2_w, w2, pk2h, pk3h, pk4, pk5);
    k_fuse<<<196, 256, 0, stream>>>(upt1_w, upt1_b, dec_w, dec_b, Wf, bf);

    // Encoder (wave-per-sample)
    k_tokens<<<B_TOT / 4, 256, 0, stream>>>(x, patch_w, patch_b, ln1g, ln1b, wi, bi,
                                            wo, bo, ln2g, ln2b, w1, b1, pk5, b2, tokens);
    k_gemm<<<dim3(256 / 64, B_TOT / 128), 256, 0, stream>>>(tokens, lat_w, lat_b, latent,
                                                            B_TOT, 256, 1568, 0);
    k_mnorm<<<4096, 256, 0, stream>>>(memory, inv_mn);
    // dots via split-fp16 MFMA (upstream-of-topk numerics probe; see header)
    k_sgemm<<<dim3(4096 / 128, B_TOT / 64), 256, 0, stream>>>(latent, memory, dots,
                                                              B_TOT, 4096, 256);
    k_memread<<<B_TOT, 256, 0, stream>>>(latent, dots, inv_mn, memory, mem_latent);

    // Decoder, full batch in one pass.
    for (int c = 0; c < B_TOT / CHUNK; ++c) {
        const float* ml = mem_latent + (size_t)c * CHUNK * 256;
        k_dgemm<<<dim3(6272 / 128, CHUNK / 64), 256, 0, stream>>>(ml, Wf, bf, d1h,
                                                                  CHUNK, 6272, 256);
        k_conv1  <<<CHUNK / 2, 256, 0, stream>>>(d1h, pk2h, c1_b, d2h);
        k_convt23<<<CHUNK, 256, 0, stream>>>(d2h, pk3h, upt2_b, pk4, c2_b, c3_w, c3_b,
                                             outp + (size_t)c * CHUNK * 784);
    }
}

// Round 15
// 1064.862 us; speedup vs baseline: 1.7597x; 1.0740x over previous
//
#include <hip/hip_runtime.h>
#include <math.h>

#define B_TOT 4096
#define CHUNK 4096

typedef _Float16 half_t;
typedef _Float16 h2 __attribute__((ext_vector_type(2)));
typedef _Float16 h8v __attribute__((ext_vector_type(8)));
typedef float f4v __attribute__((ext_vector_type(4)));
typedef float f2v __attribute__((ext_vector_type(2)));

#if __has_builtin(__builtin_amdgcn_fdot2)
#define FDOT2(a, b, c) __builtin_amdgcn_fdot2((a), (b), (c), false)
#else
#define FDOT2(a, b, c) fmaf((float)(a)[1], (float)(b)[1], fmaf((float)(a)[0], (float)(b)[0], (c)))
#endif

// k_tokens: fp32 activations computed with PACKED fp32 math (v_pk_fma_f32 via
// float2 ext-vector arithmetic) — per-element exact FMA; only dot-product
// summation ORDER changes (~1e-7 reassociation, inside the budget validated
// by round-14's split-fp16 dots probe at ~5e-7). V stays fp32 (round-4).
// latent + dots GEMMs: split-fp16 MFMA (hi+lo/2048, 3 passes, fp32-class err).
// Decoder: fp16-MFMA end to end (validated r10-r12).
#define KSTR 36
#define VSTR 34
#define KBYTES (49 * 72)
#define WAVE_LDS (49 * 72 + 49 * 136)  // 10192
#define WI_OFF  (4 * WAVE_LDS)         // 40768
#define BLOCK_LDS (WI_OFF + 12288)     // 53056

// ---------------------------------------------------------------------------
// Fused: patch conv (1->32, k4 s4) + 2 transformer blocks. Packed-fp32 math.
// ---------------------------------------------------------------------------
__global__ __launch_bounds__(256) void k_tokens(
    const float* __restrict__ x, const float* __restrict__ pw, const float* __restrict__ pb,
    const float* __restrict__ ln1g, const float* __restrict__ ln1b,
    const float* __restrict__ wi, const float* __restrict__ bi,
    const float* __restrict__ wo, const float* __restrict__ bo,
    const float* __restrict__ ln2g, const float* __restrict__ ln2b,
    const float* __restrict__ w1, const float* __restrict__ fb1,
    const float* __restrict__ w2t, const float* __restrict__ fb2,
    float* __restrict__ tokens)
{
    __shared__ __align__(16) unsigned char Lraw[BLOCK_LDS];
    const int tid = threadIdx.x;
    const int wv = tid >> 6, lane = tid & 63;
    const int b = blockIdx.x * 4 + wv;
    half_t* Kb = (half_t*)(Lraw + wv * WAVE_LDS);
    float*  Vb = (float*)(Lraw + wv * WAVE_LDS + KBYTES);
    const float* wiL = (const float*)(Lraw + WI_OFF);
    float* Lf = (float*)Lraw;            // FF-weight overlay (block-wide)
    const bool is_tok = lane < 49;
    const int s = is_tok ? lane : 48;
    const int py = s / 7, px = s % 7;

    // --- prologue: stage blk-0 qkv weights (visible after barrier (A)) ---
    {
        const float4* srcw = (const float4*)(wi);
        float4* dstw = (float4*)(Lraw + WI_OFF);
        for (int e = tid; e < 768; e += 256) dstw[e] = srcw[e];
    }

    // --- patch conv: direct float4 loads; packed accumulate ---
    f2v xv2[8];
    const float* xb = x + (size_t)b * 784 + py * 112 + px * 4;
    #pragma unroll
    for (int r = 0; r < 4; ++r) {
        float4 vq = *(const float4*)(xb + r * 28);
        f2v lo; lo[0] = vq.x; lo[1] = vq.y;
        f2v hi; hi[0] = vq.z; hi[1] = vq.w;
        xv2[2 * r] = lo; xv2[2 * r + 1] = hi;
    }
    f2v t2[16];
    #pragma unroll
    for (int c = 0; c < 32; ++c) {
        const float* wr = pw + c * 16;
        f2v a2 = (f2v){0.f, 0.f};
        #pragma unroll
        for (int c2 = 0; c2 < 4; ++c2) {
            float4 wq = *(const float4*)&wr[4 * c2];
            f2v w0; w0[0] = wq.x; w0[1] = wq.y;
            f2v w1v; w1v[0] = wq.z; w1v[1] = wq.w;
            a2 += xv2[2 * c2] * w0;
            a2 += xv2[2 * c2 + 1] * w1v;
        }
        t2[c >> 1][c & 1] = pb[c] + a2[0] + a2[1];
    }

    for (int blk = 0; blk < 2; ++blk) {
        const float* bib = bi + blk * 96;

        // --- LN1 (packed sums; reassociation-level change only) ---
        f2v mu2 = (f2v){0.f, 0.f};
        #pragma unroll
        for (int i = 0; i < 16; ++i) mu2 += t2[i];
        float mu = (mu2[0] + mu2[1]) * 0.03125f;
        f2v mub; mub[0] = mu; mub[1] = mu;
        f2v var2 = (f2v){0.f, 0.f};
        #pragma unroll
        for (int i = 0; i < 16; ++i) { f2v d = t2[i] - mub; var2 += d * d; }
        float rstd = rsqrtf((var2[0] + var2[1]) * 0.03125f + 1e-5f);
        f2v rstd2; rstd2[0] = rstd; rstd2[1] = rstd;
        f2v xn2[16];
        {
            const f2v* g2 = (const f2v*)(ln1g + blk * 32);
            const f2v* bl2 = (const f2v*)(ln1b + blk * 32);
            #pragma unroll
            for (int i = 0; i < 16; ++i)
                xn2[i] = (t2[i] - mub) * rstd2 * g2[i] + bl2[i];
        }

        __syncthreads();   // (A) prior-phase LDS reads done; wi stage visible

        // --- K projection -> LDS fp16 ---
        #pragma unroll 4
        for (int d = 0; d < 32; ++d) {
            const float* wr = wiL + (32 + d) * 32;
            f2v a2 = (f2v){0.f, 0.f};
            #pragma unroll
            for (int c2 = 0; c2 < 8; ++c2) {
                float4 wq = *(const float4*)&wr[4 * c2];
                f2v w0; w0[0] = wq.x; w0[1] = wq.y;
                f2v w1v; w1v[0] = wq.z; w1v[1] = wq.w;
                a2 += xn2[2 * c2] * w0;
                a2 += xn2[2 * c2 + 1] * w1v;
            }
            if (is_tok) Kb[s * KSTR + d] = (half_t)(bib[32 + d] + a2[0] + a2[1]);
        }
        // --- V projection -> LDS fp32 ---
        #pragma unroll 4
        for (int d = 0; d < 32; ++d) {
            const float* wr = wiL + (64 + d) * 32;
            f2v a2 = (f2v){0.f, 0.f};
            #pragma unroll
            for (int c2 = 0; c2 < 8; ++c2) {
                float4 wq = *(const float4*)&wr[4 * c2];
                f2v w0; w0[0] = wq.x; w0[1] = wq.y;
                f2v w1v; w1v[0] = wq.z; w1v[1] = wq.w;
                a2 += xn2[2 * c2] * w0;
                a2 += xn2[2 * c2 + 1] * w1v;
            }
            if (is_tok) Vb[s * VSTR + d] = bib[64 + d] + a2[0] + a2[1];
        }
        // --- Q projection (scaled) ---
        float q0[32];
        #pragma unroll 4
        for (int d = 0; d < 32; ++d) {
            const float* wr = wiL + d * 32;
            f2v a2 = (f2v){0.f, 0.f};
            #pragma unroll
            for (int c2 = 0; c2 < 8; ++c2) {
                float4 wq = *(const float4*)&wr[4 * c2];
                f2v w0; w0[0] = wq.x; w0[1] = wq.y;
                f2v w1v; w1v[0] = wq.z; w1v[1] = wq.w;
                a2 += xn2[2 * c2] * w0;
                a2 += xn2[2 * c2 + 1] * w1v;
            }
            q0[d] = (bib[d] + a2[0] + a2[1]) * 0.25f;
        }
        h2 qh[16];
        #pragma unroll
        for (int i = 0; i < 16; ++i) {
            h2 hh; hh[0] = (half_t)q0[2 * i]; hh[1] = (half_t)q0[2 * i + 1];
            qh[i] = hh;
        }

        // wave-local fence: own K/V ds_writes visible before broadcast reads
        __asm__ volatile("s_waitcnt lgkmcnt(0)" ::: "memory");

        // --- attention: 2 heads of 16 dims; packed PV ---
        f2v o2[16];
        #pragma unroll
        for (int i = 0; i < 16; ++i) o2[i] = (f2v){0.f, 0.f};
        float l0 = 0.f, l1 = 0.f;
        union H4 { double qd; h2 p[2]; };
        for (int j = 0; j < 49; ++j) {
            const double* kr = (const double*)(Kb + j * KSTR);
            const float* vr = Vb + j * VSTR;
            H4 u0, u1, u2, u3, w0, w1h, w2h, w3;
            u0.qd = kr[0]; u1.qd = kr[1]; u2.qd = kr[2]; u3.qd = kr[3];
            w0.qd = kr[4]; w1h.qd = kr[5]; w2h.qd = kr[6]; w3.qd = kr[7];
            float s0a = 0.f, s0b = 0.f, s1a = 0.f, s1b = 0.f;
            s0a = FDOT2(u0.p[0], qh[0], s0a); s0a = FDOT2(u0.p[1], qh[1], s0a);
            s0b = FDOT2(u1.p[0], qh[2], s0b); s0b = FDOT2(u1.p[1], qh[3], s0b);
            s0a = FDOT2(u2.p[0], qh[4], s0a); s0a = FDOT2(u2.p[1], qh[5], s0a);
            s0b = FDOT2(u3.p[0], qh[6], s0b); s0b = FDOT2(u3.p[1], qh[7], s0b);
            s1a = FDOT2(w0.p[0], qh[8], s1a); s1a = FDOT2(w0.p[1], qh[9], s1a);
            s1b = FDOT2(w1h.p[0], qh[10], s1b); s1b = FDOT2(w1h.p[1], qh[11], s1b);
            s1a = FDOT2(w2h.p[0], qh[12], s1a); s1a = FDOT2(w2h.p[1], qh[13], s1a);
            s1b = FDOT2(w3.p[0], qh[14], s1b); s1b = FDOT2(w3.p[1], qh[15], s1b);
            float p0 = __expf(s0a + s0b), p1 = __expf(s1a + s1b);
            l0 += p0; l1 += p1;
            f2v p02; p02[0] = p0; p02[1] = p0;
            f2v p12; p12[0] = p1; p12[1] = p1;
            #pragma unroll
            for (int i = 0; i < 8; ++i) {
                f2v va = *(const f2v*)&vr[2 * i];
                o2[i] += p02 * va;
                f2v vc = *(const f2v*)&vr[16 + 2 * i];
                o2[8 + i] += p12 * vc;
            }
        }
        {
            float il0 = 1.f / l0, il1 = 1.f / l1;
            f2v il02; il02[0] = il0; il02[1] = il0;
            f2v il12; il12[0] = il1; il12[1] = il1;
            #pragma unroll
            for (int i = 0; i < 8; ++i) { o2[i] *= il02; o2[8 + i] *= il12; }
        }

        // --- out projection + residual (wave-uniform global weights) ---
        #pragma unroll
        for (int c = 0; c < 32; ++c) {
            const float* wr = wo + blk * 1024 + c * 32;
            f2v a2 = (f2v){0.f, 0.f};
            #pragma unroll
            for (int c2 = 0; c2 < 8; ++c2) {
                float4 wq = *(const float4*)&wr[4 * c2];
                f2v w0; w0[0] = wq.x; w0[1] = wq.y;
                f2v w1v; w1v[0] = wq.z; w1v[1] = wq.w;
                a2 += o2[2 * c2] * w0;
                a2 += o2[2 * c2 + 1] * w1v;
            }
            t2[c >> 1][c & 1] += bo[blk * 32 + c] + a2[0] + a2[1];
        }

        // --- LN2 ---
        mu2 = (f2v){0.f, 0.f};
        #pragma unroll
        for (int i = 0; i < 16; ++i) mu2 += t2[i];
        mu = (mu2[0] + mu2[1]) * 0.03125f;
        mub[0] = mu; mub[1] = mu;
        var2 = (f2v){0.f, 0.f};
        #pragma unroll
        for (int i = 0; i < 16; ++i) { f2v d = t2[i] - mub; var2 += d * d; }
        rstd = rsqrtf((var2[0] + var2[1]) * 0.03125f + 1e-5f);
        rstd2[0] = rstd; rstd2[1] = rstd;
        {
            const f2v* g2 = (const f2v*)(ln2g + blk * 32);
            const f2v* bl2 = (const f2v*)(ln2b + blk * 32);
            #pragma unroll
            for (int i = 0; i < 16; ++i)
                xn2[i] = (t2[i] - mub) * rstd2 * g2[i] + bl2[i];
        }

        __syncthreads();   // (C) all waves done reading K/V + wi

        // --- stage FF weights (overlay over KV) + next blk's wi ---
        {
            const float4* src1 = (const float4*)(w1 + blk * 4096);
            const float4* src2 = (const float4*)(w2t + blk * 4096);
            float4* dst = (float4*)Lraw;
            for (int e = tid; e < 1024; e += 256) dst[e] = src1[e];
            for (int e = tid; e < 1024; e += 256) dst[1024 + e] = src2[e];
            if (blk == 0) {
                const float4* srcw = (const float4*)(wi + 3072);
                float4* dstw = (float4*)(Lraw + WI_OFF);
                for (int e = tid; e < 768; e += 256) dstw[e] = srcw[e];
            }
        }
        __syncthreads();   // (D) FF weights (and wi for blk1) visible

        // --- FF from LDS: packed dot + packed axpy ---
        const float* w2L = Lf + 4096;
        #pragma unroll 2
        for (int j = 0; j < 128; ++j) {
            const float* wr = Lf + j * 32;
            f2v h2a = (f2v){0.f, 0.f};
            #pragma unroll
            for (int c2 = 0; c2 < 8; ++c2) {
                float4 wq = *(const float4*)&wr[4 * c2];
                f2v w0; w0[0] = wq.x; w0[1] = wq.y;
                f2v w1v; w1v[0] = wq.z; w1v[1] = wq.w;
                h2a += xn2[2 * c2] * w0;
                h2a += xn2[2 * c2 + 1] * w1v;
            }
            float h = fb1[blk * 128 + j] + h2a[0] + h2a[1];
            h = 0.5f * h * (1.f + erff(h * 0.7071067811865476f));
            f2v hh; hh[0] = h; hh[1] = h;
            const float* w2r = w2L + j * 32;
            #pragma unroll
            for (int c2 = 0; c2 < 8; ++c2) {
                float4 wq = *(const float4*)&w2r[4 * c2];
                f2v w0; w0[0] = wq.x; w0[1] = wq.y;
                f2v w1v; w1v[0] = wq.z; w1v[1] = wq.w;
                t2[2 * c2]     += hh * w0;
                t2[2 * c2 + 1] += hh * w1v;
            }
        }
        {
            const f2v* fb22 = (const f2v*)(fb2 + blk * 32);
            #pragma unroll
            for (int i = 0; i < 16; ++i) t2[i] += fb22[i];
        }
    }

    if (is_tok) {
        float* op = tokens + (size_t)b * 1568 + s * 32;
        #pragma unroll
        for (int i = 0; i < 8; ++i) {
            float4 vv = make_float4(t2[2 * i][0], t2[2 * i][1],
                                    t2[2 * i + 1][0], t2[2 * i + 1][1]);
            *(float4*)&op[4 * i] = vv;
        }
    }
}

// ---------------------------------------------------------------------------
// SPLIT-fp16 MFMA GEMM: C[M,N] = A[M,K] @ B[N,K]^T (+bias), fp32 out.
// x = hi + lo/2048; dot = Σhi·hi + (Σhi·lo + Σlo·hi)/2048, fp32 accum.
// Error ~5e-7 (fp32-class; validated round 14 on dots). Used for latent+dots.
// ---------------------------------------------------------------------------
__global__ __launch_bounds__(256) void k_sgemm(
    const float* __restrict__ A, const float* __restrict__ Bm,
    const float* __restrict__ bias, float* __restrict__ C,
    int M, int N, int K)
{
    __shared__ __align__(16) half_t Ah[64 * 40];
    __shared__ __align__(16) half_t Al[64 * 40];
    __shared__ __align__(16) half_t Bh[128 * 40];
    __shared__ __align__(16) half_t Bl[128 * 40];
    const int tid = threadIdx.x;
    const int n0 = blockIdx.x * 128, m0 = blockIdx.y * 64;
    const int w = tid >> 6, lane = tid & 63;
    const int wm = (w >> 1) * 32, wn = (w & 1) * 64;
    const int lr = lane & 15, lk = lane >> 4;

    const int ar = tid >> 2, aseg = (tid & 3) * 8;
    const int br = tid >> 1, bseg = (tid & 1) * 16;

    f4v acch[2][4], accm[2][4];
    #pragma unroll
    for (int i = 0; i < 2; ++i)
        #pragma unroll
        for (int j = 0; j < 4; ++j) {
            acch[i][j] = (f4v){0.f, 0.f, 0.f, 0.f};
            accm[i][j] = (f4v){0.f, 0.f, 0.f, 0.f};
        }

    for (int k0 = 0; k0 < K; k0 += 32) {
        {
            const float* ap = A + (size_t)(m0 + ar) * K + k0 + aseg;
            float4 a0 = *(const float4*)ap;
            float4 a1 = *(const float4*)(ap + 4);
            float av[8] = {a0.x, a0.y, a0.z, a0.w, a1.x, a1.y, a1.z, a1.w};
            h8v ah, al;
            #pragma unroll
            for (int i = 0; i < 8; ++i) {
                half_t h = (half_t)av[i];
                ah[i] = h;
                al[i] = (half_t)((av[i] - (float)h) * 2048.0f);
            }
            *(h8v*)&Ah[ar * 40 + aseg] = ah;
            *(h8v*)&Al[ar * 40 + aseg] = al;

            const float* bp = Bm + (size_t)(n0 + br) * K + k0 + bseg;
            float4 b0 = *(const float4*)bp;
            float4 b1 = *(const float4*)(bp + 4);
            float4 b2 = *(const float4*)(bp + 8);
            float4 b3 = *(const float4*)(bp + 12);
            float bv[16] = {b0.x, b0.y, b0.z, b0.w, b1.x, b1.y, b1.z, b1.w,
                            b2.x, b2.y, b2.z, b2.w, b3.x, b3.y, b3.z, b3.w};
            h8v bh0, bh1, bl0, bl1;
            #pragma unroll
            for (int i = 0; i < 8; ++i) {
                half_t h = (half_t)bv[i];
                bh0[i] = h;
                bl0[i] = (half_t)((bv[i] - (float)h) * 2048.0f);
                half_t hq = (half_t)bv[8 + i];
                bh1[i] = hq;
                bl1[i] = (half_t)((bv[8 + i] - (float)hq) * 2048.0f);
            }
            *(h8v*)&Bh[br * 40 + bseg]     = bh0;
            *(h8v*)&Bh[br * 40 + bseg + 8] = bh1;
            *(h8v*)&Bl[br * 40 + bseg]     = bl0;
            *(h8v*)&Bl[br * 40 + bseg + 8] = bl1;
        }
        __syncthreads();
        h8v afh[2], afl[2], bfh[4], bfl[4];
        #pragma unroll
        for (int i = 0; i < 2; ++i) {
            afh[i] = *(const h8v*)&Ah[(wm + i * 16 + lr) * 40 + lk * 8];
            afl[i] = *(const h8v*)&Al[(wm + i * 16 + lr) * 40 + lk * 8];
        }
        #pragma unroll
        for (int j = 0; j < 4; ++j) {
            bfh[j] = *(const h8v*)&Bh[(wn + j * 16 + lr) * 40 + lk * 8];
            bfl[j] = *(const h8v*)&Bl[(wn + j * 16 + lr) * 40 + lk * 8];
        }
        #pragma unroll
        for (int i = 0; i < 2; ++i)
            #pragma unroll
            for (int j = 0; j < 4; ++j) {
                acch[i][j] = __builtin_amdgcn_mfma_f32_16x16x32_f16(afh[i], bfh[j], acch[i][j], 0, 0, 0);
                accm[i][j] = __builtin_amdgcn_mfma_f32_16x16x32_f16(afh[i], bfl[j], accm[i][j], 0, 0, 0);
                accm[i][j] = __builtin_amdgcn_mfma_f32_16x16x32_f16(afl[i], bfh[j], accm[i][j], 0, 0, 0);
            }
        __syncthreads();
    }

    #pragma unroll
    for (int j = 0; j < 4; ++j) {
        int n = n0 + wn + j * 16 + lr;
        float bv = bias ? bias[n] : 0.f;
        #pragma unroll
        for (int i = 0; i < 2; ++i) {
            #pragma unroll
            for (int r = 0; r < 4; ++r) {
                int m = m0 + wm + i * 16 + lk * 4 + r;
                C[(size_t)m * N + n] = acch[i][j][r] + accm[i][j][r] * (1.0f / 2048.0f) + bv;
            }
        }
    }
}

// ---------------------------------------------------------------------------
// MFMA decoder GEMM: d1h[M,N] = (fp16)relu(A[M,K] @ B[N,K]^T + bias).
// ---------------------------------------------------------------------------
__global__ __launch_bounds__(256) void k_dgemm(
    const float* __restrict__ A, const float* __restrict__ Bm,
    const float* __restrict__ bias, half_t* __restrict__ C,
    int M, int N, int K)
{
    __shared__ __align__(16) half_t As[64 * 40];
    __shared__ __align__(16) half_t Bs[128 * 40];
    const int tid = threadIdx.x;
    const int n0 = blockIdx.x * 128, m0 = blockIdx.y * 64;
    const int w = tid >> 6, lane = tid & 63;
    const int wm = (w >> 1) * 32, wn = (w & 1) * 64;
    const int lr = lane & 15, lk = lane >> 4;

    const int ar = tid >> 2, aseg = (tid & 3) * 8;
    const int br = tid >> 1, bseg = (tid & 1) * 16;

    f4v acc[2][4];
    #pragma unroll
    for (int i = 0; i < 2; ++i)
        #pragma unroll
        for (int j = 0; j < 4; ++j) acc[i][j] = (f4v){0.f, 0.f, 0.f, 0.f};

    for (int k0 = 0; k0 < K; k0 += 32) {
        {
            const float* ap = A + (size_t)(m0 + ar) * K + k0 + aseg;
            float4 a0 = *(const float4*)ap;
            float4 a1 = *(const float4*)(ap + 4);
            h8v ha;
            ha[0] = (half_t)a0.x; ha[1] = (half_t)a0.y;
            ha[2] = (half_t)a0.z; ha[3] = (half_t)a0.w;
            ha[4] = (half_t)a1.x; ha[5] = (half_t)a1.y;
            ha[6] = (half_t)a1.z; ha[7] = (half_t)a1.w;
            *(h8v*)&As[ar * 40 + aseg] = ha;

            const float* bp = Bm + (size_t)(n0 + br) * K + k0 + bseg;
            float4 b0 = *(const float4*)bp;
            float4 b1 = *(const float4*)(bp + 4);
            float4 b2 = *(const float4*)(bp + 8);
            float4 b3 = *(const float4*)(bp + 12);
            h8v hb0, hb1;
            hb0[0] = (half_t)b0.x; hb0[1] = (half_t)b0.y;
            hb0[2] = (half_t)b0.z; hb0[3] = (half_t)b0.w;
            hb0[4] = (half_t)b1.x; hb0[5] = (half_t)b1.y;
            hb0[6] = (half_t)b1.z; hb0[7] = (half_t)b1.w;
            hb1[0] = (half_t)b2.x; hb1[1] = (half_t)b2.y;
            hb1[2] = (half_t)b2.z; hb1[3] = (half_t)b2.w;
            hb1[4] = (half_t)b3.x; hb1[5] = (half_t)b3.y;
            hb1[6] = (half_t)b3.z; hb1[7] = (half_t)b3.w;
            *(h8v*)&Bs[br * 40 + bseg] = hb0;
            *(h8v*)&Bs[br * 40 + bseg + 8] = hb1;
        }
        __syncthreads();
        h8v af[2], bfr[4];
        #pragma unroll
        for (int i = 0; i < 2; ++i)
            af[i] = *(const h8v*)&As[(wm + i * 16 + lr) * 40 + lk * 8];
        #pragma unroll
        for (int j = 0; j < 4; ++j)
            bfr[j] = *(const h8v*)&Bs[(wn + j * 16 + lr) * 40 + lk * 8];
        #pragma unroll
        for (int i = 0; i < 2; ++i)
            #pragma unroll
            for (int j = 0; j < 4; ++j)
                acc[i][j] = __builtin_amdgcn_mfma_f32_16x16x32_f16(af[i], bfr[j], acc[i][j], 0, 0, 0);
        __syncthreads();
    }

    #pragma unroll
    for (int j = 0; j < 4; ++j) {
        int n = n0 + wn + j * 16 + lr;
        float bv = bias[n];
        #pragma unroll
        for (int i = 0; i < 2; ++i) {
            #pragma unroll
            for (int r = 0; r < 4; ++r) {
                int m = m0 + wm + i * 16 + lk * 4 + r;
                C[(size_t)m * N + n] = (half_t)fmaxf(acc[i][j][r] + bv, 0.f);
            }
        }
    }
}

// ---------------------------------------------------------------------------
// Fuse dec (linear 256->3136) with convt1 (convT 64->32 k4 s2 p1).
// One block per pixel p; dec_w rows read once; bit-identical Wf/bf.
// ---------------------------------------------------------------------------
__global__ __launch_bounds__(256) void k_fuse(
    const float* __restrict__ wt1, const float* __restrict__ upt1_b,
    const float* __restrict__ dec_w, const float* __restrict__ dec_b,
    float* __restrict__ Wf, float* __restrict__ bf)
{
    __shared__ float WL[4][64][32];
    const int p = blockIdx.x;
    const int k = threadIdx.x;
    const int y = p / 14, x = p % 14;

    int ky0 = 0, iy0 = 0, ky1 = 0, iy1 = 0, nky = 0;
    for (int ky = 0; ky < 4; ++ky) {
        int iyn = y + 1 - ky;
        if (iyn < 0 || (iyn & 1)) continue;
        int iy = iyn >> 1;
        if (iy > 6) continue;
        if (nky == 0) { ky0 = ky; iy0 = iy; } else { ky1 = ky; iy1 = iy; }
        ++nky;
    }
    int kx0 = 0, ix0 = 0, kx1 = 0, ix1 = 0, nkx = 0;
    for (int kx = 0; kx < 4; ++kx) {
        int ixn = x + 1 - kx;
        if (ixn < 0 || (ixn & 1)) continue;
        int ix = ixn >> 1;
        if (ix > 6) continue;
        if (nkx == 0) { kx0 = kx; ix0 = ix; } else { kx1 = kx; ix1 = ix; }
        ++nkx;
    }
    const int ntap = nky * nkx;

    for (int e = k; e < ntap * 2048; e += 256) {
        int t = e >> 11, c = (e >> 5) & 63, o = e & 31;
        int ti = (nkx == 2) ? (t >> 1) : t;
        int tj = (nkx == 2) ? (t & 1) : 0;
        int ky = ti ? ky1 : ky0;
        int kx = tj ? kx1 : kx0;
        WL[t][c][o] = wt1[((c * 32 + o) * 4 + ky) * 4 + kx];
    }
    __syncthreads();

    float acc[32];
    #pragma unroll
    for (int o = 0; o < 32; ++o) acc[o] = 0.f;
    float bacc = 0.f;

    for (int t = 0; t < ntap; ++t) {
        int ti = (nkx == 2) ? (t >> 1) : t;
        int tj = (nkx == 2) ? (t & 1) : 0;
        int iy = ti ? iy1 : iy0;
        int ix = tj ? ix1 : ix0;
        int rbase = iy * 7 + ix;
        for (int c = 0; c < 64; ++c) {
            int row = c * 49 + rbase;
            float v = dec_w[(size_t)row * 256 + k];
            const float* wr = &WL[t][c][0];
            #pragma unroll
            for (int o8 = 0; o8 < 8; ++o8) {
                float4 wq = *(const float4*)&wr[4 * o8];
                acc[4 * o8 + 0] = fmaf(wq.x, v, acc[4 * o8 + 0]);
                acc[4 * o8 + 1] = fmaf(wq.y, v, acc[4 * o8 + 1]);
                acc[4 * o8 + 2] = fmaf(wq.z, v, acc[4 * o8 + 2]);
                acc[4 * o8 + 3] = fmaf(wq.w, v, acc[4 * o8 + 3]);
            }
            if (k < 32) bacc = fmaf(WL[t][c][k], dec_b[row], bacc);
        }
    }

    #pragma unroll 4
    for (int o = 0; o < 32; ++o)
        Wf[((size_t)(p * 32 + o)) * 256 + k] = acc[o];
    if (k < 32) bf[p * 32 + k] = bacc + upt1_b[k];
}

// ---------------------------------------------------------------------------
__global__ __launch_bounds__(256) void k_mnorm(const float* __restrict__ mem, float* __restrict__ inv_norm)
{
    __shared__ float red[256];
    const int row = blockIdx.x, tid = threadIdx.x;
    float v = mem[(size_t)row * 256 + tid];
    red[tid] = v * v;
    __syncthreads();
    for (int s = 128; s > 0; s >>= 1) {
        if (tid < s) red[tid] += red[tid + s];
        __syncthreads();
    }
    if (tid == 0) inv_norm[row] = 1.f / fmaxf(sqrtf(red[0]), 1e-12f);
}

// ---------------------------------------------------------------------------
// Top-k via wave __shfl_xor lexicographic (v,idx) reduce (exactly associative).
// ---------------------------------------------------------------------------
__global__ __launch_bounds__(256) void k_memread(
    const float* __restrict__ latent, const float* __restrict__ dots,
    const float* __restrict__ inv_mn, const float* __restrict__ mem,
    float* __restrict__ out)
{
    __shared__ float red[256];
    __shared__ int   redi[4];
    __shared__ float inv_x_s;
    const int b = blockIdx.x, tid = threadIdx.x;
    const int w = tid >> 6, lane = tid & 63;
    float lx = latent[(size_t)b * 256 + tid];
    red[tid] = lx * lx;
    __syncthreads();
    for (int s = 128; s > 0; s >>= 1) {
        if (tid < s) red[tid] += red[tid + s];
        __syncthreads();
    }
    if (tid == 0) inv_x_s = 1.f / fmaxf(sqrtf(red[0]), 1e-12f);
    __syncthreads();
    const float inv_x = inv_x_s;

    float vals[16];
    for (int j = 0; j < 16; ++j) {
        int m = tid + j * 256;
        vals[j] = dots[(size_t)b * 4096 + m] * inv_mn[m] * inv_x;
    }
    float tv[10]; int ti[10];
    for (int t = 0; t < 10; ++t) {
        float bv = -1e30f; int bidx = 0x7fffffff;
        #pragma unroll
        for (int j = 0; j < 16; ++j) {
            int m = tid + j * 256;
            float v = vals[j];
            if (v > bv || (v == bv && m < bidx)) { bv = v; bidx = m; }
        }
        #pragma unroll
        for (int off = 32; off > 0; off >>= 1) {
            float ov = __shfl_xor(bv, off);
            int   oi = __shfl_xor(bidx, off);
            if (ov > bv || (ov == bv && oi < bidx)) { bv = ov; bidx = oi; }
        }
        if (lane == 0) { red[w] = bv; redi[w] = bidx; }
        __syncthreads();
        float fv = red[0]; int fi = redi[0];
        #pragma unroll
        for (int q = 1; q < 4; ++q) {
            float v2 = red[q]; int i2 = redi[q];
            if (v2 > fv || (v2 == fv && i2 < fi)) { fv = v2; fi = i2; }
        }
        tv[t] = fv; ti[t] = fi;
        if ((fi & 255) == tid) vals[fi >> 8] = -1e30f;
        __syncthreads();
    }
    float wgt[10], wsum = 0.f;
    for (int t = 0; t < 10; ++t) { wgt[t] = expf(tv[t] - tv[0]); wsum += wgt[t]; }
    float inv_ws = 1.f / wsum;
    float acc = 0.f;
    for (int t = 0; t < 10; ++t) acc += (wgt[t] * inv_ws) * mem[(size_t)ti[t] * 256 + tid];
    out[(size_t)b * 256 + tid] = acc;
}

// ---------------------------------------------------------------------------
// Weight repack.
// ---------------------------------------------------------------------------
__global__ __launch_bounds__(256) void k_pack(
    const float* __restrict__ wc1, const float* __restrict__ wt2,
    const float* __restrict__ wc2, const float* __restrict__ w2src,
    half_t* __restrict__ pk2h, half_t* __restrict__ pk3h,
    float* __restrict__ pk4, float* __restrict__ pk5)
{
    int i = blockIdx.x * 256 + threadIdx.x;
    if (i < 9216) {
        int ic = i & 31, oc = (i >> 5) & 15, nt = (i >> 9) & 1, t = i >> 10;
        pk2h[i] = (half_t)wc1[((nt * 16 + oc) * 32 + ic) * 9 + t];
    }
    if (i < 8192) {
        int ic = i & 31, oc = (i >> 5) & 15, t = (i >> 9) & 3, q = i >> 11;
        int wy = t >> 1, wx = t & 1, py = q >> 1, px = q & 1;
        int ky = 3 - py - 2 * wy, kx = 3 - px - 2 * wx;
        pk3h[i] = (half_t)wt2[((ic * 16 + oc) * 4 + ky) * 4 + kx];
    }
    if (i < 1152) {
        int o = i & 7, tap = (i >> 3) % 9, c = i / 72;
        pk4[i] = wc2[(o * 16 + c) * 9 + tap];
    }
    if (i < 8192) {
        int c = i & 31, j = (i >> 5) & 127, bq = i >> 12;
        pk5[i] = w2src[bq * 4096 + c * 128 + j];
    }
}

// ---------------------------------------------------------------------------
// Conv2d 32->32 k3 p1, 14x14, ReLU — MFMA. 2 samples/block.
// ---------------------------------------------------------------------------
__global__ __launch_bounds__(256) void k_conv1(
    const half_t* __restrict__ in, const half_t* __restrict__ wh,
    const float* __restrict__ bias, half_t* __restrict__ out)
{
    __shared__ __align__(16) half_t P[2 * 16 * 16 * 40];
    const int tid = threadIdx.x;
    const int w = tid >> 6, lane = tid & 63;
    const size_t b0 = (size_t)blockIdx.x * 2;

    for (int e = tid; e < 10240; e += 256) ((unsigned int*)P)[e] = 0u;
    __syncthreads();
    {
        const unsigned int* src = (const unsigned int*)in;
        for (int e = tid; e < 6272; e += 256) {
            int si = e / 3136;
            int rem = e - si * 3136;
            int p = rem >> 4, c2 = rem & 15;
            int y = p / 14, x = p % 14;
            ((unsigned int*)P)[si * 5120 + ((y + 1) * 16 + (x + 1)) * 20 + c2] =
                src[(b0 + si) * 3136 + rem];
        }
    }

    h8v bfr[9][2];
    #pragma unroll
    for (int t = 0; t < 9; ++t)
        #pragma unroll
        for (int nt = 0; nt < 2; ++nt)
            bfr[t][nt] = *(const h8v*)&wh[((size_t)((t * 2 + nt) * 16 + (lane & 15))) * 32 + (lane >> 4) * 8];

    __syncthreads();

    const int kseg = (lane >> 4) * 8;
    const int oc = lane & 15;
    const float bv0 = bias[oc], bv1 = bias[16 + oc];

    for (int job = w; job < 26; job += 4) {
        const int si = job >= 13 ? 1 : 0;
        const int tile = job - si * 13;
        int p = tile * 16 + (lane & 15);
        if (p > 195) p = 195;
        const int y = p / 14, x = p % 14;
        const half_t* Pb = P + si * 10240;

        f4v acc0 = (f4v){0.f, 0.f, 0.f, 0.f};
        f4v acc1 = (f4v){0.f, 0.f, 0.f, 0.f};
        #pragma unroll
        for (int ky = 0; ky < 3; ++ky) {
            #pragma unroll
            for (int kx = 0; kx < 3; ++kx) {
                h8v af = *(const h8v*)&Pb[((y + ky) * 16 + (x + kx)) * 40 + kseg];
                acc0 = __builtin_amdgcn_mfma_f32_16x16x32_f16(af, bfr[ky * 3 + kx][0], acc0, 0, 0, 0);
                acc1 = __builtin_amdgcn_mfma_f32_16x16x32_f16(af, bfr[ky * 3 + kx][1], acc1, 0, 0, 0);
            }
        }

        const int pr0 = tile * 16 + (lane >> 4) * 4;
        half_t* ob = out + (b0 + si) * 6272;
        #pragma unroll
        for (int r = 0; r < 4; ++r) {
            int pp = pr0 + r;
            if (pp < 196) {
                ob[(size_t)pp * 32 + oc]      = (half_t)fmaxf(acc0[r] + bv0, 0.f);
                ob[(size_t)pp * 32 + 16 + oc] = (half_t)fmaxf(acc1[r] + bv1, 0.f);
            }
        }
    }
}

// ---------------------------------------------------------------------------
// FUSED: ConvTranspose2d 32->16 k4 s2 p1 (MFMA) + Conv2d 16->8 k3 p1 (ReLU)
//        + Conv2d 8->1 k1. One sample/block.
// ---------------------------------------------------------------------------
__global__ __launch_bounds__(256) void k_convt23(
    const half_t* __restrict__ in, const half_t* __restrict__ pk3h,
    const float* __restrict__ bt2, const float* __restrict__ pk4,
    const float* __restrict__ b2, const float* __restrict__ w3,
    const float* __restrict__ b3, float* __restrict__ out)
{
    __shared__ __align__(16) unsigned char Lraw[30720];
    half_t* Pin = (half_t*)Lraw;
    float*  P2  = (float*)Lraw;
    const int tid = threadIdx.x;
    const int w = tid >> 6, lane = tid & 63;
    const int b = blockIdx.x;

    for (int e = tid; e < 5120; e += 256) ((unsigned int*)Pin)[e] = 0u;
    __syncthreads();
    {
        const unsigned int* src = (const unsigned int*)in;
        for (int e = tid; e < 3136; e += 256) {
            int p = e >> 4, c2 = e & 15;
            int y = p / 14, x = p % 14;
            ((unsigned int*)Pin)[((y + 1) * 16 + (x + 1)) * 20 + c2] =
                src[(size_t)b * 3136 + e];
        }
    }
    __syncthreads();

    const int oc = lane & 15;
    const int kseg = (lane >> 4) * 8;

    f4v res[13];
    #pragma unroll
    for (int j = 0; j < 13; ++j) {
        const int job = w + 4 * j;
        const int q = job / 13, tile = job - q * 13;
        const int py = q >> 1, px = q & 1;
        int p = tile * 16 + (lane & 15);
        if (p > 195) p = 195;
        const int ty = p / 14, tx = p % 14;
        f4v a = (f4v){0.f, 0.f, 0.f, 0.f};
        #pragma unroll
        for (int t = 0; t < 4; ++t) {
            const int wy = t >> 1, wx = t & 1;
            h8v bf = *(const h8v*)&pk3h[((size_t)((q * 4 + t) * 16 + oc)) * 32 + kseg];
            h8v af = *(const h8v*)&Pin[((ty + py + wy) * 16 + (tx + px + wx)) * 40 + kseg];
            a = __builtin_amdgcn_mfma_f32_16x16x32_f16(af, bf, a, 0, 0, 0);
        }
        res[j] = a;
    }
    __syncthreads();

    const bool active2 = tid < 196;
    int row = active2 ? tid / 7 : 0;
    int tx0b = active2 ? (tid % 7) * 4 : 0;
    const float bco = bt2[oc];

    float acc2[4][8];
    #pragma unroll
    for (int i = 0; i < 4; ++i)
        #pragma unroll
        for (int o = 0; o < 8; ++o) acc2[i][o] = 0.f;

    #pragma unroll
    for (int g = 0; g < 2; ++g) {
        for (int e = tid; e < 7680; e += 256) P2[e] = 0.f;
        __syncthreads();
        if ((oc >> 3) == g) {
            #pragma unroll
            for (int j = 0; j < 13; ++j) {
                const int job = w + 4 * j;
                const int q = job / 13, tile = job - q * 13;
                const int py = q >> 1, px = q & 1;
                const int pr0 = tile * 16 + (lane >> 4) * 4;
                #pragma unroll
                for (int r = 0; r < 4; ++r) {
                    int p = pr0 + r;
                    if (p < 196) {
                        int Y = 2 * (p / 14) + py, X = 2 * (p % 14) + px;
                        P2[((oc & 7) * 30 + Y + 1) * 32 + (X + 1)] = fmaxf(res[j][r] + bco, 0.f);
                    }
                }
            }
        }
        __syncthreads();
        for (int cl = 0; cl < 8; ++cl) {
            const float* Pb = &P2[(cl * 30 + row) * 32 + tx0b];
            const float* wb = pk4 + (size_t)(g * 8 + cl) * 72;
            #pragma unroll
            for (int ky = 0; ky < 3; ++ky) {
                float4 a = *(const float4*)&Pb[ky * 32];
                float4 bq = *(const float4*)&Pb[ky * 32 + 4];
                float rowb[8] = {a.x, a.y, a.z, a.w, bq.x, bq.y, bq.z, bq.w};
                #pragma unroll
                for (int kx = 0; kx < 3; ++kx) {
                    const float* wt = wb + (ky * 3 + kx) * 8;
                    #pragma unroll
                    for (int o = 0; o < 8; ++o) {
                        float wv2 = wt[o];
                        #pragma unroll
                        for (int i = 0; i < 4; ++i)
                            acc2[i][o] = fmaf(rowb[i + kx], wv2, acc2[i][o]);
                    }
                }
            }
        }
        __syncthreads();
    }

    if (active2) {
        const float bias3 = b3[0];
        #pragma unroll
        for (int i = 0; i < 4; ++i) {
            float r = bias3;
            #pragma unroll
            for (int o = 0; o < 8; ++o) r += fmaxf(acc2[i][o] + b2[o], 0.f) * w3[o];
            out[(size_t)b * 784 + row * 28 + tx0b + i] = r;
        }
    }
}

// ---------------------------------------------------------------------------
extern "C" void kernel_launch(void* const* d_in, const int* in_sizes, int n_in,
                              void* d_out, int out_size, void* d_ws, size_t ws_size,
                              hipStream_t stream)
{
    const float* x       = (const float*)d_in[0];
    const float* patch_w = (const float*)d_in[1];
    const float* patch_b = (const float*)d_in[2];
    const float* ln1g    = (const float*)d_in[3];
    const float* ln1b    = (const float*)d_in[4];
    const float* wi      = (const float*)d_in[5];
    const float* bi      = (const float*)d_in[6];
    const float* wo      = (const float*)d_in[7];
    const float* bo      = (const float*)d_in[8];
    const float* ln2g    = (const float*)d_in[9];
    const float* ln2b    = (const float*)d_in[10];
    const float* w1      = (const float*)d_in[11];
    const float* b1      = (const float*)d_in[12];
    const float* w2      = (const float*)d_in[13];
    const float* b2      = (const float*)d_in[14];
    const float* lat_w   = (const float*)d_in[15];
    const float* lat_b   = (const float*)d_in[16];
    const float* memory  = (const float*)d_in[17];
    const float* dec_w   = (const float*)d_in[18];
    const float* dec_b   = (const float*)d_in[19];
    const float* upt1_w  = (const float*)d_in[20];
    const float* upt1_b  = (const float*)d_in[21];
    const float* c1_w    = (const float*)d_in[22];
    const float* c1_b    = (const float*)d_in[23];
    const float* upt2_w  = (const float*)d_in[24];
    const float* upt2_b  = (const float*)d_in[25];
    const float* c2_w    = (const float*)d_in[26];
    const float* c2_b    = (const float*)d_in[27];
    const float* c3_w    = (const float*)d_in[28];
    const float* c3_b    = (const float*)d_in[29];
    float* outp = (float*)d_out;

    float* ws = (float*)d_ws;
    size_t off = 0;
    auto alloc = [&](size_t n) { float* p = ws + off; off += (n + 63) & ~(size_t)63; return p; };
    float* tokens     = alloc((size_t)B_TOT * 1568);
    float* latent     = alloc((size_t)B_TOT * 256);
    float* dots       = alloc((size_t)B_TOT * 4096);
    float* mem_latent = alloc((size_t)B_TOT * 256);
    float* inv_mn     = alloc(4096);
    half_t* pk2h      = (half_t*)alloc(4608);
    half_t* pk3h      = (half_t*)alloc(4096);
    float* pk4        = alloc(1152);
    float* pk5        = alloc(8192);
    float* Wf         = alloc((size_t)6272 * 256);
    float* bf         = alloc(6272);
    half_t* d1h       = (half_t*)alloc((size_t)CHUNK * 6272 / 2);
    half_t* d2h       = (half_t*)alloc((size_t)CHUNK * 6272 / 2);
    (void)in_sizes; (void)n_in; (void)out_size; (void)ws_size;

    // Weight repack + dec/convt1 algebraic fusion (Wf rows channel-minor)
    k_pack<<<36, 256, 0, stream>>>(c1_w, upt2_w, c2_w, w2, pk2h, pk3h, pk4, pk5);
    k_fuse<<<196, 256, 0, stream>>>(upt1_w, upt1_b, dec_w, dec_b, Wf, bf);

    // Encoder (wave-per-sample, packed fp32 math)
    k_tokens<<<B_TOT / 4, 256, 0, stream>>>(x, patch_w, patch_b, ln1g, ln1b, wi, bi,
                                            wo, bo, ln2g, ln2b, w1, b1, pk5, b2, tokens);
    // latent + dots via split-fp16 MFMA (validated error class, round 14)
    k_sgemm<<<dim3(256 / 128, B_TOT / 64), 256, 0, stream>>>(tokens, lat_w, lat_b, latent,
                                                             B_TOT, 256, 1568);
    k_mnorm<<<4096, 256, 0, stream>>>(memory, inv_mn);
    k_sgemm<<<dim3(4096 / 128, B_TOT / 64), 256, 0, stream>>>(latent, memory, nullptr, dots,
                                                              B_TOT, 4096, 256);
    k_memread<<<B_TOT, 256, 0, stream>>>(latent, dots, inv_mn, memory, mem_latent);

    // Decoder, full batch in one pass.
    for (int c = 0; c < B_TOT / CHUNK; ++c) {
        const float* ml = mem_latent + (size_t)c * CHUNK * 256;
        k_dgemm<<<dim3(6272 / 128, CHUNK / 64), 256, 0, stream>>>(ml, Wf, bf, d1h,
                                                                  CHUNK, 6272, 256);
        k_conv1  <<<CHUNK / 2, 256, 0, stream>>>(d1h, pk2h, c1_b, d2h);
        k_convt23<<<CHUNK, 256, 0, stream>>>(d2h, pk3h, upt2_b, pk4, c2_b, c3_w, c3_b,
                                             outp + (size_t)c * CHUNK * 784);
    }
}

// Round 16
// 1049.576 us; speedup vs baseline: 1.7853x; 1.0146x over previous
//
#include <hip/hip_runtime.h>
#include <math.h>

#define B_TOT 4096
#define CHUNK 4096

typedef _Float16 half_t;
typedef _Float16 h2 __attribute__((ext_vector_type(2)));
typedef _Float16 h8v __attribute__((ext_vector_type(8)));
typedef float f4v __attribute__((ext_vector_type(4)));
typedef float f2v __attribute__((ext_vector_type(2)));

#if __has_builtin(__builtin_amdgcn_fdot2)
#define FDOT2(a, b, c) __builtin_amdgcn_fdot2((a), (b), (c), false)
#else
#define FDOT2(a, b, c) fmaf((float)(a)[1], (float)(b)[1], fmaf((float)(a)[0], (float)(b)[0], (c)))
#endif

// k_tokens: packed-fp32 math (r15); plateaued ~425us, latency-bound at
// 3 blocks/CU (fp32 V is numerics-mandatory — round 4).
// latent+dots: split-fp16 MFMA (validated r14); B matrices PRE-SPLIT once
// (k_split) -> staging is a pure copy; values bit-identical to r15.
// Decoder: fp16-MFMA end to end (validated r10-r12).
#define KSTR 36
#define VSTR 34
#define KBYTES (49 * 72)
#define WAVE_LDS (49 * 72 + 49 * 136)  // 10192
#define WI_OFF  (4 * WAVE_LDS)         // 40768
#define BLOCK_LDS (WI_OFF + 12288)     // 53056

// ---------------------------------------------------------------------------
// Fused: patch conv (1->32, k4 s4) + 2 transformer blocks. Packed-fp32 math.
// ---------------------------------------------------------------------------
__global__ __launch_bounds__(256) void k_tokens(
    const float* __restrict__ x, const float* __restrict__ pw, const float* __restrict__ pb,
    const float* __restrict__ ln1g, const float* __restrict__ ln1b,
    const float* __restrict__ wi, const float* __restrict__ bi,
    const float* __restrict__ wo, const float* __restrict__ bo,
    const float* __restrict__ ln2g, const float* __restrict__ ln2b,
    const float* __restrict__ w1, const float* __restrict__ fb1,
    const float* __restrict__ w2t, const float* __restrict__ fb2,
    float* __restrict__ tokens)
{
    __shared__ __align__(16) unsigned char Lraw[BLOCK_LDS];
    const int tid = threadIdx.x;
    const int wv = tid >> 6, lane = tid & 63;
    const int b = blockIdx.x * 4 + wv;
    half_t* Kb = (half_t*)(Lraw + wv * WAVE_LDS);
    float*  Vb = (float*)(Lraw + wv * WAVE_LDS + KBYTES);
    const float* wiL = (const float*)(Lraw + WI_OFF);
    float* Lf = (float*)Lraw;            // FF-weight overlay (block-wide)
    const bool is_tok = lane < 49;
    const int s = is_tok ? lane : 48;
    const int py = s / 7, px = s % 7;

    // --- prologue: stage blk-0 qkv weights (visible after barrier (A)) ---
    {
        const float4* srcw = (const float4*)(wi);
        float4* dstw = (float4*)(Lraw + WI_OFF);
        for (int e = tid; e < 768; e += 256) dstw[e] = srcw[e];
    }

    // --- patch conv: direct float4 loads; packed accumulate ---
    f2v xv2[8];
    const float* xb = x + (size_t)b * 784 + py * 112 + px * 4;
    #pragma unroll
    for (int r = 0; r < 4; ++r) {
        float4 vq = *(const float4*)(xb + r * 28);
        f2v lo; lo[0] = vq.x; lo[1] = vq.y;
        f2v hi; hi[0] = vq.z; hi[1] = vq.w;
        xv2[2 * r] = lo; xv2[2 * r + 1] = hi;
    }
    f2v t2[16];
    #pragma unroll
    for (int c = 0; c < 32; ++c) {
        const float* wr = pw + c * 16;
        f2v a2 = (f2v){0.f, 0.f};
        #pragma unroll
        for (int c2 = 0; c2 < 4; ++c2) {
            float4 wq = *(const float4*)&wr[4 * c2];
            f2v w0; w0[0] = wq.x; w0[1] = wq.y;
            f2v w1v; w1v[0] = wq.z; w1v[1] = wq.w;
            a2 += xv2[2 * c2] * w0;
            a2 += xv2[2 * c2 + 1] * w1v;
        }
        t2[c >> 1][c & 1] = pb[c] + a2[0] + a2[1];
    }

    for (int blk = 0; blk < 2; ++blk) {
        const float* bib = bi + blk * 96;

        // --- LN1 ---
        f2v mu2 = (f2v){0.f, 0.f};
        #pragma unroll
        for (int i = 0; i < 16; ++i) mu2 += t2[i];
        float mu = (mu2[0] + mu2[1]) * 0.03125f;
        f2v mub; mub[0] = mu; mub[1] = mu;
        f2v var2 = (f2v){0.f, 0.f};
        #pragma unroll
        for (int i = 0; i < 16; ++i) { f2v d = t2[i] - mub; var2 += d * d; }
        float rstd = rsqrtf((var2[0] + var2[1]) * 0.03125f + 1e-5f);
        f2v rstd2; rstd2[0] = rstd; rstd2[1] = rstd;
        f2v xn2[16];
        {
            const f2v* g2 = (const f2v*)(ln1g + blk * 32);
            const f2v* bl2 = (const f2v*)(ln1b + blk * 32);
            #pragma unroll
            for (int i = 0; i < 16; ++i)
                xn2[i] = (t2[i] - mub) * rstd2 * g2[i] + bl2[i];
        }

        __syncthreads();   // (A) prior-phase LDS reads done; wi stage visible

        // --- K projection -> LDS fp16 ---
        #pragma unroll 4
        for (int d = 0; d < 32; ++d) {
            const float* wr = wiL + (32 + d) * 32;
            f2v a2 = (f2v){0.f, 0.f};
            #pragma unroll
            for (int c2 = 0; c2 < 8; ++c2) {
                float4 wq = *(const float4*)&wr[4 * c2];
                f2v w0; w0[0] = wq.x; w0[1] = wq.y;
                f2v w1v; w1v[0] = wq.z; w1v[1] = wq.w;
                a2 += xn2[2 * c2] * w0;
                a2 += xn2[2 * c2 + 1] * w1v;
            }
            if (is_tok) Kb[s * KSTR + d] = (half_t)(bib[32 + d] + a2[0] + a2[1]);
        }
        // --- V projection -> LDS fp32 ---
        #pragma unroll 4
        for (int d = 0; d < 32; ++d) {
            const float* wr = wiL + (64 + d) * 32;
            f2v a2 = (f2v){0.f, 0.f};
            #pragma unroll
            for (int c2 = 0; c2 < 8; ++c2) {
                float4 wq = *(const float4*)&wr[4 * c2];
                f2v w0; w0[0] = wq.x; w0[1] = wq.y;
                f2v w1v; w1v[0] = wq.z; w1v[1] = wq.w;
                a2 += xn2[2 * c2] * w0;
                a2 += xn2[2 * c2 + 1] * w1v;
            }
            if (is_tok) Vb[s * VSTR + d] = bib[64 + d] + a2[0] + a2[1];
        }
        // --- Q projection (scaled) ---
        float q0[32];
        #pragma unroll 4
        for (int d = 0; d < 32; ++d) {
            const float* wr = wiL + d * 32;
            f2v a2 = (f2v){0.f, 0.f};
            #pragma unroll
            for (int c2 = 0; c2 < 8; ++c2) {
                float4 wq = *(const float4*)&wr[4 * c2];
                f2v w0; w0[0] = wq.x; w0[1] = wq.y;
                f2v w1v; w1v[0] = wq.z; w1v[1] = wq.w;
                a2 += xn2[2 * c2] * w0;
                a2 += xn2[2 * c2 + 1] * w1v;
            }
            q0[d] = (bib[d] + a2[0] + a2[1]) * 0.25f;
        }
        h2 qh[16];
        #pragma unroll
        for (int i = 0; i < 16; ++i) {
            h2 hh; hh[0] = (half_t)q0[2 * i]; hh[1] = (half_t)q0[2 * i + 1];
            qh[i] = hh;
        }

        // wave-local fence: own K/V ds_writes visible before broadcast reads
        __asm__ volatile("s_waitcnt lgkmcnt(0)" ::: "memory");

        // --- attention: 2 heads of 16 dims; packed PV ---
        f2v o2[16];
        #pragma unroll
        for (int i = 0; i < 16; ++i) o2[i] = (f2v){0.f, 0.f};
        float l0 = 0.f, l1 = 0.f;
        union H4 { double qd; h2 p[2]; };
        for (int j = 0; j < 49; ++j) {
            const double* kr = (const double*)(Kb + j * KSTR);
            const float* vr = Vb + j * VSTR;
            H4 u0, u1, u2, u3, w0, w1h, w2h, w3;
            u0.qd = kr[0]; u1.qd = kr[1]; u2.qd = kr[2]; u3.qd = kr[3];
            w0.qd = kr[4]; w1h.qd = kr[5]; w2h.qd = kr[6]; w3.qd = kr[7];
            float s0a = 0.f, s0b = 0.f, s1a = 0.f, s1b = 0.f;
            s0a = FDOT2(u0.p[0], qh[0], s0a); s0a = FDOT2(u0.p[1], qh[1], s0a);
            s0b = FDOT2(u1.p[0], qh[2], s0b); s0b = FDOT2(u1.p[1], qh[3], s0b);
            s0a = FDOT2(u2.p[0], qh[4], s0a); s0a = FDOT2(u2.p[1], qh[5], s0a);
            s0b = FDOT2(u3.p[0], qh[6], s0b); s0b = FDOT2(u3.p[1], qh[7], s0b);
            s1a = FDOT2(w0.p[0], qh[8], s1a); s1a = FDOT2(w0.p[1], qh[9], s1a);
            s1b = FDOT2(w1h.p[0], qh[10], s1b); s1b = FDOT2(w1h.p[1], qh[11], s1b);
            s1a = FDOT2(w2h.p[0], qh[12], s1a); s1a = FDOT2(w2h.p[1], qh[13], s1a);
            s1b = FDOT2(w3.p[0], qh[14], s1b); s1b = FDOT2(w3.p[1], qh[15], s1b);
            float p0 = __expf(s0a + s0b), p1 = __expf(s1a + s1b);
            l0 += p0; l1 += p1;
            f2v p02; p02[0] = p0; p02[1] = p0;
            f2v p12; p12[0] = p1; p12[1] = p1;
            #pragma unroll
            for (int i = 0; i < 8; ++i) {
                f2v va = *(const f2v*)&vr[2 * i];
                o2[i] += p02 * va;
                f2v vc = *(const f2v*)&vr[16 + 2 * i];
                o2[8 + i] += p12 * vc;
            }
        }
        {
            float il0 = 1.f / l0, il1 = 1.f / l1;
            f2v il02; il02[0] = il0; il02[1] = il0;
            f2v il12; il12[0] = il1; il12[1] = il1;
            #pragma unroll
            for (int i = 0; i < 8; ++i) { o2[i] *= il02; o2[8 + i] *= il12; }
        }

        // --- out projection + residual ---
        #pragma unroll
        for (int c = 0; c < 32; ++c) {
            const float* wr = wo + blk * 1024 + c * 32;
            f2v a2 = (f2v){0.f, 0.f};
            #pragma unroll
            for (int c2 = 0; c2 < 8; ++c2) {
                float4 wq = *(const float4*)&wr[4 * c2];
                f2v w0; w0[0] = wq.x; w0[1] = wq.y;
                f2v w1v; w1v[0] = wq.z; w1v[1] = wq.w;
                a2 += o2[2 * c2] * w0;
                a2 += o2[2 * c2 + 1] * w1v;
            }
            t2[c >> 1][c & 1] += bo[blk * 32 + c] + a2[0] + a2[1];
        }

        // --- LN2 ---
        mu2 = (f2v){0.f, 0.f};
        #pragma unroll
        for (int i = 0; i < 16; ++i) mu2 += t2[i];
        mu = (mu2[0] + mu2[1]) * 0.03125f;
        mub[0] = mu; mub[1] = mu;
        var2 = (f2v){0.f, 0.f};
        #pragma unroll
        for (int i = 0; i < 16; ++i) { f2v d = t2[i] - mub; var2 += d * d; }
        rstd = rsqrtf((var2[0] + var2[1]) * 0.03125f + 1e-5f);
        rstd2[0] = rstd; rstd2[1] = rstd;
        {
            const f2v* g2 = (const f2v*)(ln2g + blk * 32);
            const f2v* bl2 = (const f2v*)(ln2b + blk * 32);
            #pragma unroll
            for (int i = 0; i < 16; ++i)
                xn2[i] = (t2[i] - mub) * rstd2 * g2[i] + bl2[i];
        }

        __syncthreads();   // (C) all waves done reading K/V + wi

        // --- stage FF weights (overlay over KV) + next blk's wi ---
        {
            const float4* src1 = (const float4*)(w1 + blk * 4096);
            const float4* src2 = (const float4*)(w2t + blk * 4096);
            float4* dst = (float4*)Lraw;
            for (int e = tid; e < 1024; e += 256) dst[e] = src1[e];
            for (int e = tid; e < 1024; e += 256) dst[1024 + e] = src2[e];
            if (blk == 0) {
                const float4* srcw = (const float4*)(wi + 3072);
                float4* dstw = (float4*)(Lraw + WI_OFF);
                for (int e = tid; e < 768; e += 256) dstw[e] = srcw[e];
            }
        }
        __syncthreads();   // (D) FF weights (and wi for blk1) visible

        // --- FF from LDS: packed dot + packed axpy ---
        const float* w2L = Lf + 4096;
        #pragma unroll 2
        for (int j = 0; j < 128; ++j) {
            const float* wr = Lf + j * 32;
            f2v h2a = (f2v){0.f, 0.f};
            #pragma unroll
            for (int c2 = 0; c2 < 8; ++c2) {
                float4 wq = *(const float4*)&wr[4 * c2];
                f2v w0; w0[0] = wq.x; w0[1] = wq.y;
                f2v w1v; w1v[0] = wq.z; w1v[1] = wq.w;
                h2a += xn2[2 * c2] * w0;
                h2a += xn2[2 * c2 + 1] * w1v;
            }
            float h = fb1[blk * 128 + j] + h2a[0] + h2a[1];
            h = 0.5f * h * (1.f + erff(h * 0.7071067811865476f));
            f2v hh; hh[0] = h; hh[1] = h;
            const float* w2r = w2L + j * 32;
            #pragma unroll
            for (int c2 = 0; c2 < 8; ++c2) {
                float4 wq = *(const float4*)&w2r[4 * c2];
                f2v w0; w0[0] = wq.x; w0[1] = wq.y;
                f2v w1v; w1v[0] = wq.z; w1v[1] = wq.w;
                t2[2 * c2]     += hh * w0;
                t2[2 * c2 + 1] += hh * w1v;
            }
        }
        {
            const f2v* fb22 = (const f2v*)(fb2 + blk * 32);
            #pragma unroll
            for (int i = 0; i < 16; ++i) t2[i] += fb22[i];
        }
    }

    if (is_tok) {
        float* op = tokens + (size_t)b * 1568 + s * 32;
        #pragma unroll
        for (int i = 0; i < 8; ++i) {
            float4 vv = make_float4(t2[2 * i][0], t2[2 * i][1],
                                    t2[2 * i + 1][0], t2[2 * i + 1][1]);
            *(float4*)&op[4 * i] = vv;
        }
    }
}

// ---------------------------------------------------------------------------
// Pre-split lat_w and memory into fp16 hi/lo pairs (hi=fp16(x),
// lo=fp16((x-hi)*2048)). Deterministic conversion -> values bit-identical to
// the previous inline split.
// ---------------------------------------------------------------------------
__global__ __launch_bounds__(256) void k_split(
    const float* __restrict__ lat_w, const float* __restrict__ memory,
    half_t* __restrict__ lwh, half_t* __restrict__ lwl,
    half_t* __restrict__ memh, half_t* __restrict__ meml)
{
    size_t i = (size_t)blockIdx.x * 256 + threadIdx.x;
    if (i < 401408) {   // 256*1568
        float v = lat_w[i];
        half_t h = (half_t)v;
        lwh[i] = h; lwl[i] = (half_t)((v - (float)h) * 2048.0f);
    }
    if (i < 1048576) {  // 4096*256
        float v = memory[i];
        half_t h = (half_t)v;
        memh[i] = h; meml[i] = (half_t)((v - (float)h) * 2048.0f);
    }
}

// ---------------------------------------------------------------------------
// SPLIT-fp16 MFMA GEMM with PRE-SPLIT B: C = A @ B^T (+bias), fp32 out.
// A split at stage time; B loaded directly from hi/lo half arrays.
// dot = Σhi·hi + (Σhi·lo + Σlo·hi)/2048, fp32 accum (validated r14).
// ---------------------------------------------------------------------------
__global__ __launch_bounds__(256) void k_sgemm(
    const float* __restrict__ A, const half_t* __restrict__ Bhg,
    const half_t* __restrict__ Blg, const float* __restrict__ bias,
    float* __restrict__ C, int M, int N, int K)
{
    __shared__ __align__(16) half_t Ah[64 * 40];
    __shared__ __align__(16) half_t Al[64 * 40];
    __shared__ __align__(16) half_t Bh[128 * 40];
    __shared__ __align__(16) half_t Bl[128 * 40];
    const int tid = threadIdx.x;
    const int n0 = blockIdx.x * 128, m0 = blockIdx.y * 64;
    const int w = tid >> 6, lane = tid & 63;
    const int wm = (w >> 1) * 32, wn = (w & 1) * 64;
    const int lr = lane & 15, lk = lane >> 4;

    const int ar = tid >> 2, aseg = (tid & 3) * 8;
    const int br = tid >> 1, bseg = (tid & 1) * 16;

    f4v acch[2][4], accm[2][4];
    #pragma unroll
    for (int i = 0; i < 2; ++i)
        #pragma unroll
        for (int j = 0; j < 4; ++j) {
            acch[i][j] = (f4v){0.f, 0.f, 0.f, 0.f};
            accm[i][j] = (f4v){0.f, 0.f, 0.f, 0.f};
        }

    for (int k0 = 0; k0 < K; k0 += 32) {
        {
            const float* ap = A + (size_t)(m0 + ar) * K + k0 + aseg;
            float4 a0 = *(const float4*)ap;
            float4 a1 = *(const float4*)(ap + 4);
            float av[8] = {a0.x, a0.y, a0.z, a0.w, a1.x, a1.y, a1.z, a1.w};
            h8v ah, al;
            #pragma unroll
            for (int i = 0; i < 8; ++i) {
                half_t h = (half_t)av[i];
                ah[i] = h;
                al[i] = (half_t)((av[i] - (float)h) * 2048.0f);
            }
            *(h8v*)&Ah[ar * 40 + aseg] = ah;
            *(h8v*)&Al[ar * 40 + aseg] = al;

            const half_t* bph = Bhg + (size_t)(n0 + br) * K + k0 + bseg;
            const half_t* bpl = Blg + (size_t)(n0 + br) * K + k0 + bseg;
            h8v bh0 = *(const h8v*)bph;
            h8v bh1 = *(const h8v*)(bph + 8);
            h8v bl0 = *(const h8v*)bpl;
            h8v bl1 = *(const h8v*)(bpl + 8);
            *(h8v*)&Bh[br * 40 + bseg]     = bh0;
            *(h8v*)&Bh[br * 40 + bseg + 8] = bh1;
            *(h8v*)&Bl[br * 40 + bseg]     = bl0;
            *(h8v*)&Bl[br * 40 + bseg + 8] = bl1;
        }
        __syncthreads();
        h8v afh[2], afl[2], bfh[4], bfl[4];
        #pragma unroll
        for (int i = 0; i < 2; ++i) {
            afh[i] = *(const h8v*)&Ah[(wm + i * 16 + lr) * 40 + lk * 8];
            afl[i] = *(const h8v*)&Al[(wm + i * 16 + lr) * 40 + lk * 8];
        }
        #pragma unroll
        for (int j = 0; j < 4; ++j) {
            bfh[j] = *(const h8v*)&Bh[(wn + j * 16 + lr) * 40 + lk * 8];
            bfl[j] = *(const h8v*)&Bl[(wn + j * 16 + lr) * 40 + lk * 8];
        }
        #pragma unroll
        for (int i = 0; i < 2; ++i)
            #pragma unroll
            for (int j = 0; j < 4; ++j) {
                acch[i][j] = __builtin_amdgcn_mfma_f32_16x16x32_f16(afh[i], bfh[j], acch[i][j], 0, 0, 0);
                accm[i][j] = __builtin_amdgcn_mfma_f32_16x16x32_f16(afh[i], bfl[j], accm[i][j], 0, 0, 0);
                accm[i][j] = __builtin_amdgcn_mfma_f32_16x16x32_f16(afl[i], bfh[j], accm[i][j], 0, 0, 0);
            }
        __syncthreads();
    }

    #pragma unroll
    for (int j = 0; j < 4; ++j) {
        int n = n0 + wn + j * 16 + lr;
        float bv = bias ? bias[n] : 0.f;
        #pragma unroll
        for (int i = 0; i < 2; ++i) {
            #pragma unroll
            for (int r = 0; r < 4; ++r) {
                int m = m0 + wm + i * 16 + lk * 4 + r;
                C[(size_t)m * N + n] = acch[i][j][r] + accm[i][j][r] * (1.0f / 2048.0f) + bv;
            }
        }
    }
}

// ---------------------------------------------------------------------------
// MFMA decoder GEMM: d1h[M,N] = (fp16)relu(A[M,K] @ B[N,K]^T + bias).
// ---------------------------------------------------------------------------
__global__ __launch_bounds__(256) void k_dgemm(
    const float* __restrict__ A, const float* __restrict__ Bm,
    const float* __restrict__ bias, half_t* __restrict__ C,
    int M, int N, int K)
{
    __shared__ __align__(16) half_t As[64 * 40];
    __shared__ __align__(16) half_t Bs[128 * 40];
    const int tid = threadIdx.x;
    const int n0 = blockIdx.x * 128, m0 = blockIdx.y * 64;
    const int w = tid >> 6, lane = tid & 63;
    const int wm = (w >> 1) * 32, wn = (w & 1) * 64;
    const int lr = lane & 15, lk = lane >> 4;

    const int ar = tid >> 2, aseg = (tid & 3) * 8;
    const int br = tid >> 1, bseg = (tid & 1) * 16;

    f4v acc[2][4];
    #pragma unroll
    for (int i = 0; i < 2; ++i)
        #pragma unroll
        for (int j = 0; j < 4; ++j) acc[i][j] = (f4v){0.f, 0.f, 0.f, 0.f};

    for (int k0 = 0; k0 < K; k0 += 32) {
        {
            const float* ap = A + (size_t)(m0 + ar) * K + k0 + aseg;
            float4 a0 = *(const float4*)ap;
            float4 a1 = *(const float4*)(ap + 4);
            h8v ha;
            ha[0] = (half_t)a0.x; ha[1] = (half_t)a0.y;
            ha[2] = (half_t)a0.z; ha[3] = (half_t)a0.w;
            ha[4] = (half_t)a1.x; ha[5] = (half_t)a1.y;
            ha[6] = (half_t)a1.z; ha[7] = (half_t)a1.w;
            *(h8v*)&As[ar * 40 + aseg] = ha;

            const float* bp = Bm + (size_t)(n0 + br) * K + k0 + bseg;
            float4 b0 = *(const float4*)bp;
            float4 b1 = *(const float4*)(bp + 4);
            float4 b2 = *(const float4*)(bp + 8);
            float4 b3 = *(const float4*)(bp + 12);
            h8v hb0, hb1;
            hb0[0] = (half_t)b0.x; hb0[1] = (half_t)b0.y;
            hb0[2] = (half_t)b0.z; hb0[3] = (half_t)b0.w;
            hb0[4] = (half_t)b1.x; hb0[5] = (half_t)b1.y;
            hb0[6] = (half_t)b1.z; hb0[7] = (half_t)b1.w;
            hb1[0] = (half_t)b2.x; hb1[1] = (half_t)b2.y;
            hb1[2] = (half_t)b2.z; hb1[3] = (half_t)b2.w;
            hb1[4] = (half_t)b3.x; hb1[5] = (half_t)b3.y;
            hb1[6] = (half_t)b3.z; hb1[7] = (half_t)b3.w;
            *(h8v*)&Bs[br * 40 + bseg] = hb0;
            *(h8v*)&Bs[br * 40 + bseg + 8] = hb1;
        }
        __syncthreads();
        h8v af[2], bfr[4];
        #pragma unroll
        for (int i = 0; i < 2; ++i)
            af[i] = *(const h8v*)&As[(wm + i * 16 + lr) * 40 + lk * 8];
        #pragma unroll
        for (int j = 0; j < 4; ++j)
            bfr[j] = *(const h8v*)&Bs[(wn + j * 16 + lr) * 40 + lk * 8];
        #pragma unroll
        for (int i = 0; i < 2; ++i)
            #pragma unroll
            for (int j = 0; j < 4; ++j)
                acc[i][j] = __builtin_amdgcn_mfma_f32_16x16x32_f16(af[i], bfr[j], acc[i][j], 0, 0, 0);
        __syncthreads();
    }

    #pragma unroll
    for (int j = 0; j < 4; ++j) {
        int n = n0 + wn + j * 16 + lr;
        float bv = bias[n];
        #pragma unroll
        for (int i = 0; i < 2; ++i) {
            #pragma unroll
            for (int r = 0; r < 4; ++r) {
                int m = m0 + wm + i * 16 + lk * 4 + r;
                C[(size_t)m * N + n] = (half_t)fmaxf(acc[i][j][r] + bv, 0.f);
            }
        }
    }
}

// ---------------------------------------------------------------------------
// Fuse dec (linear 256->3136) with convt1. Packed f2v accumulators
// (per-element chains unchanged -> bit-identical Wf/bf).
// ---------------------------------------------------------------------------
__global__ __launch_bounds__(256) void k_fuse(
    const float* __restrict__ wt1, const float* __restrict__ upt1_b,
    const float* __restrict__ dec_w, const float* __restrict__ dec_b,
    float* __restrict__ Wf, float* __restrict__ bf)
{
    __shared__ float WL[4][64][32];
    const int p = blockIdx.x;
    const int k = threadIdx.x;
    const int y = p / 14, x = p % 14;

    int ky0 = 0, iy0 = 0, ky1 = 0, iy1 = 0, nky = 0;
    for (int ky = 0; ky < 4; ++ky) {
        int iyn = y + 1 - ky;
        if (iyn < 0 || (iyn & 1)) continue;
        int iy = iyn >> 1;
        if (iy > 6) continue;
        if (nky == 0) { ky0 = ky; iy0 = iy; } else { ky1 = ky; iy1 = iy; }
        ++nky;
    }
    int kx0 = 0, ix0 = 0, kx1 = 0, ix1 = 0, nkx = 0;
    for (int kx = 0; kx < 4; ++kx) {
        int ixn = x + 1 - kx;
        if (ixn < 0 || (ixn & 1)) continue;
        int ix = ixn >> 1;
        if (ix > 6) continue;
        if (nkx == 0) { kx0 = kx; ix0 = ix; } else { kx1 = kx; ix1 = ix; }
        ++nkx;
    }
    const int ntap = nky * nkx;

    for (int e = k; e < ntap * 2048; e += 256) {
        int t = e >> 11, c = (e >> 5) & 63, o = e & 31;
        int ti = (nkx == 2) ? (t >> 1) : t;
        int tj = (nkx == 2) ? (t & 1) : 0;
        int ky = ti ? ky1 : ky0;
        int kx = tj ? kx1 : kx0;
        WL[t][c][o] = wt1[((c * 32 + o) * 4 + ky) * 4 + kx];
    }
    __syncthreads();

    f2v acc2[16];
    #pragma unroll
    for (int o = 0; o < 16; ++o) acc2[o] = (f2v){0.f, 0.f};
    float bacc = 0.f;

    for (int t = 0; t < ntap; ++t) {
        int ti = (nkx == 2) ? (t >> 1) : t;
        int tj = (nkx == 2) ? (t & 1) : 0;
        int iy = ti ? iy1 : iy0;
        int ix = tj ? ix1 : ix0;
        int rbase = iy * 7 + ix;
        for (int c = 0; c < 64; ++c) {
            int row = c * 49 + rbase;
            float v = dec_w[(size_t)row * 256 + k];
            f2v vv; vv[0] = v; vv[1] = v;
            const f2v* w2p = (const f2v*)&WL[t][c][0];
            #pragma unroll
            for (int o2 = 0; o2 < 16; ++o2) acc2[o2] += vv * w2p[o2];
            if (k < 32) bacc = fmaf(WL[t][c][k], dec_b[row], bacc);
        }
    }

    #pragma unroll 4
    for (int o = 0; o < 32; ++o)
        Wf[((size_t)(p * 32 + o)) * 256 + k] = acc2[o >> 1][o & 1];
    if (k < 32) bf[p * 32 + k] = bacc + upt1_b[k];
}

// ---------------------------------------------------------------------------
__global__ __launch_bounds__(256) void k_mnorm(const float* __restrict__ mem, float* __restrict__ inv_norm)
{
    __shared__ float red[256];
    const int row = blockIdx.x, tid = threadIdx.x;
    float v = mem[(size_t)row * 256 + tid];
    red[tid] = v * v;
    __syncthreads();
    for (int s = 128; s > 0; s >>= 1) {
        if (tid < s) red[tid] += red[tid + s];
        __syncthreads();
    }
    if (tid == 0) inv_norm[row] = 1.f / fmaxf(sqrtf(red[0]), 1e-12f);
}

// ---------------------------------------------------------------------------
// Top-k via wave __shfl_xor lexicographic (v,idx) reduce (exactly associative).
// ---------------------------------------------------------------------------
__global__ __launch_bounds__(256) void k_memread(
    const float* __restrict__ latent, const float* __restrict__ dots,
    const float* __restrict__ inv_mn, const float* __restrict__ mem,
    float* __restrict__ out)
{
    __shared__ float red[256];
    __shared__ int   redi[4];
    __shared__ float inv_x_s;
    const int b = blockIdx.x, tid = threadIdx.x;
    const int w = tid >> 6, lane = tid & 63;
    float lx = latent[(size_t)b * 256 + tid];
    red[tid] = lx * lx;
    __syncthreads();
    for (int s = 128; s > 0; s >>= 1) {
        if (tid < s) red[tid] += red[tid + s];
        __syncthreads();
    }
    if (tid == 0) inv_x_s = 1.f / fmaxf(sqrtf(red[0]), 1e-12f);
    __syncthreads();
    const float inv_x = inv_x_s;

    float vals[16];
    for (int j = 0; j < 16; ++j) {
        int m = tid + j * 256;
        vals[j] = dots[(size_t)b * 4096 + m] * inv_mn[m] * inv_x;
    }
    float tv[10]; int ti[10];
    for (int t = 0; t < 10; ++t) {
        float bv = -1e30f; int bidx = 0x7fffffff;
        #pragma unroll
        for (int j = 0; j < 16; ++j) {
            int m = tid + j * 256;
            float v = vals[j];
            if (v > bv || (v == bv && m < bidx)) { bv = v; bidx = m; }
        }
        #pragma unroll
        for (int off = 32; off > 0; off >>= 1) {
            float ov = __shfl_xor(bv, off);
            int   oi = __shfl_xor(bidx, off);
            if (ov > bv || (ov == bv && oi < bidx)) { bv = ov; bidx = oi; }
        }
        if (lane == 0) { red[w] = bv; redi[w] = bidx; }
        __syncthreads();
        float fv = red[0]; int fi = redi[0];
        #pragma unroll
        for (int q = 1; q < 4; ++q) {
            float v2 = red[q]; int i2 = redi[q];
            if (v2 > fv || (v2 == fv && i2 < fi)) { fv = v2; fi = i2; }
        }
        tv[t] = fv; ti[t] = fi;
        if ((fi & 255) == tid) vals[fi >> 8] = -1e30f;
        __syncthreads();
    }
    float wgt[10], wsum = 0.f;
    for (int t = 0; t < 10; ++t) { wgt[t] = expf(tv[t] - tv[0]); wsum += wgt[t]; }
    float inv_ws = 1.f / wsum;
    float acc = 0.f;
    for (int t = 0; t < 10; ++t) acc += (wgt[t] * inv_ws) * mem[(size_t)ti[t] * 256 + tid];
    out[(size_t)b * 256 + tid] = acc;
}

// ---------------------------------------------------------------------------
// Weight repack.
// ---------------------------------------------------------------------------
__global__ __launch_bounds__(256) void k_pack(
    const float* __restrict__ wc1, const float* __restrict__ wt2,
    const float* __restrict__ wc2, const float* __restrict__ w2src,
    half_t* __restrict__ pk2h, half_t* __restrict__ pk3h,
    float* __restrict__ pk4, float* __restrict__ pk5)
{
    int i = blockIdx.x * 256 + threadIdx.x;
    if (i < 9216) {
        int ic = i & 31, oc = (i >> 5) & 15, nt = (i >> 9) & 1, t = i >> 10;
        pk2h[i] = (half_t)wc1[((nt * 16 + oc) * 32 + ic) * 9 + t];
    }
    if (i < 8192) {
        int ic = i & 31, oc = (i >> 5) & 15, t = (i >> 9) & 3, q = i >> 11;
        int wy = t >> 1, wx = t & 1, py = q >> 1, px = q & 1;
        int ky = 3 - py - 2 * wy, kx = 3 - px - 2 * wx;
        pk3h[i] = (half_t)wt2[((ic * 16 + oc) * 4 + ky) * 4 + kx];
    }
    if (i < 1152) {
        int o = i & 7, tap = (i >> 3) % 9, c = i / 72;
        pk4[i] = wc2[(o * 16 + c) * 9 + tap];
    }
    if (i < 8192) {
        int c = i & 31, j = (i >> 5) & 127, bq = i >> 12;
        pk5[i] = w2src[bq * 4096 + c * 128 + j];
    }
}

// ---------------------------------------------------------------------------
// Conv2d 32->32 k3 p1, 14x14, ReLU — MFMA. 2 samples/block.
// ---------------------------------------------------------------------------
__global__ __launch_bounds__(256) void k_conv1(
    const half_t* __restrict__ in, const half_t* __restrict__ wh,
    const float* __restrict__ bias, half_t* __restrict__ out)
{
    __shared__ __align__(16) half_t P[2 * 16 * 16 * 40];
    const int tid = threadIdx.x;
    const int w = tid >> 6, lane = tid & 63;
    const size_t b0 = (size_t)blockIdx.x * 2;

    for (int e = tid; e < 10240; e += 256) ((unsigned int*)P)[e] = 0u;
    __syncthreads();
    {
        const unsigned int* src = (const unsigned int*)in;
        for (int e = tid; e < 6272; e += 256) {
            int si = e / 3136;
            int rem = e - si * 3136;
            int p = rem >> 4, c2 = rem & 15;
            int y = p / 14, x = p % 14;
            ((unsigned int*)P)[si * 5120 + ((y + 1) * 16 + (x + 1)) * 20 + c2] =
                src[(b0 + si) * 3136 + rem];
        }
    }

    h8v bfr[9][2];
    #pragma unroll
    for (int t = 0; t < 9; ++t)
        #pragma unroll
        for (int nt = 0; nt < 2; ++nt)
            bfr[t][nt] = *(const h8v*)&wh[((size_t)((t * 2 + nt) * 16 + (lane & 15))) * 32 + (lane >> 4) * 8];

    __syncthreads();

    const int kseg = (lane >> 4) * 8;
    const int oc = lane & 15;
    const float bv0 = bias[oc], bv1 = bias[16 + oc];

    for (int job = w; job < 26; job += 4) {
        const int si = job >= 13 ? 1 : 0;
        const int tile = job - si * 13;
        int p = tile * 16 + (lane & 15);
        if (p > 195) p = 195;
        const int y = p / 14, x = p % 14;
        const half_t* Pb = P + si * 10240;

        f4v acc0 = (f4v){0.f, 0.f, 0.f, 0.f};
        f4v acc1 = (f4v){0.f, 0.f, 0.f, 0.f};
        #pragma unroll
        for (int ky = 0; ky < 3; ++ky) {
            #pragma unroll
            for (int kx = 0; kx < 3; ++kx) {
                h8v af = *(const h8v*)&Pb[((y + ky) * 16 + (x + kx)) * 40 + kseg];
                acc0 = __builtin_amdgcn_mfma_f32_16x16x32_f16(af, bfr[ky * 3 + kx][0], acc0, 0, 0, 0);
                acc1 = __builtin_amdgcn_mfma_f32_16x16x32_f16(af, bfr[ky * 3 + kx][1], acc1, 0, 0, 0);
            }
        }

        const int pr0 = tile * 16 + (lane >> 4) * 4;
        half_t* ob = out + (b0 + si) * 6272;
        #pragma unroll
        for (int r = 0; r < 4; ++r) {
            int pp = pr0 + r;
            if (pp < 196) {
                ob[(size_t)pp * 32 + oc]      = (half_t)fmaxf(acc0[r] + bv0, 0.f);
                ob[(size_t)pp * 32 + 16 + oc] = (half_t)fmaxf(acc1[r] + bv1, 0.f);
            }
        }
    }
}

// ---------------------------------------------------------------------------
// FUSED: ConvTranspose2d 32->16 k4 s2 p1 (MFMA) + Conv2d 16->8 k3 p1 (ReLU,
// packed f2v) + Conv2d 8->1 k1. One sample/block.
// ---------------------------------------------------------------------------
__global__ __launch_bounds__(256) void k_convt23(
    const half_t* __restrict__ in, const half_t* __restrict__ pk3h,
    const float* __restrict__ bt2, const float* __restrict__ pk4,
    const float* __restrict__ b2, const float* __restrict__ w3,
    const float* __restrict__ b3, float* __restrict__ out)
{
    __shared__ __align__(16) unsigned char Lraw[30720];
    half_t* Pin = (half_t*)Lraw;
    float*  P2  = (float*)Lraw;
    const int tid = threadIdx.x;
    const int w = tid >> 6, lane = tid & 63;
    const int b = blockIdx.x;

    for (int e = tid; e < 5120; e += 256) ((unsigned int*)Pin)[e] = 0u;
    __syncthreads();
    {
        const unsigned int* src = (const unsigned int*)in;
        for (int e = tid; e < 3136; e += 256) {
            int p = e >> 4, c2 = e & 15;
            int y = p / 14, x = p % 14;
            ((unsigned int*)Pin)[((y + 1) * 16 + (x + 1)) * 20 + c2] =
                src[(size_t)b * 3136 + e];
        }
    }
    __syncthreads();

    const int oc = lane & 15;
    const int kseg = (lane >> 4) * 8;

    f4v res[13];
    #pragma unroll
    for (int j = 0; j < 13; ++j) {
        const int job = w + 4 * j;
        const int q = job / 13, tile = job - q * 13;
        const int py = q >> 1, px = q & 1;
        int p = tile * 16 + (lane & 15);
        if (p > 195) p = 195;
        const int ty = p / 14, tx = p % 14;
        f4v a = (f4v){0.f, 0.f, 0.f, 0.f};
        #pragma unroll
        for (int t = 0; t < 4; ++t) {
            const int wy = t >> 1, wx = t & 1;
            h8v bf = *(const h8v*)&pk3h[((size_t)((q * 4 + t) * 16 + oc)) * 32 + kseg];
            h8v af = *(const h8v*)&Pin[((ty + py + wy) * 16 + (tx + px + wx)) * 40 + kseg];
            a = __builtin_amdgcn_mfma_f32_16x16x32_f16(af, bf, a, 0, 0, 0);
        }
        res[j] = a;
    }
    __syncthreads();

    const bool active2 = tid < 196;
    int row = active2 ? tid / 7 : 0;
    int tx0b = active2 ? (tid % 7) * 4 : 0;
    const float bco = bt2[oc];

    f2v acc2[4][4];
    #pragma unroll
    for (int i = 0; i < 4; ++i)
        #pragma unroll
        for (int o2 = 0; o2 < 4; ++o2) acc2[i][o2] = (f2v){0.f, 0.f};

    #pragma unroll
    for (int g = 0; g < 2; ++g) {
        for (int e = tid; e < 7680; e += 256) P2[e] = 0.f;
        __syncthreads();
        if ((oc >> 3) == g) {
            #pragma unroll
            for (int j = 0; j < 13; ++j) {
                const int job = w + 4 * j;
                const int q = job / 13, tile = job - q * 13;
                const int py = q >> 1, px = q & 1;
                const int pr0 = tile * 16 + (lane >> 4) * 4;
                #pragma unroll
                for (int r = 0; r < 4; ++r) {
                    int p = pr0 + r;
                    if (p < 196) {
                        int Y = 2 * (p / 14) + py, X = 2 * (p % 14) + px;
                        P2[((oc & 7) * 30 + Y + 1) * 32 + (X + 1)] = fmaxf(res[j][r] + bco, 0.f);
                    }
                }
            }
        }
        __syncthreads();
        for (int cl = 0; cl < 8; ++cl) {
            const float* Pb = &P2[(cl * 30 + row) * 32 + tx0b];
            const float* wb = pk4 + (size_t)(g * 8 + cl) * 72;
            #pragma unroll
            for (int ky = 0; ky < 3; ++ky) {
                float4 a = *(const float4*)&Pb[ky * 32];
                float4 bq = *(const float4*)&Pb[ky * 32 + 4];
                float rowb[8] = {a.x, a.y, a.z, a.w, bq.x, bq.y, bq.z, bq.w};
                #pragma unroll
                for (int kx = 0; kx < 3; ++kx) {
                    const f2v* wt2p = (const f2v*)(wb + (ky * 3 + kx) * 8);
                    #pragma unroll
                    for (int i = 0; i < 4; ++i) {
                        f2v rb; rb[0] = rowb[i + kx]; rb[1] = rowb[i + kx];
                        acc2[i][0] += rb * wt2p[0];
                        acc2[i][1] += rb * wt2p[1];
                        acc2[i][2] += rb * wt2p[2];
                        acc2[i][3] += rb * wt2p[3];
                    }
                }
            }
        }
        __syncthreads();
    }

    if (active2) {
        const float bias3 = b3[0];
        #pragma unroll
        for (int i = 0; i < 4; ++i) {
            float r = bias3;
            #pragma unroll
            for (int o = 0; o < 8; ++o)
                r += fmaxf(acc2[i][o >> 1][o & 1] + b2[o], 0.f) * w3[o];
            out[(size_t)b * 784 + row * 28 + tx0b + i] = r;
        }
    }
}

// ---------------------------------------------------------------------------
extern "C" void kernel_launch(void* const* d_in, const int* in_sizes, int n_in,
                              void* d_out, int out_size, void* d_ws, size_t ws_size,
                              hipStream_t stream)
{
    const float* x       = (const float*)d_in[0];
    const float* patch_w = (const float*)d_in[1];
    const float* patch_b = (const float*)d_in[2];
    const float* ln1g    = (const float*)d_in[3];
    const float* ln1b    = (const float*)d_in[4];
    const float* wi      = (const float*)d_in[5];
    const float* bi      = (const float*)d_in[6];
    const float* wo      = (const float*)d_in[7];
    const float* bo      = (const float*)d_in[8];
    const float* ln2g    = (const float*)d_in[9];
    const float* ln2b    = (const float*)d_in[10];
    const float* w1      = (const float*)d_in[11];
    const float* b1      = (const float*)d_in[12];
    const float* w2      = (const float*)d_in[13];
    const float* b2      = (const float*)d_in[14];
    const float* lat_w   = (const float*)d_in[15];
    const float* lat_b   = (const float*)d_in[16];
    const float* memory  = (const float*)d_in[17];
    const float* dec_w   = (const float*)d_in[18];
    const float* dec_b   = (const float*)d_in[19];
    const float* upt1_w  = (const float*)d_in[20];
    const float* upt1_b  = (const float*)d_in[21];
    const float* c1_w    = (const float*)d_in[22];
    const float* c1_b    = (const float*)d_in[23];
    const float* upt2_w  = (const float*)d_in[24];
    const float* upt2_b  = (const float*)d_in[25];
    const float* c2_w    = (const float*)d_in[26];
    const float* c2_b    = (const float*)d_in[27];
    const float* c3_w    = (const float*)d_in[28];
    const float* c3_b    = (const float*)d_in[29];
    float* outp = (float*)d_out;

    float* ws = (float*)d_ws;
    size_t off = 0;
    auto alloc = [&](size_t n) { float* p = ws + off; off += (n + 63) & ~(size_t)63; return p; };
    float* tokens     = alloc((size_t)B_TOT * 1568);
    float* latent     = alloc((size_t)B_TOT * 256);
    float* dots       = alloc((size_t)B_TOT * 4096);
    float* mem_latent = alloc((size_t)B_TOT * 256);
    float* inv_mn     = alloc(4096);
    half_t* pk2h      = (half_t*)alloc(4608);
    half_t* pk3h      = (half_t*)alloc(4096);
    float* pk4        = alloc(1152);
    float* pk5        = alloc(8192);
    float* Wf         = alloc((size_t)6272 * 256);
    float* bf         = alloc(6272);
    half_t* d1h       = (half_t*)alloc((size_t)CHUNK * 6272 / 2);
    half_t* d2h       = (half_t*)alloc((size_t)CHUNK * 6272 / 2);
    half_t* lwh       = (half_t*)alloc(200704);   // 256*1568 halves
    half_t* lwl       = (half_t*)alloc(200704);
    half_t* memh      = (half_t*)alloc(524288);   // 4096*256 halves
    half_t* meml      = (half_t*)alloc(524288);
    (void)in_sizes; (void)n_in; (void)out_size; (void)ws_size;

    // Prep: repack, pre-split GEMM B operands, dec/convt1 fusion
    k_pack<<<36, 256, 0, stream>>>(c1_w, upt2_w, c2_w, w2, pk2h, pk3h, pk4, pk5);
    k_split<<<4096, 256, 0, stream>>>(lat_w, memory, lwh, lwl, memh, meml);
    k_fuse<<<196, 256, 0, stream>>>(upt1_w, upt1_b, dec_w, dec_b, Wf, bf);

    // Encoder (wave-per-sample, packed fp32 math)
    k_tokens<<<B_TOT / 4, 256, 0, stream>>>(x, patch_w, patch_b, ln1g, ln1b, wi, bi,
                                            wo, bo, ln2g, ln2b, w1, b1, pk5, b2, tokens);
    // latent + dots via split-fp16 MFMA with pre-split B
    k_sgemm<<<dim3(256 / 128, B_TOT / 64), 256, 0, stream>>>(tokens, lwh, lwl, lat_b,
                                                             latent, B_TOT, 256, 1568);
    k_mnorm<<<4096, 256, 0, stream>>>(memory, inv_mn);
    k_sgemm<<<dim3(4096 / 128, B_TOT / 64), 256, 0, stream>>>(latent, memh, meml, nullptr,
                                                              dots, B_TOT, 4096, 256);
    k_memread<<<B_TOT, 256, 0, stream>>>(latent, dots, inv_mn, memory, mem_latent);

    // Decoder, full batch in one pass.
    for (int c = 0; c < B_TOT / CHUNK; ++c) {
        const float* ml = mem_latent + (size_t)c * CHUNK * 256;
        k_dgemm<<<dim3(6272 / 128, CHUNK / 64), 256, 0, stream>>>(ml, Wf, bf, d1h,
                                                                  CHUNK, 6272, 256);
        k_conv1  <<<CHUNK / 2, 256, 0, stream>>>(d1h, pk2h, c1_b, d2h);
        k_convt23<<<CHUNK, 256, 0, stream>>>(d2h, pk3h, upt2_b, pk4, c2_b, c3_w, c3_b,
                                             outp + (size_t)c * CHUNK * 784);
    }
}